// Round 1
// baseline (6568.089 us; speedup 1.0000x reference)
//
#include <hip/hip_runtime.h>
#include <hip/hip_fp16.h>
#include <cstdint>

typedef unsigned short u16;

#define D_DIM 1000
#define C_IN  1024
#define HW    256
#define S_DIM 512
#define Q_DIM 64

__device__ __forceinline__ float h2f(u16 h) { return __half2float(__ushort_as_half(h)); }
__device__ __forceinline__ u16  f2h(float f) { return __half_as_ushort(__float2half(f)); }

// ---------------------------------------------------------------------------
// Kernel A: 1x1 conv.  img[b, d, s] ; s<256 -> frontal (d_in[1]), s>=256 -> lateral (d_in[0])
// grid: 32(b) * 2(half) * 16(mt) * 4(nt) = 4096 blocks, 256 threads
// ---------------------------------------------------------------------------
__global__ __launch_bounds__(256) void k_conv(
    const float* __restrict__ feat_l, const float* __restrict__ feat_f,
    const float* __restrict__ cw, const float* __restrict__ cb,
    float* __restrict__ img)
{
    int bid = blockIdx.x;
    int nt = bid & 3;
    int mt = (bid >> 2) & 15;
    int half_ = (bid >> 6) & 1;
    int b = bid >> 7;
    const float* feat = (half_ ? feat_l : feat_f) + (size_t)b * C_IN * HW;

    __shared__ float As[64 * 17];   // [m][k]
    __shared__ float Bs[16 * 65];   // [k][n]

    int tid = threadIdx.x;
    int tx = tid & 15, ty = tid >> 4;
    int m0 = mt * 64, n0 = nt * 64;

    float acc[4][4] = {};

    for (int k0 = 0; k0 < C_IN; k0 += 16) {
        {
            int mm = tid >> 2, k4 = (tid & 3) << 2;
            int m = m0 + mm;
            float4 v = make_float4(0.f, 0.f, 0.f, 0.f);
            if (m < D_DIM) v = *reinterpret_cast<const float4*>(cw + (size_t)m * C_IN + k0 + k4);
            As[mm * 17 + k4 + 0] = v.x; As[mm * 17 + k4 + 1] = v.y;
            As[mm * 17 + k4 + 2] = v.z; As[mm * 17 + k4 + 3] = v.w;
        }
        {
            int k = tid >> 4, n4 = (tid & 15) << 2;
            float4 v = *reinterpret_cast<const float4*>(feat + (size_t)(k0 + k) * HW + n0 + n4);
            Bs[k * 65 + n4 + 0] = v.x; Bs[k * 65 + n4 + 1] = v.y;
            Bs[k * 65 + n4 + 2] = v.z; Bs[k * 65 + n4 + 3] = v.w;
        }
        __syncthreads();
        #pragma unroll
        for (int k = 0; k < 16; k++) {
            float a[4], bb[4];
            #pragma unroll
            for (int j = 0; j < 4; j++) a[j] = As[(ty * 4 + j) * 17 + k];
            #pragma unroll
            for (int j = 0; j < 4; j++) bb[j] = Bs[k * 65 + tx * 4 + j];
            #pragma unroll
            for (int j = 0; j < 4; j++)
                #pragma unroll
                for (int jj = 0; jj < 4; jj++)
                    acc[j][jj] = fmaf(a[j], bb[jj], acc[j][jj]);
        }
        __syncthreads();
    }
    #pragma unroll
    for (int j = 0; j < 4; j++) {
        int m = m0 + ty * 4 + j;
        if (m < D_DIM) {
            float bias = cb[m];
            float4 sv;
            sv.x = acc[j][0] + bias; sv.y = acc[j][1] + bias;
            sv.z = acc[j][2] + bias; sv.w = acc[j][3] + bias;
            int s = half_ * 256 + n0 + tx * 4;
            *reinterpret_cast<float4*>(img + (size_t)b * D_DIM * S_DIM + (size_t)m * S_DIM + s) = sv;
        }
    }
}

// ---------------------------------------------------------------------------
// Kernel B: per (i,b) pair: logits -> a1 -> U=exp(4*a1) -> Z -> (att_maps if i==b)
//           -> wctx -> v = wctx*word (unnormalized sim_loc, fp16) -> invn, sim_ave
// grid: 1024 blocks (pair = b*32 + i), 256 threads
// LDS: U 65792 + tA 4160 + uB 8448 + invZ 256 + invnS 256 = 78912 B  (2 blocks/CU)
// ---------------------------------------------------------------------------
__global__ __launch_bounds__(256) void k_attn(
    const float* __restrict__ img, const float* __restrict__ words,
    float* __restrict__ out, u16* __restrict__ vbuf,
    float* __restrict__ invn_ws, float* __restrict__ simave_ws)
{
    const int pair = blockIdx.x;
    const int i = pair & 31, b = pair >> 5;
    const float* imgb = img + (size_t)b * D_DIM * S_DIM;
    const float* wrd  = words + (size_t)i * D_DIM * Q_DIM;
    u16* vb = vbuf + (size_t)pair * 64 * D_DIM;

    __shared__ u16   U[64 * 514];          // U[q][s] = exp(4*a1[s,q]), fp16
    __shared__ float tA[16 * 65];          // img tiles (stage1 & stage3), Z scratch
    __shared__ char  uB_raw[64 * 66 * 2] __attribute__((aligned(16)));  // tB (f32 16x65) / Wth (h16 64x66)
    __shared__ float invZ[64];
    __shared__ float invnS[64];

    float* tB = reinterpret_cast<float*>(uB_raw);
    u16*  Wth = reinterpret_cast<u16*>(uB_raw);

    const int tid = threadIdx.x;
    const int tx = tid & 15, ty = tid >> 4;

    // ---- Stage 1: logits[s,q] = sum_d img[b,d,s]*words[i,d,q]; softmax over q; U = exp(4*a1)
    for (int st = 0; st < 8; st++) {
        float acc[4][4] = {};   // rows j = s, cols jj = q
        for (int k0 = 0; k0 < D_DIM; k0 += 16) {
            {
                int k = tid >> 4, s4 = (tid & 15) << 2;
                int d = k0 + k;
                float4 v = make_float4(0.f, 0.f, 0.f, 0.f);
                if (d < D_DIM) v = *reinterpret_cast<const float4*>(imgb + (size_t)d * S_DIM + st * 64 + s4);
                tA[k * 65 + s4 + 0] = v.x; tA[k * 65 + s4 + 1] = v.y;
                tA[k * 65 + s4 + 2] = v.z; tA[k * 65 + s4 + 3] = v.w;
            }
            {
                int k = tid >> 4, q4 = (tid & 15) << 2;
                int d = k0 + k;
                float4 v = make_float4(0.f, 0.f, 0.f, 0.f);
                if (d < D_DIM) v = *reinterpret_cast<const float4*>(wrd + (size_t)d * Q_DIM + q4);
                tB[k * 65 + q4 + 0] = v.x; tB[k * 65 + q4 + 1] = v.y;
                tB[k * 65 + q4 + 2] = v.z; tB[k * 65 + q4 + 3] = v.w;
            }
            __syncthreads();
            #pragma unroll
            for (int k = 0; k < 16; k++) {
                float a[4], w4[4];
                #pragma unroll
                for (int j = 0; j < 4; j++) a[j] = tA[k * 65 + ty * 4 + j];
                #pragma unroll
                for (int j = 0; j < 4; j++) w4[j] = tB[k * 65 + tx * 4 + j];
                #pragma unroll
                for (int j = 0; j < 4; j++)
                    #pragma unroll
                    for (int jj = 0; jj < 4; jj++)
                        acc[j][jj] = fmaf(a[j], w4[jj], acc[j][jj]);
            }
            __syncthreads();
        }
        #pragma unroll
        for (int j = 0; j < 4; j++) {
            float m = fmaxf(fmaxf(acc[j][0], acc[j][1]), fmaxf(acc[j][2], acc[j][3]));
            #pragma unroll
            for (int mk = 1; mk < 16; mk <<= 1) m = fmaxf(m, __shfl_xor(m, mk));
            float e[4], ssum = 0.f;
            #pragma unroll
            for (int jj = 0; jj < 4; jj++) { e[jj] = expf(acc[j][jj] - m); ssum += e[jj]; }
            #pragma unroll
            for (int mk = 1; mk < 16; mk <<= 1) ssum += __shfl_xor(ssum, mk);
            float inv = 1.f / ssum;
            int srow = st * 64 + ty * 4 + j;
            #pragma unroll
            for (int jj = 0; jj < 4; jj++) {
                float u = expf(4.f * e[jj] * inv);   // exp(TEMP1 * a1), bounded by e^4
                U[(tx * 4 + jj) * 514 + srow] = f2h(u);
            }
        }
    }
    __syncthreads();

    // ---- Stage 2: Z_q = sum_s U[q][s]
    {
        int q = tid & 63, ch = tid >> 6;
        float zp = 0.f;
        for (int s = ch * 128; s < ch * 128 + 128; s++) zp += h2f(U[q * 514 + s]);
        tA[ch * 64 + q] = zp;
    }
    __syncthreads();
    if (tid < 64) {
        float Z = tA[tid] + tA[64 + tid] + tA[128 + tid] + tA[192 + tid];
        invZ[tid] = 1.f / Z;
    }
    __syncthreads();

    if (i == b) {   // att_maps[i][q][s] = a2
        float* am = out + 1024 + (size_t)i * Q_DIM * S_DIM;
        for (int idx = tid; idx < Q_DIM * S_DIM; idx += 256) {
            int q = idx >> 9;
            am[idx] = h2f(U[q * 514 + (idx & 511)]) * invZ[q];
        }
    }

    // ---- Stage 3: wctx[q,d] = invZ[q] * sum_s U[q,s]*img[b,d,s]; v = wctx*word[i,d,q]
    float ssq[4] = {0.f, 0.f, 0.f, 0.f};
    for (int dt = 0; dt < 16; dt++) {
        float acc[4][4] = {};   // rows j = q, cols jj = d
        for (int s0 = 0; s0 < S_DIM; s0 += 16) {
            {
                int dd = tid >> 2, k4 = (tid & 3) << 2;
                int d = dt * 64 + dd;
                float4 v = make_float4(0.f, 0.f, 0.f, 0.f);
                if (d < D_DIM) v = *reinterpret_cast<const float4*>(imgb + (size_t)d * S_DIM + s0 + k4);
                tA[(k4 + 0) * 65 + dd] = v.x; tA[(k4 + 1) * 65 + dd] = v.y;
                tA[(k4 + 2) * 65 + dd] = v.z; tA[(k4 + 3) * 65 + dd] = v.w;
            }
            __syncthreads();
            #pragma unroll
            for (int k = 0; k < 16; k++) {
                float uq[4], im[4];
                #pragma unroll
                for (int j = 0; j < 4; j++) uq[j] = h2f(U[(ty * 4 + j) * 514 + s0 + k]);
                #pragma unroll
                for (int jj = 0; jj < 4; jj++) im[jj] = tA[k * 65 + tx * 4 + jj];
                #pragma unroll
                for (int j = 0; j < 4; j++)
                    #pragma unroll
                    for (int jj = 0; jj < 4; jj++)
                        acc[j][jj] = fmaf(uq[j], im[jj], acc[j][jj]);
            }
            __syncthreads();
        }
        // stage words tile (fp16): Wth[dd][q] = words[i, dt*64+dd, q]
        #pragma unroll
        for (int l = 0; l < 4; l++) {
            int e = tid + l * 256;
            int dd = e >> 4, q4 = (e & 15) << 2;
            int d = dt * 64 + dd;
            float4 v = make_float4(0.f, 0.f, 0.f, 0.f);
            if (d < D_DIM) v = *reinterpret_cast<const float4*>(wrd + (size_t)d * Q_DIM + q4);
            Wth[dd * 66 + q4 + 0] = f2h(v.x); Wth[dd * 66 + q4 + 1] = f2h(v.y);
            Wth[dd * 66 + q4 + 2] = f2h(v.z); Wth[dd * 66 + q4 + 3] = f2h(v.w);
        }
        __syncthreads();
        #pragma unroll
        for (int j = 0; j < 4; j++) {
            int q = ty * 4 + j;
            float iz = invZ[q];
            u16 pk[4];
            #pragma unroll
            for (int jj = 0; jj < 4; jj++) {
                float wctx = acc[j][jj] * iz;
                float vv = wctx * h2f(Wth[(tx * 4 + jj) * 66 + q]);
                ssq[j] = fmaf(vv, vv, ssq[j]);   // zero for d>=1000 (img & word tiles zero)
                pk[jj] = f2h(vv);
            }
            int d4 = dt * 64 + tx * 4;
            if (d4 < D_DIM) {
                ushort4 u4; u4.x = pk[0]; u4.y = pk[1]; u4.z = pk[2]; u4.w = pk[3];
                *reinterpret_cast<ushort4*>(vb + (size_t)q * D_DIM + d4) = u4;
            }
        }
        __syncthreads();
    }
    #pragma unroll
    for (int j = 0; j < 4; j++)
        #pragma unroll
        for (int mk = 1; mk < 16; mk <<= 1) ssq[j] += __shfl_xor(ssq[j], mk);
    if (tx == 0) {
        #pragma unroll
        for (int j = 0; j < 4; j++) {
            int q = ty * 4 + j;
            float n = 1.f / (sqrtf(ssq[j]) + 1e-8f);
            invnS[q] = n;
            invn_ws[pair * 64 + q] = n;
        }
    }
    __syncthreads();

    // sim_ave[d] = mean_q sim_loc[q,d]
    for (int d = tid; d < D_DIM; d += 256) {
        float s = 0.f;
        for (int q = 0; q < 64; q++) s = fmaf(h2f(vb[(size_t)q * D_DIM + d]), invnS[q], s);
        simave_ws[(size_t)pair * D_DIM + d] = s * (1.f / 64.f);
    }
}

// ---------------------------------------------------------------------------
// Kernel D: g2[pair][e] = tanh(sum_d sim_ave[pair,d]*wg[d,e] + bg[e]) * wc[e]
// One GEMM M=1024(pairs) N=1000 K=1000.  grid 256 blocks (16 mt x 16 nt)
// ---------------------------------------------------------------------------
__global__ __launch_bounds__(256) void k_g2(
    const float* __restrict__ simave, const float* __restrict__ wg,
    const float* __restrict__ bg, const float* __restrict__ wc,
    float* __restrict__ g2)
{
    int mt = blockIdx.x & 15;
    int nt = blockIdx.x >> 4;
    __shared__ float As[16 * 65], Bs[16 * 65];
    int tid = threadIdx.x;
    int tx = tid & 15, ty = tid >> 4;
    int m0 = mt * 64, n0 = nt * 64;
    float acc[4][4] = {};
    for (int k0 = 0; k0 < D_DIM; k0 += 16) {
        {
            int mm = tid >> 2, k4 = (tid & 3) << 2;
            float4 v = make_float4(0.f, 0.f, 0.f, 0.f);
            if (k0 + k4 < D_DIM) v = *reinterpret_cast<const float4*>(simave + (size_t)(m0 + mm) * D_DIM + k0 + k4);
            As[(k4 + 0) * 65 + mm] = v.x; As[(k4 + 1) * 65 + mm] = v.y;
            As[(k4 + 2) * 65 + mm] = v.z; As[(k4 + 3) * 65 + mm] = v.w;
        }
        {
            int k = tid >> 4, n4 = (tid & 15) << 2;
            float4 v = make_float4(0.f, 0.f, 0.f, 0.f);
            if (k0 + k < D_DIM && n0 + n4 < D_DIM)
                v = *reinterpret_cast<const float4*>(wg + (size_t)(k0 + k) * D_DIM + n0 + n4);
            Bs[k * 65 + n4 + 0] = v.x; Bs[k * 65 + n4 + 1] = v.y;
            Bs[k * 65 + n4 + 2] = v.z; Bs[k * 65 + n4 + 3] = v.w;
        }
        __syncthreads();
        #pragma unroll
        for (int k = 0; k < 16; k++) {
            float a[4], bb[4];
            #pragma unroll
            for (int j = 0; j < 4; j++) a[j] = As[k * 65 + ty * 4 + j];
            #pragma unroll
            for (int j = 0; j < 4; j++) bb[j] = Bs[k * 65 + tx * 4 + j];
            #pragma unroll
            for (int j = 0; j < 4; j++)
                #pragma unroll
                for (int jj = 0; jj < 4; jj++)
                    acc[j][jj] = fmaf(a[j], bb[jj], acc[j][jj]);
        }
        __syncthreads();
    }
    #pragma unroll
    for (int j = 0; j < 4; j++) {
        int p = m0 + ty * 4 + j;
        #pragma unroll
        for (int jj = 0; jj < 4; jj++) {
            int e = n0 + tx * 4 + jj;
            if (e < D_DIM) g2[(size_t)p * D_DIM + e] = tanhf(acc[j][jj] + bg[e]) * wc[e];
        }
    }
}

// ---------------------------------------------------------------------------
// Kernel C: per pair: w[q] = sum_e tanh(sum_d simloc[q,d]*wl[d,e] + bl[e]) * g2[e]
//           -> softmax(w) -> new_global -> l2norm -> sigmoid -> out[b*32+i]
// grid: 1024 blocks, 256 threads
// ---------------------------------------------------------------------------
__global__ __launch_bounds__(256) void k_sa(
    const u16* __restrict__ vbuf, const float* __restrict__ invn_ws,
    const float* __restrict__ g2_ws, const float* __restrict__ wl,
    const float* __restrict__ bl, const float* __restrict__ capw,
    const float* __restrict__ capb, float* __restrict__ out)
{
    const int pair = blockIdx.x;
    const int i = pair & 31, b = pair >> 5;
    const u16* vb = vbuf + (size_t)pair * 64 * D_DIM;

    __shared__ float SL[16 * 65], WL[16 * 65];
    __shared__ float g2l[1024], bll[1024];
    __shared__ float invnS[64], wiS[64];
    __shared__ float red[8];

    const int tid = threadIdx.x;
    const int tx = tid & 15, ty = tid >> 4;

    for (int e = tid; e < 1024; e += 256) {
        g2l[e] = (e < D_DIM) ? g2_ws[(size_t)pair * D_DIM + e] : 0.f;
        bll[e] = (e < D_DIM) ? bl[e] : 0.f;
    }
    if (tid < 64) invnS[tid] = invn_ws[pair * 64 + tid];
    __syncthreads();

    float wpart[4] = {0.f, 0.f, 0.f, 0.f};
    for (int et = 0; et < 16; et++) {
        float acc[4][4] = {};   // rows j = q, cols jj = e
        for (int k0 = 0; k0 < D_DIM; k0 += 16) {
            {
                int qq = tid >> 2, k4 = (tid & 3) << 2;
                float sc = invnS[qq];
                ushort4 uv = make_ushort4(0, 0, 0, 0);
                if (k0 + k4 < D_DIM) uv = *reinterpret_cast<const ushort4*>(vb + (size_t)qq * D_DIM + k0 + k4);
                SL[(k4 + 0) * 65 + qq] = h2f(uv.x) * sc; SL[(k4 + 1) * 65 + qq] = h2f(uv.y) * sc;
                SL[(k4 + 2) * 65 + qq] = h2f(uv.z) * sc; SL[(k4 + 3) * 65 + qq] = h2f(uv.w) * sc;
            }
            {
                int k = tid >> 4, e4 = (tid & 15) << 2;
                float4 v = make_float4(0.f, 0.f, 0.f, 0.f);
                if (k0 + k < D_DIM && et * 64 + e4 < D_DIM)
                    v = *reinterpret_cast<const float4*>(wl + (size_t)(k0 + k) * D_DIM + et * 64 + e4);
                WL[k * 65 + e4 + 0] = v.x; WL[k * 65 + e4 + 1] = v.y;
                WL[k * 65 + e4 + 2] = v.z; WL[k * 65 + e4 + 3] = v.w;
            }
            __syncthreads();
            #pragma unroll
            for (int k = 0; k < 16; k++) {
                float a[4], bw[4];
                #pragma unroll
                for (int j = 0; j < 4; j++) a[j] = SL[k * 65 + ty * 4 + j];
                #pragma unroll
                for (int j = 0; j < 4; j++) bw[j] = WL[k * 65 + tx * 4 + j];
                #pragma unroll
                for (int j = 0; j < 4; j++)
                    #pragma unroll
                    for (int jj = 0; jj < 4; jj++)
                        acc[j][jj] = fmaf(a[j], bw[jj], acc[j][jj]);
            }
            __syncthreads();
        }
        #pragma unroll
        for (int j = 0; j < 4; j++)
            #pragma unroll
            for (int jj = 0; jj < 4; jj++) {
                int e = et * 64 + tx * 4 + jj;   // e>=1000: acc=0,bll=0,g2l=0 -> contributes 0
                wpart[j] += tanhf(acc[j][jj] + bll[e]) * g2l[e];
            }
    }
    #pragma unroll
    for (int j = 0; j < 4; j++)
        #pragma unroll
        for (int mk = 1; mk < 16; mk <<= 1) wpart[j] += __shfl_xor(wpart[j], mk);
    if (tx == 0) {
        #pragma unroll
        for (int j = 0; j < 4; j++) wiS[ty * 4 + j] = wpart[j];
    }
    __syncthreads();
    if (tid < 64) {  // softmax over q, then fold in invn
        float x = wiS[tid];
        float m = x;
        #pragma unroll
        for (int mk = 1; mk < 64; mk <<= 1) m = fmaxf(m, __shfl_xor(m, mk));
        float e = expf(x - m);
        float Z = e;
        #pragma unroll
        for (int mk = 1; mk < 64; mk <<= 1) Z += __shfl_xor(Z, mk);
        wiS[tid] = (e / Z) * invnS[tid];
    }
    __syncthreads();

    float s1 = 0.f, s2 = 0.f;
    for (int d = tid; d < D_DIM; d += 256) {
        float ng = 0.f;
        for (int q = 0; q < 64; q++) ng = fmaf(wiS[q], h2f(vb[(size_t)q * D_DIM + d]), ng);
        s1 = fmaf(ng, capw[d], s1);
        s2 = fmaf(ng, ng, s2);
    }
    #pragma unroll
    for (int mk = 1; mk < 64; mk <<= 1) { s1 += __shfl_xor(s1, mk); s2 += __shfl_xor(s2, mk); }
    if ((tid & 63) == 0) { red[tid >> 6] = s1; red[4 + (tid >> 6)] = s2; }
    __syncthreads();
    if (tid == 0) {
        float S1 = red[0] + red[1] + red[2] + red[3];
        float S2 = red[4] + red[5] + red[6] + red[7];
        float val = S1 / (sqrtf(S2) + 1e-8f) + capb[0];
        out[b * 32 + i] = 1.f / (1.f + expf(-val));
    }
}

// ---------------------------------------------------------------------------
extern "C" void kernel_launch(void* const* d_in, const int* in_sizes, int n_in,
                              void* d_out, int out_size, void* d_ws, size_t ws_size,
                              hipStream_t stream)
{
    const float* feat_l = (const float*)d_in[0];
    const float* feat_f = (const float*)d_in[1];
    const float* words  = (const float*)d_in[2];
    const float* conv_w = (const float*)d_in[3];
    const float* conv_b = (const float*)d_in[4];
    const float* sa_wl  = (const float*)d_in[5];
    const float* sa_bl  = (const float*)d_in[6];
    const float* sa_wg  = (const float*)d_in[7];
    const float* sa_bg  = (const float*)d_in[8];
    const float* sa_wc  = (const float*)d_in[9];
    // d_in[10] = sa_bc: constant shift before softmax -> result-invariant, unused
    const float* cap_w  = (const float*)d_in[11];
    const float* cap_b  = (const float*)d_in[12];
    float* out = (float*)d_out;

    char* ws = (char*)d_ws;
    // ws layout (bytes):
    //   img    : 32*1000*512*4      = 65,536,000
    //   vbuf   : 1024*64*1000*2     = 131,072,000   (fp16 unnormalized sim_loc)
    //   invn   : 1024*64*4          = 262,144
    //   simave : 1024*1000*4        = 4,096,000
    //   g2     : 1024*1000*4        = 4,096,000     total ~205.1 MB
    float* img    = (float*)(ws);
    u16*   vbuf   = (u16*)  (ws + 65536000);
    float* invn   = (float*)(ws + 196608000);
    float* simave = (float*)(ws + 196870144);
    float* g2     = (float*)(ws + 200966144);

    hipLaunchKernelGGL(k_conv, dim3(4096), dim3(256), 0, stream,
                       feat_l, feat_f, conv_w, conv_b, img);
    hipLaunchKernelGGL(k_attn, dim3(1024), dim3(256), 0, stream,
                       img, words, out, vbuf, invn, simave);
    hipLaunchKernelGGL(k_g2, dim3(256), dim3(256), 0, stream,
                       simave, sa_wg, sa_bg, sa_wc, g2);
    hipLaunchKernelGGL(k_sa, dim3(1024), dim3(256), 0, stream,
                       vbuf, invn, g2, sa_wl, sa_bl, cap_w, cap_b, out);
}

// Round 2
// 3645.433 us; speedup vs baseline: 1.8017x; 1.8017x over previous
//
#include <hip/hip_runtime.h>
#include <cstdint>

typedef unsigned short u16;
typedef unsigned int   u32;
typedef __attribute__((ext_vector_type(8))) short bf16x8;
typedef __attribute__((ext_vector_type(4))) float f32x4;

#define D_DIM 1000
#define C_IN  1024
#define HW    256
#define S_DIM 512
#define Q_DIM 64

__device__ __forceinline__ u16 f2b(float x) {
    u32 u = __builtin_bit_cast(u32, x);
    u32 r = (u + 0x7FFFu + ((u >> 16) & 1u)) >> 16;
    return (u16)r;
}
__device__ __forceinline__ float b2f(u16 h) {
    u32 u = ((u32)h) << 16;
    return __builtin_bit_cast(float, u);
}

// ---------------------------------------------------------------------------
// Kernel A: 1x1 conv (fp32). img[b, d, s]; s<256 frontal, s>=256 lateral
// ---------------------------------------------------------------------------
__global__ __launch_bounds__(256) void k_conv(
    const float* __restrict__ feat_l, const float* __restrict__ feat_f,
    const float* __restrict__ cw, const float* __restrict__ cb,
    float* __restrict__ img)
{
    int bid = blockIdx.x;
    int nt = bid & 3;
    int mt = (bid >> 2) & 15;
    int half_ = (bid >> 6) & 1;
    int b = bid >> 7;
    const float* feat = (half_ ? feat_l : feat_f) + (size_t)b * C_IN * HW;

    __shared__ float As[64 * 17];
    __shared__ float Bs[16 * 65];

    int tid = threadIdx.x;
    int tx = tid & 15, ty = tid >> 4;
    int m0 = mt * 64, n0 = nt * 64;

    float acc[4][4] = {};

    for (int k0 = 0; k0 < C_IN; k0 += 16) {
        {
            int mm = tid >> 2, k4 = (tid & 3) << 2;
            int m = m0 + mm;
            float4 v = make_float4(0.f, 0.f, 0.f, 0.f);
            if (m < D_DIM) v = *reinterpret_cast<const float4*>(cw + (size_t)m * C_IN + k0 + k4);
            As[mm * 17 + k4 + 0] = v.x; As[mm * 17 + k4 + 1] = v.y;
            As[mm * 17 + k4 + 2] = v.z; As[mm * 17 + k4 + 3] = v.w;
        }
        {
            int k = tid >> 4, n4 = (tid & 15) << 2;
            float4 v = *reinterpret_cast<const float4*>(feat + (size_t)(k0 + k) * HW + n0 + n4);
            Bs[k * 65 + n4 + 0] = v.x; Bs[k * 65 + n4 + 1] = v.y;
            Bs[k * 65 + n4 + 2] = v.z; Bs[k * 65 + n4 + 3] = v.w;
        }
        __syncthreads();
        #pragma unroll
        for (int k = 0; k < 16; k++) {
            float a[4], bb[4];
            #pragma unroll
            for (int j = 0; j < 4; j++) a[j] = As[(ty * 4 + j) * 17 + k];
            #pragma unroll
            for (int j = 0; j < 4; j++) bb[j] = Bs[k * 65 + tx * 4 + j];
            #pragma unroll
            for (int j = 0; j < 4; j++)
                #pragma unroll
                for (int jj = 0; jj < 4; jj++)
                    acc[j][jj] = fmaf(a[j], bb[jj], acc[j][jj]);
        }
        __syncthreads();
    }
    #pragma unroll
    for (int j = 0; j < 4; j++) {
        int m = m0 + ty * 4 + j;
        if (m < D_DIM) {
            float bias = cb[m];
            float4 sv;
            sv.x = acc[j][0] + bias; sv.y = acc[j][1] + bias;
            sv.z = acc[j][2] + bias; sv.w = acc[j][3] + bias;
            int s = half_ * 256 + n0 + tx * 4;
            *reinterpret_cast<float4*>(img + (size_t)b * D_DIM * S_DIM + (size_t)m * S_DIM + s) = sv;
        }
    }
}

// ---------------------------------------------------------------------------
// k_prep: wlT_bf16[e][d] = bf16(wl[d][e]); [1024][1024], zero-padded. 256 blocks.
// ---------------------------------------------------------------------------
__global__ __launch_bounds__(256) void k_prep(const float* __restrict__ wl, u16* __restrict__ wlT)
{
    __shared__ float t[64][65];
    int bd = blockIdx.x & 15, be = blockIdx.x >> 4;
    int tx = threadIdx.x & 15, ty = threadIdx.x >> 4;
    #pragma unroll
    for (int rr = 0; rr < 4; rr++) {
        int r = ty * 4 + rr;
        int d = bd * 64 + r;
        int e4 = be * 64 + tx * 4;
        float v0 = 0.f, v1 = 0.f, v2 = 0.f, v3 = 0.f;
        if (d < D_DIM) {
            if (e4 + 3 < D_DIM) {
                float4 v = *reinterpret_cast<const float4*>(wl + (size_t)d * D_DIM + e4);
                v0 = v.x; v1 = v.y; v2 = v.z; v3 = v.w;
            } else {
                if (e4 + 0 < D_DIM) v0 = wl[(size_t)d * D_DIM + e4 + 0];
                if (e4 + 1 < D_DIM) v1 = wl[(size_t)d * D_DIM + e4 + 1];
                if (e4 + 2 < D_DIM) v2 = wl[(size_t)d * D_DIM + e4 + 2];
                if (e4 + 3 < D_DIM) v3 = wl[(size_t)d * D_DIM + e4 + 3];
            }
        }
        t[r][tx * 4 + 0] = v0; t[r][tx * 4 + 1] = v1;
        t[r][tx * 4 + 2] = v2; t[r][tx * 4 + 3] = v3;
    }
    __syncthreads();
    #pragma unroll
    for (int rr = 0; rr < 4; rr++) {
        int r2 = ty * 4 + rr;          // e within tile
        int e = be * 64 + r2;
        int d0 = bd * 64 + tx * 4;
        ushort4 h;
        h.x = f2b(t[tx * 4 + 0][r2]); h.y = f2b(t[tx * 4 + 1][r2]);
        h.z = f2b(t[tx * 4 + 2][r2]); h.w = f2b(t[tx * 4 + 3][r2]);
        *reinterpret_cast<ushort4*>(wlT + (size_t)e * 1024 + d0) = h;
    }
}

// ---------------------------------------------------------------------------
// Kernel B: per (i,b): fp32 logits+softmax -> U(bf16, xor-swz, pre-scaled by 1/Z)
//           -> MFMA wctx -> v = wctx*word -> vb (bf16, rows padded to 1024), invn, simave
// LDS: U 65536 + union 16384 = 81920 (2 blocks/CU)
// ---------------------------------------------------------------------------
__global__ __launch_bounds__(256) void k_attn(
    const float* __restrict__ img, const float* __restrict__ words,
    u16* __restrict__ vbuf, float* __restrict__ invn_ws, float* __restrict__ simave_ws)
{
    const int pair = blockIdx.x;
    const int i = pair & 31, b = pair >> 5;
    const float* imgb = img + (size_t)b * D_DIM * S_DIM;
    const float* wrd  = words + (size_t)i * D_DIM * Q_DIM;
    u16* vb = vbuf + (size_t)pair * 64 * 1024;

    __shared__ char Ubytes[64 * 1024] __attribute__((aligned(16)));
    __shared__ char unionb[16384] __attribute__((aligned(16)));

    const int tid = threadIdx.x;
    const int tx = tid & 15, ty = tid >> 4;

    // ---- Stage 1: fp32 logits GEMM + softmax over q; U[q][s] = bf16(exp(4*a1))
    {
        float* tA = (float*)unionb;            // 16x65 f32
        float* tB = (float*)(unionb + 4352);   // 16x65 f32
        for (int st = 0; st < 8; st++) {
            float acc[4][4] = {};   // rows j = s, cols jj = q
            for (int k0 = 0; k0 < D_DIM; k0 += 16) {
                {
                    int k = tid >> 4, s4 = (tid & 15) << 2;
                    int d = k0 + k;
                    float4 v = make_float4(0.f, 0.f, 0.f, 0.f);
                    if (d < D_DIM) v = *reinterpret_cast<const float4*>(imgb + (size_t)d * S_DIM + st * 64 + s4);
                    tA[k * 65 + s4 + 0] = v.x; tA[k * 65 + s4 + 1] = v.y;
                    tA[k * 65 + s4 + 2] = v.z; tA[k * 65 + s4 + 3] = v.w;
                }
                {
                    int k = tid >> 4, q4 = (tid & 15) << 2;
                    int d = k0 + k;
                    float4 v = make_float4(0.f, 0.f, 0.f, 0.f);
                    if (d < D_DIM) v = *reinterpret_cast<const float4*>(wrd + (size_t)d * Q_DIM + q4);
                    tB[k * 65 + q4 + 0] = v.x; tB[k * 65 + q4 + 1] = v.y;
                    tB[k * 65 + q4 + 2] = v.z; tB[k * 65 + q4 + 3] = v.w;
                }
                __syncthreads();
                #pragma unroll
                for (int k = 0; k < 16; k++) {
                    float a[4], w4[4];
                    #pragma unroll
                    for (int j = 0; j < 4; j++) a[j] = tA[k * 65 + ty * 4 + j];
                    #pragma unroll
                    for (int j = 0; j < 4; j++) w4[j] = tB[k * 65 + tx * 4 + j];
                    #pragma unroll
                    for (int j = 0; j < 4; j++)
                        #pragma unroll
                        for (int jj = 0; jj < 4; jj++)
                            acc[j][jj] = fmaf(a[j], w4[jj], acc[j][jj]);
                }
                __syncthreads();
            }
            #pragma unroll
            for (int j = 0; j < 4; j++) {
                float m = fmaxf(fmaxf(acc[j][0], acc[j][1]), fmaxf(acc[j][2], acc[j][3]));
                #pragma unroll
                for (int mk = 1; mk < 16; mk <<= 1) m = fmaxf(m, __shfl_xor(m, mk));
                float e[4], ssum = 0.f;
                #pragma unroll
                for (int jj = 0; jj < 4; jj++) { e[jj] = expf(acc[j][jj] - m); ssum += e[jj]; }
                #pragma unroll
                for (int mk = 1; mk < 16; mk <<= 1) ssum += __shfl_xor(ssum, mk);
                float inv = 1.f / ssum;
                int srow = st * 64 + ty * 4 + j;
                #pragma unroll
                for (int jj = 0; jj < 4; jj++) {
                    float u = expf(4.f * e[jj] * inv);     // exp(TEMP1*a1) in [1, e^4]
                    int q = tx * 4 + jj;
                    int off = q * 1024 + ((2 * srow) ^ ((q & 7) << 4));
                    *(u16*)(Ubytes + off) = f2b(u);
                }
            }
        }
    }
    __syncthreads();

    // ---- Stage 2: Z_q = sum_s U[q][s]; rescale U *= 1/Z in place
    {
        float* zred = (float*)unionb;   // 256 f32
        int q = tid & 63, ch = tid >> 6;
        float zp = 0.f;
        for (int s = ch * 128; s < ch * 128 + 128; s++) {
            int off = q * 1024 + ((2 * s) ^ ((q & 7) << 4));
            zp += b2f(*(const u16*)(Ubytes + off));
        }
        zred[ch * 64 + q] = zp;
        __syncthreads();
        float Z = zred[q] + zred[64 + q] + zred[128 + q] + zred[192 + q];
        float iz = 1.f / Z;
        for (int s = ch * 128; s < ch * 128 + 128; s++) {
            int off = q * 1024 + ((2 * s) ^ ((q & 7) << 4));
            u16* p = (u16*)(Ubytes + off);
            *p = f2b(b2f(*p) * iz);
        }
    }
    __syncthreads();

    // ---- Stage 3: MFMA wctx[q,d] = sum_s a2[q,s]*img[d,s]; v = wctx*word; vb bf16
    char* Bt = unionb;           // img tile: [chunk 0..7][dd 0..63][16B] = 8192
    char* Wt = unionb + 8192;    // word tile: [dd][128B xor-swz] = 8192

    const int w  = tid >> 6;
    const int l  = tid & 63;
    const int l15 = l & 15, l4 = l >> 4;

    float ssq[4] = {0.f, 0.f, 0.f, 0.f};

    for (int dt = 0; dt < 16; dt++) {
        __syncthreads();   // prior epilogue/MFMA reads of Wt/Bt done
        // stage word tile: Wt[dd][q], xor-swizzled 8-q slots
        {
            int dd = tid >> 2, qg = (tid & 3) * 16;
            int d = dt * 64 + dd;
            float4 p0, p1, p2, p3;
            if (d < D_DIM) {
                const float* src = wrd + (size_t)d * Q_DIM + qg;
                p0 = *(const float4*)(src);      p1 = *(const float4*)(src + 4);
                p2 = *(const float4*)(src + 8);  p3 = *(const float4*)(src + 12);
            } else {
                p0 = p1 = p2 = p3 = make_float4(0.f, 0.f, 0.f, 0.f);
            }
            bf16x8 h0, h1;
            h0[0]=(short)f2b(p0.x); h0[1]=(short)f2b(p0.y); h0[2]=(short)f2b(p0.z); h0[3]=(short)f2b(p0.w);
            h0[4]=(short)f2b(p1.x); h0[5]=(short)f2b(p1.y); h0[6]=(short)f2b(p1.z); h0[7]=(short)f2b(p1.w);
            h1[0]=(short)f2b(p2.x); h1[1]=(short)f2b(p2.y); h1[2]=(short)f2b(p2.z); h1[3]=(short)f2b(p2.w);
            h1[4]=(short)f2b(p3.x); h1[5]=(short)f2b(p3.y); h1[6]=(short)f2b(p3.z); h1[7]=(short)f2b(p3.w);
            int c0 = (qg >> 3) ^ (dd & 7);
            int c1 = ((qg >> 3) + 1) ^ (dd & 7);
            *(bf16x8*)(Wt + dd * 128 + c0 * 16) = h0;
            *(bf16x8*)(Wt + dd * 128 + c1 * 16) = h1;
        }
        f32x4 acc[4] = {};
        for (int ss = 0; ss < 8; ss++) {
            if (ss) __syncthreads();
            // stage img tile: Bt[chunk][dd][16B]
            {
                int dd = tid >> 2, sg = tid & 3;
                int d = dt * 64 + dd;
                float4 p0, p1, p2, p3;
                if (d < D_DIM) {
                    const float* src = imgb + (size_t)d * S_DIM + ss * 64 + sg * 16;
                    p0 = *(const float4*)(src);      p1 = *(const float4*)(src + 4);
                    p2 = *(const float4*)(src + 8);  p3 = *(const float4*)(src + 12);
                } else {
                    p0 = p1 = p2 = p3 = make_float4(0.f, 0.f, 0.f, 0.f);
                }
                bf16x8 h0, h1;
                h0[0]=(short)f2b(p0.x); h0[1]=(short)f2b(p0.y); h0[2]=(short)f2b(p0.z); h0[3]=(short)f2b(p0.w);
                h0[4]=(short)f2b(p1.x); h0[5]=(short)f2b(p1.y); h0[6]=(short)f2b(p1.z); h0[7]=(short)f2b(p1.w);
                h1[0]=(short)f2b(p2.x); h1[1]=(short)f2b(p2.y); h1[2]=(short)f2b(p2.z); h1[3]=(short)f2b(p2.w);
                h1[4]=(short)f2b(p3.x); h1[5]=(short)f2b(p3.y); h1[6]=(short)f2b(p3.z); h1[7]=(short)f2b(p3.w);
                int c0 = sg * 2;
                *(bf16x8*)(Bt + c0 * 1024 + dd * 16) = h0;
                *(bf16x8*)(Bt + (c0 + 1) * 1024 + dd * 16) = h1;
            }
            __syncthreads();
            #pragma unroll
            for (int kf = 0; kf < 2; kf++) {
                int q = w * 16 + l15;
                int ks = ss * 64 + kf * 32 + l4 * 8;
                bf16x8 af = *(const bf16x8*)(Ubytes + q * 1024 + ((2 * ks) ^ ((q & 7) << 4)));
                int chunk = kf * 4 + l4;
                #pragma unroll
                for (int nf = 0; nf < 4; nf++) {
                    bf16x8 bfr = *(const bf16x8*)(Bt + chunk * 1024 + (nf * 16 + l15) * 16);
                    acc[nf] = __builtin_amdgcn_mfma_f32_16x16x32_bf16(af, bfr, acc[nf], 0, 0, 0);
                }
            }
        }
        // epilogue: v = wctx * word; write vb bf16; accumulate ssq
        #pragma unroll
        for (int nf = 0; nf < 4; nf++) {
            int dd = nf * 16 + l15;
            int d = dt * 64 + dd;
            #pragma unroll
            for (int r = 0; r < 4; r++) {
                int q = w * 16 + l4 * 4 + r;
                float wctx = acc[nf][r];
                float wv = b2f(*(const u16*)(Wt + dd * 128 + ((((q >> 3) ^ (dd & 7)) << 4)) + (q & 7) * 2));
                float vv = wctx * wv;
                ssq[r] = fmaf(vv, vv, ssq[r]);
                vb[(size_t)q * 1024 + d] = f2b(vv);
            }
        }
    }
    __syncthreads();   // union free; alias invnS
    float* invnS = (float*)unionb;
    #pragma unroll
    for (int r = 0; r < 4; r++) {
        float s = ssq[r];
        #pragma unroll
        for (int mk = 1; mk < 16; mk <<= 1) s += __shfl_xor(s, mk);
        if (l15 == 0) {
            int q = w * 16 + l4 * 4 + r;
            float n = 1.f / (sqrtf(s) + 1e-8f);
            invnS[q] = n;
            invn_ws[pair * 64 + q] = n;
        }
    }
    __syncthreads();

    for (int d = tid; d < D_DIM; d += 256) {
        float s = 0.f;
        for (int q = 0; q < 64; q++) s = fmaf(b2f(vb[(size_t)q * 1024 + d]), invnS[q], s);
        simave_ws[(size_t)pair * D_DIM + d] = s * (1.f / 64.f);
    }
}

// ---------------------------------------------------------------------------
// k_attmap: fp32 recompute of logits+softmax for diagonal pairs (i,i);
// writes UNNORMALIZED u=exp(4*a1) into out att_maps region. 32 blocks.
// ---------------------------------------------------------------------------
__global__ __launch_bounds__(256) void k_attmap(
    const float* __restrict__ img, const float* __restrict__ words, float* __restrict__ out)
{
    const int i = blockIdx.x;
    const float* imgb = img + (size_t)i * D_DIM * S_DIM;
    const float* wrd  = words + (size_t)i * D_DIM * Q_DIM;
    float* am = out + 1024 + (size_t)i * Q_DIM * S_DIM;

    __shared__ float tA[16 * 65], tB[16 * 65];
    const int tid = threadIdx.x;
    const int tx = tid & 15, ty = tid >> 4;

    for (int st = 0; st < 8; st++) {
        float acc[4][4] = {};
        for (int k0 = 0; k0 < D_DIM; k0 += 16) {
            {
                int k = tid >> 4, s4 = (tid & 15) << 2;
                int d = k0 + k;
                float4 v = make_float4(0.f, 0.f, 0.f, 0.f);
                if (d < D_DIM) v = *reinterpret_cast<const float4*>(imgb + (size_t)d * S_DIM + st * 64 + s4);
                tA[k * 65 + s4 + 0] = v.x; tA[k * 65 + s4 + 1] = v.y;
                tA[k * 65 + s4 + 2] = v.z; tA[k * 65 + s4 + 3] = v.w;
            }
            {
                int k = tid >> 4, q4 = (tid & 15) << 2;
                int d = k0 + k;
                float4 v = make_float4(0.f, 0.f, 0.f, 0.f);
                if (d < D_DIM) v = *reinterpret_cast<const float4*>(wrd + (size_t)d * Q_DIM + q4);
                tB[k * 65 + q4 + 0] = v.x; tB[k * 65 + q4 + 1] = v.y;
                tB[k * 65 + q4 + 2] = v.z; tB[k * 65 + q4 + 3] = v.w;
            }
            __syncthreads();
            #pragma unroll
            for (int k = 0; k < 16; k++) {
                float a[4], w4[4];
                #pragma unroll
                for (int j = 0; j < 4; j++) a[j] = tA[k * 65 + ty * 4 + j];
                #pragma unroll
                for (int j = 0; j < 4; j++) w4[j] = tB[k * 65 + tx * 4 + j];
                #pragma unroll
                for (int j = 0; j < 4; j++)
                    #pragma unroll
                    for (int jj = 0; jj < 4; jj++)
                        acc[j][jj] = fmaf(a[j], w4[jj], acc[j][jj]);
            }
            __syncthreads();
        }
        #pragma unroll
        for (int j = 0; j < 4; j++) {
            float m = fmaxf(fmaxf(acc[j][0], acc[j][1]), fmaxf(acc[j][2], acc[j][3]));
            #pragma unroll
            for (int mk = 1; mk < 16; mk <<= 1) m = fmaxf(m, __shfl_xor(m, mk));
            float e[4], ssum = 0.f;
            #pragma unroll
            for (int jj = 0; jj < 4; jj++) { e[jj] = expf(acc[j][jj] - m); ssum += e[jj]; }
            #pragma unroll
            for (int mk = 1; mk < 16; mk <<= 1) ssum += __shfl_xor(ssum, mk);
            float inv = 1.f / ssum;
            int srow = st * 64 + ty * 4 + j;
            #pragma unroll
            for (int jj = 0; jj < 4; jj++) {
                int q = tx * 4 + jj;
                am[(size_t)q * S_DIM + srow] = expf(4.f * e[jj] * inv);
            }
        }
    }
}

// normalize att_maps rows in place: a2 = u / sum_s u
__global__ __launch_bounds__(256) void k_attmap2(float* __restrict__ out)
{
    const int i = blockIdx.x;
    float* am = out + 1024 + (size_t)i * Q_DIM * S_DIM;
    int q = threadIdx.x >> 2, ch = threadIdx.x & 3;
    float s = 0.f;
    for (int ss = ch * 128; ss < ch * 128 + 128; ss++) s += am[(size_t)q * S_DIM + ss];
    s += __shfl_xor(s, 1);
    s += __shfl_xor(s, 2);
    float iz = 1.f / s;
    for (int ss = ch * 128; ss < ch * 128 + 128; ss++) am[(size_t)q * S_DIM + ss] *= iz;
}

// ---------------------------------------------------------------------------
// Kernel D: g2[pair][e] = tanh(simave . wg + bg) * wc  (fp32, 2 GFLOP)
// ---------------------------------------------------------------------------
__global__ __launch_bounds__(256) void k_g2(
    const float* __restrict__ simave, const float* __restrict__ wg,
    const float* __restrict__ bg, const float* __restrict__ wc,
    float* __restrict__ g2)
{
    int mt = blockIdx.x & 15;
    int nt = blockIdx.x >> 4;
    __shared__ float As[16 * 65], Bs[16 * 65];
    int tid = threadIdx.x;
    int tx = tid & 15, ty = tid >> 4;
    int m0 = mt * 64, n0 = nt * 64;
    float acc[4][4] = {};
    for (int k0 = 0; k0 < D_DIM; k0 += 16) {
        {
            int mm = tid >> 2, k4 = (tid & 3) << 2;
            float4 v = make_float4(0.f, 0.f, 0.f, 0.f);
            if (k0 + k4 < D_DIM) v = *reinterpret_cast<const float4*>(simave + (size_t)(m0 + mm) * D_DIM + k0 + k4);
            As[(k4 + 0) * 65 + mm] = v.x; As[(k4 + 1) * 65 + mm] = v.y;
            As[(k4 + 2) * 65 + mm] = v.z; As[(k4 + 3) * 65 + mm] = v.w;
        }
        {
            int k = tid >> 4, n4 = (tid & 15) << 2;
            float4 v = make_float4(0.f, 0.f, 0.f, 0.f);
            if (k0 + k < D_DIM && n0 + n4 < D_DIM)
                v = *reinterpret_cast<const float4*>(wg + (size_t)(k0 + k) * D_DIM + n0 + n4);
            Bs[k * 65 + n4 + 0] = v.x; Bs[k * 65 + n4 + 1] = v.y;
            Bs[k * 65 + n4 + 2] = v.z; Bs[k * 65 + n4 + 3] = v.w;
        }
        __syncthreads();
        #pragma unroll
        for (int k = 0; k < 16; k++) {
            float a[4], bb[4];
            #pragma unroll
            for (int j = 0; j < 4; j++) a[j] = As[k * 65 + ty * 4 + j];
            #pragma unroll
            for (int j = 0; j < 4; j++) bb[j] = Bs[k * 65 + tx * 4 + j];
            #pragma unroll
            for (int j = 0; j < 4; j++)
                #pragma unroll
                for (int jj = 0; jj < 4; jj++)
                    acc[j][jj] = fmaf(a[j], bb[jj], acc[j][jj]);
        }
        __syncthreads();
    }
    #pragma unroll
    for (int j = 0; j < 4; j++) {
        int p = m0 + ty * 4 + j;
        #pragma unroll
        for (int jj = 0; jj < 4; jj++) {
            int e = n0 + tx * 4 + jj;
            if (e < D_DIM) g2[(size_t)p * D_DIM + e] = tanhf(acc[j][jj] + bg[e]) * wc[e];
        }
    }
}

// ---------------------------------------------------------------------------
// Kernel C (MFMA): per pair: acc = vb . wlT^T ; w[q] = sum_e tanh(acc*invn+bl)*g2
//           -> softmax -> new_global -> l2norm -> sigmoid -> out[b*32+i]
// ---------------------------------------------------------------------------
__global__ __launch_bounds__(256) void k_sa(
    const u16* __restrict__ vbuf, const float* __restrict__ invn_ws,
    const float* __restrict__ g2_ws, const u16* __restrict__ wlT,
    const float* __restrict__ bl, const float* __restrict__ capw,
    const float* __restrict__ capb, float* __restrict__ out)
{
    const int pair = blockIdx.x;
    const int i = pair & 31, b = pair >> 5;
    const u16* vb = vbuf + (size_t)pair * 64 * 1024;

    __shared__ char At[8192]  __attribute__((aligned(16)));   // [chunk][q][16B]
    __shared__ char Btl[8192] __attribute__((aligned(16)));   // [chunk][e][16B]
    __shared__ float g2l[1024], bll[1024];
    __shared__ float invnS2[64], wiS[64];
    __shared__ float red[8];

    const int tid = threadIdx.x;
    const int w  = tid >> 6;
    const int l  = tid & 63;
    const int l15 = l & 15, l4 = l >> 4;

    for (int e = tid; e < 1024; e += 256) {
        g2l[e] = (e < D_DIM) ? g2_ws[(size_t)pair * D_DIM + e] : 0.f;
        bll[e] = (e < D_DIM) ? bl[e] : 0.f;
    }
    if (tid < 64) invnS2[tid] = invn_ws[pair * 64 + tid];

    float wacc[4] = {0.f, 0.f, 0.f, 0.f};

    for (int et = 0; et < 16; et++) {
        f32x4 acc[4] = {};
        for (int k0 = 0; k0 < 1024; k0 += 64) {
            __syncthreads();   // also covers initial g2l staging
            {
                int q = tid >> 2, kg = (tid & 3) * 16;
                const u16* src = vb + (size_t)q * 1024 + k0 + kg;
                bf16x8 h0 = *(const bf16x8*)(src);
                bf16x8 h1 = *(const bf16x8*)(src + 8);
                int c0 = (tid & 3) * 2;
                *(bf16x8*)(At + c0 * 1024 + q * 16) = h0;
                *(bf16x8*)(At + (c0 + 1) * 1024 + q * 16) = h1;
            }
            {
                int ee = tid >> 2, kg = (tid & 3) * 16;
                const u16* src = wlT + (size_t)(et * 64 + ee) * 1024 + k0 + kg;
                bf16x8 h0 = *(const bf16x8*)(src);
                bf16x8 h1 = *(const bf16x8*)(src + 8);
                int c0 = (tid & 3) * 2;
                *(bf16x8*)(Btl + c0 * 1024 + ee * 16) = h0;
                *(bf16x8*)(Btl + (c0 + 1) * 1024 + ee * 16) = h1;
            }
            __syncthreads();
            #pragma unroll
            for (int kf = 0; kf < 2; kf++) {
                int chunk = kf * 4 + l4;
                bf16x8 af = *(const bf16x8*)(At + chunk * 1024 + (w * 16 + l15) * 16);
                #pragma unroll
                for (int nf = 0; nf < 4; nf++) {
                    bf16x8 bfr = *(const bf16x8*)(Btl + chunk * 1024 + (nf * 16 + l15) * 16);
                    acc[nf] = __builtin_amdgcn_mfma_f32_16x16x32_bf16(af, bfr, acc[nf], 0, 0, 0);
                }
            }
        }
        #pragma unroll
        for (int nf = 0; nf < 4; nf++) {
            int e = et * 64 + nf * 16 + l15;
            float g2v = g2l[e];
            float blv = bll[e];
            #pragma unroll
            for (int r = 0; r < 4; r++) {
                int q = w * 16 + l4 * 4 + r;
                float x = acc[nf][r] * invnS2[q] + blv;
                wacc[r] += tanhf(x) * g2v;
            }
        }
    }
    #pragma unroll
    for (int r = 0; r < 4; r++) {
        float s = wacc[r];
        #pragma unroll
        for (int mk = 1; mk < 16; mk <<= 1) s += __shfl_xor(s, mk);
        if (l15 == 0) wiS[w * 16 + l4 * 4 + r] = s;
    }
    __syncthreads();
    if (tid < 64) {
        float x = wiS[tid];
        float m = x;
        #pragma unroll
        for (int mk = 1; mk < 64; mk <<= 1) m = fmaxf(m, __shfl_xor(m, mk));
        float e = expf(x - m);
        float Z = e;
        #pragma unroll
        for (int mk = 1; mk < 64; mk <<= 1) Z += __shfl_xor(Z, mk);
        wiS[tid] = (e / Z) * invnS2[tid];
    }
    __syncthreads();

    float s1 = 0.f, s2 = 0.f;
    for (int d = tid; d < D_DIM; d += 256) {
        float ng = 0.f;
        for (int q = 0; q < 64; q++) ng = fmaf(wiS[q], b2f(vb[(size_t)q * 1024 + d]), ng);
        s1 = fmaf(ng, capw[d], s1);
        s2 = fmaf(ng, ng, s2);
    }
    #pragma unroll
    for (int mk = 1; mk < 64; mk <<= 1) { s1 += __shfl_xor(s1, mk); s2 += __shfl_xor(s2, mk); }
    if ((tid & 63) == 0) { red[tid >> 6] = s1; red[4 + (tid >> 6)] = s2; }
    __syncthreads();
    if (tid == 0) {
        float S1 = red[0] + red[1] + red[2] + red[3];
        float S2 = red[4] + red[5] + red[6] + red[7];
        float val = S1 / (sqrtf(S2) + 1e-8f) + capb[0];
        out[b * 32 + i] = 1.f / (1.f + expf(-val));
    }
}

// ---------------------------------------------------------------------------
extern "C" void kernel_launch(void* const* d_in, const int* in_sizes, int n_in,
                              void* d_out, int out_size, void* d_ws, size_t ws_size,
                              hipStream_t stream)
{
    const float* feat_l = (const float*)d_in[0];
    const float* feat_f = (const float*)d_in[1];
    const float* words  = (const float*)d_in[2];
    const float* conv_w = (const float*)d_in[3];
    const float* conv_b = (const float*)d_in[4];
    const float* sa_wl  = (const float*)d_in[5];
    const float* sa_bl  = (const float*)d_in[6];
    const float* sa_wg  = (const float*)d_in[7];
    const float* sa_bg  = (const float*)d_in[8];
    const float* sa_wc  = (const float*)d_in[9];
    // d_in[10] = sa_bc: constant pre-softmax shift -> result-invariant
    const float* cap_w  = (const float*)d_in[11];
    const float* cap_b  = (const float*)d_in[12];
    float* out = (float*)d_out;

    char* ws = (char*)d_ws;
    // ws layout (bytes), total 204,111,872:
    //   img    : [0, 65,536,000)                       fp32 [32][1000][512]
    //   wlT    : [0, 2,097,152)      OVERLAYS img      (written after img's last read)
    //   g2     : [4,194,304, +4,096,000)  OVERLAYS img (written after img's last read)
    //   vbuf   : [65,536,000, +134,217,728)            bf16 [1024][64][1024]
    //   invn   : [199,753,728, +262,144)
    //   simave : [200,015,872, +4,096,000)
    float* img    = (float*)(ws);
    u16*   wlT    = (u16*)(ws);
    float* g2     = (float*)(ws + 4194304);
    u16*   vbuf   = (u16*)(ws + 65536000);
    float* invn   = (float*)(ws + 199753728);
    float* simave = (float*)(ws + 200015872);

    hipLaunchKernelGGL(k_conv, dim3(4096), dim3(256), 0, stream,
                       feat_l, feat_f, conv_w, conv_b, img);
    hipLaunchKernelGGL(k_attn, dim3(1024), dim3(256), 0, stream,
                       img, words, vbuf, invn, simave);
    hipLaunchKernelGGL(k_attmap, dim3(32), dim3(256), 0, stream,
                       img, words, out);
    hipLaunchKernelGGL(k_attmap2, dim3(32), dim3(256), 0, stream, out);
    hipLaunchKernelGGL(k_prep, dim3(256), dim3(256), 0, stream, sa_wl, wlT);
    hipLaunchKernelGGL(k_g2, dim3(256), dim3(256), 0, stream,
                       simave, sa_wg, sa_bg, sa_wc, g2);
    hipLaunchKernelGGL(k_sa, dim3(1024), dim3(256), 0, stream,
                       vbuf, invn, g2, wlT, sa_bl, cap_w, cap_b, out);
}

// Round 3
// 2966.223 us; speedup vs baseline: 2.2143x; 1.2290x over previous
//
#include <hip/hip_runtime.h>
#include <cstdint>

typedef unsigned short u16;
typedef unsigned int   u32;
typedef __attribute__((ext_vector_type(8))) short bf16x8;
typedef __attribute__((ext_vector_type(4))) float f32x4;

#define D_DIM 1000
#define C_IN  1024
#define HW    256
#define S_DIM 512
#define Q_DIM 64

__device__ __forceinline__ u16 f2b(float x) {
    u32 u = __builtin_bit_cast(u32, x);
    u32 r = (u + 0x7FFFu + ((u >> 16) & 1u)) >> 16;
    return (u16)r;
}
__device__ __forceinline__ float b2f(u16 h) {
    u32 u = ((u32)h) << 16;
    return __builtin_bit_cast(float, u);
}
__device__ __forceinline__ float ftanh(float x) {
    float e = __expf(2.f * x);
    return 1.f - 2.f / (e + 1.f);   // x>>0: e=inf -> 1 ; x<<0: e=0 -> -1
}

// ---------------------------------------------------------------------------
// Kernel A: 1x1 conv (fp32 compute), outputs split-bf16 img_hi/img_lo [b][1024][512]
// (d rows 1000..1023 zeroed). grid 32*2*16*4 = 4096 blocks.
// ---------------------------------------------------------------------------
__global__ __launch_bounds__(256) void k_conv(
    const float* __restrict__ feat_l, const float* __restrict__ feat_f,
    const float* __restrict__ cw, const float* __restrict__ cb,
    u16* __restrict__ img_hi, u16* __restrict__ img_lo)
{
    int bid = blockIdx.x;
    int nt = bid & 3;
    int mt = (bid >> 2) & 15;
    int half_ = (bid >> 6) & 1;
    int b = bid >> 7;
    const float* feat = (half_ ? feat_l : feat_f) + (size_t)b * C_IN * HW;

    __shared__ float As[64 * 17];
    __shared__ float Bs[16 * 65];

    int tid = threadIdx.x;
    int tx = tid & 15, ty = tid >> 4;
    int m0 = mt * 64, n0 = nt * 64;

    float acc[4][4] = {};

    for (int k0 = 0; k0 < C_IN; k0 += 16) {
        {
            int mm = tid >> 2, k4 = (tid & 3) << 2;
            int m = m0 + mm;
            float4 v = make_float4(0.f, 0.f, 0.f, 0.f);
            if (m < D_DIM) v = *reinterpret_cast<const float4*>(cw + (size_t)m * C_IN + k0 + k4);
            As[mm * 17 + k4 + 0] = v.x; As[mm * 17 + k4 + 1] = v.y;
            As[mm * 17 + k4 + 2] = v.z; As[mm * 17 + k4 + 3] = v.w;
        }
        {
            int k = tid >> 4, n4 = (tid & 15) << 2;
            float4 v = *reinterpret_cast<const float4*>(feat + (size_t)(k0 + k) * HW + n0 + n4);
            Bs[k * 65 + n4 + 0] = v.x; Bs[k * 65 + n4 + 1] = v.y;
            Bs[k * 65 + n4 + 2] = v.z; Bs[k * 65 + n4 + 3] = v.w;
        }
        __syncthreads();
        #pragma unroll
        for (int k = 0; k < 16; k++) {
            float a[4], bb[4];
            #pragma unroll
            for (int j = 0; j < 4; j++) a[j] = As[(ty * 4 + j) * 17 + k];
            #pragma unroll
            for (int j = 0; j < 4; j++) bb[j] = Bs[k * 65 + tx * 4 + j];
            #pragma unroll
            for (int j = 0; j < 4; j++)
                #pragma unroll
                for (int jj = 0; jj < 4; jj++)
                    acc[j][jj] = fmaf(a[j], bb[jj], acc[j][jj]);
        }
        __syncthreads();
    }
    #pragma unroll
    for (int j = 0; j < 4; j++) {
        int m = m0 + ty * 4 + j;           // 0..1023
        float v4[4] = {0.f, 0.f, 0.f, 0.f};
        if (m < D_DIM) {
            float bias = cb[m];
            #pragma unroll
            for (int jj = 0; jj < 4; jj++) v4[jj] = acc[j][jj] + bias;
        }
        int s = half_ * 256 + n0 + tx * 4;
        ushort4 h, lo;
        u16* ph = (u16*)&h; u16* pl = (u16*)&lo;
        #pragma unroll
        for (int jj = 0; jj < 4; jj++) {
            u16 hh = f2b(v4[jj]);
            ph[jj] = hh;
            pl[jj] = f2b(v4[jj] - b2f(hh));
        }
        size_t off = (size_t)b * 1024 * 512 + (size_t)m * 512 + s;
        *reinterpret_cast<ushort4*>(img_hi + off) = h;
        *reinterpret_cast<ushort4*>(img_lo + off) = lo;
    }
}

// ---------------------------------------------------------------------------
// k_trans: img_hi/lo [b][1024 d][512 s] -> imgT_hi/lo [b][512 s][1024 d]
// grid 32*16*8 = 4096 blocks
// ---------------------------------------------------------------------------
__global__ __launch_bounds__(256) void k_trans(
    const u16* __restrict__ ih, const u16* __restrict__ il,
    u16* __restrict__ oth, u16* __restrict__ otl)
{
    int bid = blockIdx.x;
    int st = bid & 7, dt = (bid >> 3) & 15, b = bid >> 7;
    const u16* srcH = ih + (size_t)b * 1024 * 512;
    const u16* srcL = il + (size_t)b * 1024 * 512;
    u16* dstH = oth + (size_t)b * 512 * 1024;
    u16* dstL = otl + (size_t)b * 512 * 1024;
    __shared__ u16 Th[64][72], Tl[64][72];
    int tid = threadIdx.x;
    #pragma unroll
    for (int rep = 0; rep < 2; rep++) {
        int idx = tid + rep * 256;
        int dl = idx >> 3, c8 = idx & 7;
        size_t so = (size_t)(dt * 64 + dl) * 512 + st * 64 + c8 * 8;
        bf16x8 vh = *(const bf16x8*)(srcH + so);
        bf16x8 vl = *(const bf16x8*)(srcL + so);
        #pragma unroll
        for (int jj = 0; jj < 8; jj++) { Th[c8 * 8 + jj][dl] = (u16)vh[jj]; Tl[c8 * 8 + jj][dl] = (u16)vl[jj]; }
    }
    __syncthreads();
    #pragma unroll
    for (int rep = 0; rep < 2; rep++) {
        int idx = tid + rep * 256;
        int sl = idx >> 3, c8 = idx & 7;
        bf16x8 vh = *(const bf16x8*)(&Th[sl][c8 * 8]);
        bf16x8 vl = *(const bf16x8*)(&Tl[sl][c8 * 8]);
        size_t doff = (size_t)(st * 64 + sl) * 1024 + dt * 64 + c8 * 8;
        *(bf16x8*)(dstH + doff) = vh;
        *(bf16x8*)(dstL + doff) = vl;
    }
}

// ---------------------------------------------------------------------------
// k_prepw: words [i][1000 d][64 q] fp32 -> wT_hi/lo bf16 [i][64 q][1024 d] (pad zero)
// grid 32*16 = 512 blocks
// ---------------------------------------------------------------------------
__global__ __launch_bounds__(256) void k_prepw(
    const float* __restrict__ words, u16* __restrict__ wth, u16* __restrict__ wtl)
{
    int i = blockIdx.x >> 4, dt = blockIdx.x & 15;
    const float* src = words + (size_t)i * D_DIM * Q_DIM;
    __shared__ u16 Th[64][72], Tl[64][72];
    int tid = threadIdx.x;
    #pragma unroll
    for (int rep = 0; rep < 4; rep++) {
        int idx = tid + rep * 256;
        int dl = idx >> 4, q4 = (idx & 15) * 4;
        int d = dt * 64 + dl;
        float4 v = make_float4(0.f, 0.f, 0.f, 0.f);
        if (d < D_DIM) v = *(const float4*)(src + (size_t)d * Q_DIM + q4);
        float a[4] = {v.x, v.y, v.z, v.w};
        #pragma unroll
        for (int jj = 0; jj < 4; jj++) {
            u16 hh = f2b(a[jj]);
            Th[dl][q4 + jj] = hh;
            Tl[dl][q4 + jj] = f2b(a[jj] - b2f(hh));
        }
    }
    __syncthreads();
    #pragma unroll
    for (int rep = 0; rep < 2; rep++) {
        int idx = tid + rep * 256;
        int q = idx >> 3, c8 = idx & 7;
        bf16x8 vh, vl;
        #pragma unroll
        for (int jj = 0; jj < 8; jj++) { vh[jj] = (short)Th[c8 * 8 + jj][q]; vl[jj] = (short)Tl[c8 * 8 + jj][q]; }
        size_t doff = (size_t)i * 65536 + (size_t)q * 1024 + dt * 64 + c8 * 8;
        *(bf16x8*)(wth + doff) = vh;
        *(bf16x8*)(wtl + doff) = vl;
    }
}

// ---------------------------------------------------------------------------
// Kernel B: per (i,b) pair.
// Stage1: split-bf16 MFMA logits^T[q][s] (hi*hi+hi*lo+lo*hi), softmax over q in-reg,
//         U[q][s]=bf16(exp(4*a1)) to LDS (xor-swz); diag pairs write u fp32 to out.
// Stage2: Z_q, rescale U *= 1/Z.
// Stage3: MFMA wctx = U . img_hi^T (B streamed from global), v = wctx*word -> vbuf,
//         invn, simave.
// LDS: U 65536 + Wt 8192 + zred 1024 + invnS 256 = 75 KB (2 blocks/CU)
// ---------------------------------------------------------------------------
__global__ __launch_bounds__(256) void k_attn(
    const u16* __restrict__ imgT_hi, const u16* __restrict__ imgT_lo,
    const u16* __restrict__ img_hi,
    const u16* __restrict__ wT_hi, const u16* __restrict__ wT_lo,
    const float* __restrict__ words,
    u16* __restrict__ vbuf, float* __restrict__ invn_ws,
    float* __restrict__ simave_ws, float* __restrict__ out)
{
    const int pair = blockIdx.x;
    const int i = pair & 31, b = pair >> 5;
    const u16* iTh = imgT_hi + (size_t)b * 512 * 1024;
    const u16* iTl = imgT_lo + (size_t)b * 512 * 1024;
    const u16* iH  = img_hi  + (size_t)b * 1024 * 512;
    const u16* wTh = wT_hi + (size_t)i * 65536;
    const u16* wTl = wT_lo + (size_t)i * 65536;
    const float* wrd = words + (size_t)i * D_DIM * Q_DIM;
    u16* vb = vbuf + (size_t)pair * 64 * 1024;

    __shared__ char Ubytes[65536] __attribute__((aligned(16)));
    __shared__ char Wt[8192] __attribute__((aligned(16)));
    __shared__ float zred[256];
    __shared__ float invnS[64];

    const int tid = threadIdx.x;
    const int w = tid >> 6, l = tid & 63;
    const int l15 = l & 15, l4 = l >> 4;

    // ---- Stage 1: logits^T[q][s], M=q(4 frags), N=s(wave w: s in [w*128, w*128+128))
    {
        f32x4 acc[4][8] = {};
        for (int k0 = 0; k0 < 1024; k0 += 32) {
            bf16x8 ah[4], al[4];
            #pragma unroll
            for (int mf = 0; mf < 4; mf++) {
                int q = mf * 16 + l15;
                ah[mf] = *(const bf16x8*)(wTh + (size_t)q * 1024 + k0 + l4 * 8);
                al[mf] = *(const bf16x8*)(wTl + (size_t)q * 1024 + k0 + l4 * 8);
            }
            #pragma unroll
            for (int nf = 0; nf < 8; nf++) {
                int s = w * 128 + nf * 16 + l15;
                bf16x8 bh = *(const bf16x8*)(iTh + (size_t)s * 1024 + k0 + l4 * 8);
                bf16x8 blo = *(const bf16x8*)(iTl + (size_t)s * 1024 + k0 + l4 * 8);
                #pragma unroll
                for (int mf = 0; mf < 4; mf++)
                    acc[mf][nf] = __builtin_amdgcn_mfma_f32_16x16x32_bf16(ah[mf], bh, acc[mf][nf], 0, 0, 0);
                #pragma unroll
                for (int mf = 0; mf < 4; mf++)
                    acc[mf][nf] = __builtin_amdgcn_mfma_f32_16x16x32_bf16(al[mf], bh, acc[mf][nf], 0, 0, 0);
                #pragma unroll
                for (int mf = 0; mf < 4; mf++)
                    acc[mf][nf] = __builtin_amdgcn_mfma_f32_16x16x32_bf16(ah[mf], blo, acc[mf][nf], 0, 0, 0);
            }
        }
        // epilogue: softmax over q (lane-local 16 + shfl over lane bits 4,5), U + diag u
        const bool diag = (i == b);
        float* am = out + 1024 + (size_t)i * Q_DIM * S_DIM;
        #pragma unroll
        for (int nf = 0; nf < 8; nf++) {
            int s = w * 128 + nf * 16 + l15;
            float m = -3.4e38f;
            #pragma unroll
            for (int mf = 0; mf < 4; mf++)
                #pragma unroll
                for (int r = 0; r < 4; r++) m = fmaxf(m, acc[mf][nf][r]);
            m = fmaxf(m, __shfl_xor(m, 16));
            m = fmaxf(m, __shfl_xor(m, 32));
            float e[16], sum = 0.f;
            #pragma unroll
            for (int mf = 0; mf < 4; mf++)
                #pragma unroll
                for (int r = 0; r < 4; r++) {
                    float ev = __expf(acc[mf][nf][r] - m);
                    e[mf * 4 + r] = ev; sum += ev;
                }
            sum += __shfl_xor(sum, 16);
            sum += __shfl_xor(sum, 32);
            float inv = 1.f / sum;
            #pragma unroll
            for (int mf = 0; mf < 4; mf++)
                #pragma unroll
                for (int r = 0; r < 4; r++) {
                    int q = mf * 16 + l4 * 4 + r;
                    float u = __expf(4.f * e[mf * 4 + r] * inv);   // exp(TEMP1*a1) in [1,e^4]
                    *(u16*)(Ubytes + q * 1024 + ((2 * s) ^ ((q & 7) << 4))) = f2b(u);
                    if (diag) am[(size_t)q * S_DIM + s] = u;
                }
        }
    }
    __syncthreads();

    // ---- Stage 2: Z_q and rescale
    {
        int q = tid & 63, ch = tid >> 6;
        float zp = 0.f;
        for (int s = ch * 128; s < ch * 128 + 128; s++)
            zp += b2f(*(const u16*)(Ubytes + q * 1024 + ((2 * s) ^ ((q & 7) << 4))));
        zred[ch * 64 + q] = zp;
        __syncthreads();
        float Z = zred[q] + zred[64 + q] + zred[128 + q] + zred[192 + q];
        float iz = 1.f / Z;
        for (int s = ch * 128; s < ch * 128 + 128; s++) {
            u16* p = (u16*)(Ubytes + q * 1024 + ((2 * s) ^ ((q & 7) << 4)));
            *p = f2b(b2f(*p) * iz);
        }
    }

    // ---- Stage 3: wctx[q,d] = sum_s a2[q,s]*img[d,s]; B streamed from img_hi
    float ssq[4] = {0.f, 0.f, 0.f, 0.f};
    for (int dt = 0; dt < 16; dt++) {
        __syncthreads();   // Wt reuse (and stage2 visibility on dt=0)
        {
            int dd = tid >> 2, qg = (tid & 3) * 16;
            int d = dt * 64 + dd;
            float4 p0, p1, p2, p3;
            if (d < D_DIM) {
                const float* src = wrd + (size_t)d * Q_DIM + qg;
                p0 = *(const float4*)(src);      p1 = *(const float4*)(src + 4);
                p2 = *(const float4*)(src + 8);  p3 = *(const float4*)(src + 12);
            } else {
                p0 = p1 = p2 = p3 = make_float4(0.f, 0.f, 0.f, 0.f);
            }
            bf16x8 h0, h1;
            h0[0]=(short)f2b(p0.x); h0[1]=(short)f2b(p0.y); h0[2]=(short)f2b(p0.z); h0[3]=(short)f2b(p0.w);
            h0[4]=(short)f2b(p1.x); h0[5]=(short)f2b(p1.y); h0[6]=(short)f2b(p1.z); h0[7]=(short)f2b(p1.w);
            h1[0]=(short)f2b(p2.x); h1[1]=(short)f2b(p2.y); h1[2]=(short)f2b(p2.z); h1[3]=(short)f2b(p2.w);
            h1[4]=(short)f2b(p3.x); h1[5]=(short)f2b(p3.y); h1[6]=(short)f2b(p3.z); h1[7]=(short)f2b(p3.w);
            int c0 = (qg >> 3) ^ (dd & 7);
            int c1 = ((qg >> 3) + 1) ^ (dd & 7);
            *(bf16x8*)(Wt + dd * 128 + c0 * 16) = h0;
            *(bf16x8*)(Wt + dd * 128 + c1 * 16) = h1;
        }
        __syncthreads();
        f32x4 acc[4] = {};
        #pragma unroll
        for (int ss = 0; ss < 8; ss++) {
            #pragma unroll
            for (int kf = 0; kf < 2; kf++) {
                int q = w * 16 + l15;
                int ks = ss * 64 + kf * 32 + l4 * 8;
                bf16x8 af = *(const bf16x8*)(Ubytes + q * 1024 + ((2 * ks) ^ ((q & 7) << 4)));
                #pragma unroll
                for (int nf = 0; nf < 4; nf++) {
                    int d = dt * 64 + nf * 16 + l15;
                    bf16x8 bfr = *(const bf16x8*)(iH + (size_t)d * 512 + ks);
                    acc[nf] = __builtin_amdgcn_mfma_f32_16x16x32_bf16(af, bfr, acc[nf], 0, 0, 0);
                }
            }
        }
        #pragma unroll
        for (int nf = 0; nf < 4; nf++) {
            int dd = nf * 16 + l15;
            int d = dt * 64 + dd;
            #pragma unroll
            for (int r = 0; r < 4; r++) {
                int q = w * 16 + l4 * 4 + r;
                float wctx = acc[nf][r];
                float wv = b2f(*(const u16*)(Wt + dd * 128 + ((((q >> 3) ^ (dd & 7)) << 4)) + (q & 7) * 2));
                float vv = wctx * wv;
                ssq[r] = fmaf(vv, vv, ssq[r]);
                if (d < D_DIM) vb[(size_t)q * 1024 + d] = f2b(vv);
            }
        }
    }
    __syncthreads();
    #pragma unroll
    for (int r = 0; r < 4; r++) {
        float s = ssq[r];
        #pragma unroll
        for (int mk = 1; mk < 16; mk <<= 1) s += __shfl_xor(s, mk);
        if (l15 == 0) {
            int q = w * 16 + l4 * 4 + r;
            float n = 1.f / (sqrtf(s) + 1e-8f);
            invnS[q] = n;
            invn_ws[pair * 64 + q] = n;
        }
    }
    __syncthreads();

    for (int d = tid; d < D_DIM; d += 256) {
        float s = 0.f;
        for (int q = 0; q < 64; q++) s = fmaf(b2f(vb[(size_t)q * 1024 + d]), invnS[q], s);
        simave_ws[(size_t)pair * D_DIM + d] = s * (1.f / 64.f);
    }
}

// normalize att_maps rows in place: a2 = u / sum_s u.  32 blocks.
__global__ __launch_bounds__(256) void k_attmap2(float* __restrict__ out)
{
    const int i = blockIdx.x;
    float* am = out + 1024 + (size_t)i * Q_DIM * S_DIM;
    int q = threadIdx.x >> 2, ch = threadIdx.x & 3;
    float s = 0.f;
    for (int ss = ch * 128; ss < ch * 128 + 128; ss++) s += am[(size_t)q * S_DIM + ss];
    s += __shfl_xor(s, 1);
    s += __shfl_xor(s, 2);
    float iz = 1.f / s;
    for (int ss = ch * 128; ss < ch * 128 + 128; ss++) am[(size_t)q * S_DIM + ss] *= iz;
}

// ---------------------------------------------------------------------------
// k_prep: wlT_bf16[e][d] = bf16(wl[d][e]); [1024][1024], zero-padded. 256 blocks.
// ---------------------------------------------------------------------------
__global__ __launch_bounds__(256) void k_prep(const float* __restrict__ wl, u16* __restrict__ wlT)
{
    __shared__ float t[64][65];
    int bd = blockIdx.x & 15, be = blockIdx.x >> 4;
    int tx = threadIdx.x & 15, ty = threadIdx.x >> 4;
    #pragma unroll
    for (int rr = 0; rr < 4; rr++) {
        int r = ty * 4 + rr;
        int d = bd * 64 + r;
        int e4 = be * 64 + tx * 4;
        float v0 = 0.f, v1 = 0.f, v2 = 0.f, v3 = 0.f;
        if (d < D_DIM) {
            if (e4 + 3 < D_DIM) {
                float4 v = *reinterpret_cast<const float4*>(wl + (size_t)d * D_DIM + e4);
                v0 = v.x; v1 = v.y; v2 = v.z; v3 = v.w;
            } else {
                if (e4 + 0 < D_DIM) v0 = wl[(size_t)d * D_DIM + e4 + 0];
                if (e4 + 1 < D_DIM) v1 = wl[(size_t)d * D_DIM + e4 + 1];
                if (e4 + 2 < D_DIM) v2 = wl[(size_t)d * D_DIM + e4 + 2];
                if (e4 + 3 < D_DIM) v3 = wl[(size_t)d * D_DIM + e4 + 3];
            }
        }
        t[r][tx * 4 + 0] = v0; t[r][tx * 4 + 1] = v1;
        t[r][tx * 4 + 2] = v2; t[r][tx * 4 + 3] = v3;
    }
    __syncthreads();
    #pragma unroll
    for (int rr = 0; rr < 4; rr++) {
        int r2 = ty * 4 + rr;          // e within tile
        int e = be * 64 + r2;
        int d0 = bd * 64 + tx * 4;
        ushort4 h;
        h.x = f2b(t[tx * 4 + 0][r2]); h.y = f2b(t[tx * 4 + 1][r2]);
        h.z = f2b(t[tx * 4 + 2][r2]); h.w = f2b(t[tx * 4 + 3][r2]);
        *reinterpret_cast<ushort4*>(wlT + (size_t)e * 1024 + d0) = h;
    }
}

// ---------------------------------------------------------------------------
// Kernel D: g2[pair][e] = tanh(simave . wg + bg) * wc  (fp32, 2 GFLOP)
// ---------------------------------------------------------------------------
__global__ __launch_bounds__(256) void k_g2(
    const float* __restrict__ simave, const float* __restrict__ wg,
    const float* __restrict__ bg, const float* __restrict__ wc,
    float* __restrict__ g2)
{
    int mt = blockIdx.x & 15;
    int nt = blockIdx.x >> 4;
    __shared__ float As[16 * 65], Bs[16 * 65];
    int tid = threadIdx.x;
    int tx = tid & 15, ty = tid >> 4;
    int m0 = mt * 64, n0 = nt * 64;
    float acc[4][4] = {};
    for (int k0 = 0; k0 < D_DIM; k0 += 16) {
        {
            int mm = tid >> 2, k4 = (tid & 3) << 2;
            float4 v = make_float4(0.f, 0.f, 0.f, 0.f);
            if (k0 + k4 < D_DIM) v = *reinterpret_cast<const float4*>(simave + (size_t)(m0 + mm) * D_DIM + k0 + k4);
            As[(k4 + 0) * 65 + mm] = v.x; As[(k4 + 1) * 65 + mm] = v.y;
            As[(k4 + 2) * 65 + mm] = v.z; As[(k4 + 3) * 65 + mm] = v.w;
        }
        {
            int k = tid >> 4, n4 = (tid & 15) << 2;
            float4 v = make_float4(0.f, 0.f, 0.f, 0.f);
            if (k0 + k < D_DIM && n0 + n4 < D_DIM)
                v = *reinterpret_cast<const float4*>(wg + (size_t)(k0 + k) * D_DIM + n0 + n4);
            Bs[k * 65 + n4 + 0] = v.x; Bs[k * 65 + n4 + 1] = v.y;
            Bs[k * 65 + n4 + 2] = v.z; Bs[k * 65 + n4 + 3] = v.w;
        }
        __syncthreads();
        #pragma unroll
        for (int k = 0; k < 16; k++) {
            float a[4], bb[4];
            #pragma unroll
            for (int j = 0; j < 4; j++) a[j] = As[k * 65 + ty * 4 + j];
            #pragma unroll
            for (int j = 0; j < 4; j++) bb[j] = Bs[k * 65 + tx * 4 + j];
            #pragma unroll
            for (int j = 0; j < 4; j++)
                #pragma unroll
                for (int jj = 0; jj < 4; jj++)
                    acc[j][jj] = fmaf(a[j], bb[jj], acc[j][jj]);
        }
        __syncthreads();
    }
    #pragma unroll
    for (int j = 0; j < 4; j++) {
        int p = m0 + ty * 4 + j;
        #pragma unroll
        for (int jj = 0; jj < 4; jj++) {
            int e = n0 + tx * 4 + jj;
            if (e < D_DIM) g2[(size_t)p * D_DIM + e] = tanhf(acc[j][jj] + bg[e]) * wc[e];
        }
    }
}

// ---------------------------------------------------------------------------
// Kernel C: per pair, both GEMM operands streamed from global (K-major), no
// K-loop barriers. w[q] = sum_e tanh(acc*invn+bl)*g2 -> softmax -> new_global
// -> l2norm -> sigmoid.
// ---------------------------------------------------------------------------
__global__ __launch_bounds__(256) void k_sa(
    const u16* __restrict__ vbuf, const float* __restrict__ invn_ws,
    const float* __restrict__ g2_ws, const u16* __restrict__ wlT,
    const float* __restrict__ bl, const float* __restrict__ capw,
    const float* __restrict__ capb, float* __restrict__ out)
{
    const int pair = blockIdx.x;
    const int i = pair & 31, b = pair >> 5;
    const u16* vb = vbuf + (size_t)pair * 64 * 1024;

    __shared__ float g2l[1024], bll[1024];
    __shared__ float invnS2[64], wiS[64];
    __shared__ float red[8];

    const int tid = threadIdx.x;
    const int w = tid >> 6, l = tid & 63;
    const int l15 = l & 15, l4 = l >> 4;

    for (int e = tid; e < 1024; e += 256) {
        g2l[e] = (e < D_DIM) ? g2_ws[(size_t)pair * D_DIM + e] : 0.f;
        bll[e] = (e < D_DIM) ? bl[e] : 0.f;
    }
    if (tid < 64) invnS2[tid] = invn_ws[pair * 64 + tid];
    __syncthreads();

    float wacc[4] = {0.f, 0.f, 0.f, 0.f};
    for (int et = 0; et < 16; et++) {
        f32x4 acc[4] = {};
        for (int k0 = 0; k0 < 1024; k0 += 32) {
            bf16x8 af = *(const bf16x8*)(vb + (size_t)(w * 16 + l15) * 1024 + k0 + l4 * 8);
            #pragma unroll
            for (int nf = 0; nf < 4; nf++) {
                bf16x8 bfr = *(const bf16x8*)(wlT + (size_t)(et * 64 + nf * 16 + l15) * 1024 + k0 + l4 * 8);
                acc[nf] = __builtin_amdgcn_mfma_f32_16x16x32_bf16(af, bfr, acc[nf], 0, 0, 0);
            }
        }
        #pragma unroll
        for (int nf = 0; nf < 4; nf++) {
            int e = et * 64 + nf * 16 + l15;   // e>=1000: acc=0 (wlT pad 0), g2l=0
            float g2v = g2l[e], blv = bll[e];
            #pragma unroll
            for (int r = 0; r < 4; r++) {
                int q = w * 16 + l4 * 4 + r;
                wacc[r] += ftanh(acc[nf][r] * invnS2[q] + blv) * g2v;
            }
        }
    }
    #pragma unroll
    for (int r = 0; r < 4; r++) {
        float s = wacc[r];
        #pragma unroll
        for (int mk = 1; mk < 16; mk <<= 1) s += __shfl_xor(s, mk);
        if (l15 == 0) wiS[w * 16 + l4 * 4 + r] = s;
    }
    __syncthreads();
    if (tid < 64) {
        float x = wiS[tid];
        float m = x;
        #pragma unroll
        for (int mk = 1; mk < 64; mk <<= 1) m = fmaxf(m, __shfl_xor(m, mk));
        float e = __expf(x - m);
        float Z = e;
        #pragma unroll
        for (int mk = 1; mk < 64; mk <<= 1) Z += __shfl_xor(Z, mk);
        wiS[tid] = (e / Z) * invnS2[tid];
    }
    __syncthreads();

    float s1 = 0.f, s2 = 0.f;
    for (int d = tid; d < D_DIM; d += 256) {
        float ng = 0.f;
        for (int q = 0; q < 64; q++) ng = fmaf(wiS[q], b2f(vb[(size_t)q * 1024 + d]), ng);
        s1 = fmaf(ng, capw[d], s1);
        s2 = fmaf(ng, ng, s2);
    }
    #pragma unroll
    for (int mk = 1; mk < 64; mk <<= 1) { s1 += __shfl_xor(s1, mk); s2 += __shfl_xor(s2, mk); }
    if ((tid & 63) == 0) { red[tid >> 6] = s1; red[4 + (tid >> 6)] = s2; }
    __syncthreads();
    if (tid == 0) {
        float S1 = red[0] + red[1] + red[2] + red[3];
        float S2 = red[4] + red[5] + red[6] + red[7];
        float val = S1 / (sqrtf(S2) + 1e-8f) + capb[0];
        out[b * 32 + i] = 1.f / (1.f + __expf(-val));
    }
}

// ---------------------------------------------------------------------------
extern "C" void kernel_launch(void* const* d_in, const int* in_sizes, int n_in,
                              void* d_out, int out_size, void* d_ws, size_t ws_size,
                              hipStream_t stream)
{
    const float* feat_l = (const float*)d_in[0];
    const float* feat_f = (const float*)d_in[1];
    const float* words  = (const float*)d_in[2];
    const float* conv_w = (const float*)d_in[3];
    const float* conv_b = (const float*)d_in[4];
    const float* sa_wl  = (const float*)d_in[5];
    const float* sa_bl  = (const float*)d_in[6];
    const float* sa_wg  = (const float*)d_in[7];
    const float* sa_bg  = (const float*)d_in[8];
    const float* sa_wc  = (const float*)d_in[9];
    // d_in[10] = sa_bc: constant pre-softmax shift -> result-invariant
    const float* cap_w  = (const float*)d_in[11];
    const float* cap_b  = (const float*)d_in[12];
    float* out = (float*)d_out;

    char* ws = (char*)d_ws;
    // ws layout (bytes), total ~253.8 MB:
    //   vbuf    : [0, 134,217,728)          bf16 [1024][64][1024]
    //   img_lo  : [0, 33,554,432)           OVERLAYS vbuf head (dead before attn)
    //   img_hi  : [134,217,728, +33,554,432) bf16 [32][1024][512]
    //   imgT_hi : [167,772,160, +33,554,432) bf16 [32][512][1024]
    //   imgT_lo : [201,326,592, +33,554,432)
    //   wT_hi   : [234,881,024, +4,194,304)  bf16 [32][64][1024]
    //   wT_lo   : [239,075,328, +4,194,304)
    //   wlT     : [243,269,632, +2,097,152)  bf16 [1024][1024]
    //   g2      : [245,366,784, +4,096,000)  f32 [1024][1000]
    //   invn    : [249,462,784, +262,144)
    //   simave  : [249,724,928, +4,096,000)
    u16*   img_lo  = (u16*)(ws);
    u16*   vbuf    = (u16*)(ws);
    u16*   img_hi  = (u16*)(ws + 134217728);
    u16*   imgT_hi = (u16*)(ws + 167772160);
    u16*   imgT_lo = (u16*)(ws + 201326592);
    u16*   wT_hi   = (u16*)(ws + 234881024);
    u16*   wT_lo   = (u16*)(ws + 239075328);
    u16*   wlT     = (u16*)(ws + 243269632);
    float* g2      = (float*)(ws + 245366784);
    float* invn    = (float*)(ws + 249462784);
    float* simave  = (float*)(ws + 249724928);

    hipLaunchKernelGGL(k_conv, dim3(4096), dim3(256), 0, stream,
                       feat_l, feat_f, conv_w, conv_b, img_hi, img_lo);
    hipLaunchKernelGGL(k_trans, dim3(4096), dim3(256), 0, stream,
                       img_hi, img_lo, imgT_hi, imgT_lo);
    hipLaunchKernelGGL(k_prepw, dim3(512), dim3(256), 0, stream,
                       words, wT_hi, wT_lo);
    hipLaunchKernelGGL(k_prep, dim3(256), dim3(256), 0, stream, sa_wl, wlT);
    hipLaunchKernelGGL(k_attn, dim3(1024), dim3(256), 0, stream,
                       imgT_hi, imgT_lo, img_hi, wT_hi, wT_lo, words,
                       vbuf, invn, simave, out);
    hipLaunchKernelGGL(k_attmap2, dim3(32), dim3(256), 0, stream, out);
    hipLaunchKernelGGL(k_g2, dim3(256), dim3(256), 0, stream,
                       simave, sa_wg, sa_bg, sa_wc, g2);
    hipLaunchKernelGGL(k_sa, dim3(1024), dim3(256), 0, stream,
                       vbuf, invn, g2, wlT, sa_bl, cap_w, cap_b, out);
}

// Round 4
// 2074.100 us; speedup vs baseline: 3.1667x; 1.4301x over previous
//
#include <hip/hip_runtime.h>
#include <cstdint>

typedef unsigned short u16;
typedef unsigned int   u32;
typedef __attribute__((ext_vector_type(8))) short bf16x8;
typedef __attribute__((ext_vector_type(4))) float f32x4;

#define D_DIM 1000
#define C_IN  1024
#define HW    256
#define S_DIM 512
#define Q_DIM 64

__device__ __forceinline__ u16 f2b(float x) {
    u32 u = __builtin_bit_cast(u32, x);
    u32 r = (u + 0x7FFFu + ((u >> 16) & 1u)) >> 16;
    return (u16)r;
}
__device__ __forceinline__ float b2f(u16 h) {
    u32 u = ((u32)h) << 16;
    return __builtin_bit_cast(float, u);
}
__device__ __forceinline__ float ftanh(float x) {
    float e = __expf(2.f * x);
    return 1.f - 2.f / (e + 1.f);   // x>>0: e=inf -> 1 ; x<<0: e=0 -> -1
}

#define GLOAD(ldsptr, gptr) \
    __builtin_amdgcn_global_load_lds( \
        (const __attribute__((address_space(1))) unsigned int*)(gptr), \
        (__attribute__((address_space(3))) unsigned int*)(ldsptr), 16, 0, 0)

// ---------------------------------------------------------------------------
// Kernel A: 1x1 conv (fp32 compute), outputs split-bf16 img_hi/img_lo [b][1024][512]
// ---------------------------------------------------------------------------
__global__ __launch_bounds__(256) void k_conv(
    const float* __restrict__ feat_l, const float* __restrict__ feat_f,
    const float* __restrict__ cw, const float* __restrict__ cb,
    u16* __restrict__ img_hi, u16* __restrict__ img_lo)
{
    int bid = blockIdx.x;
    int nt = bid & 3;
    int mt = (bid >> 2) & 15;
    int half_ = (bid >> 6) & 1;
    int b = bid >> 7;
    const float* feat = (half_ ? feat_l : feat_f) + (size_t)b * C_IN * HW;

    __shared__ float As[64 * 17];
    __shared__ float Bs[16 * 65];

    int tid = threadIdx.x;
    int tx = tid & 15, ty = tid >> 4;
    int m0 = mt * 64, n0 = nt * 64;

    float acc[4][4] = {};

    for (int k0 = 0; k0 < C_IN; k0 += 16) {
        {
            int mm = tid >> 2, k4 = (tid & 3) << 2;
            int m = m0 + mm;
            float4 v = make_float4(0.f, 0.f, 0.f, 0.f);
            if (m < D_DIM) v = *reinterpret_cast<const float4*>(cw + (size_t)m * C_IN + k0 + k4);
            As[mm * 17 + k4 + 0] = v.x; As[mm * 17 + k4 + 1] = v.y;
            As[mm * 17 + k4 + 2] = v.z; As[mm * 17 + k4 + 3] = v.w;
        }
        {
            int k = tid >> 4, n4 = (tid & 15) << 2;
            float4 v = *reinterpret_cast<const float4*>(feat + (size_t)(k0 + k) * HW + n0 + n4);
            Bs[k * 65 + n4 + 0] = v.x; Bs[k * 65 + n4 + 1] = v.y;
            Bs[k * 65 + n4 + 2] = v.z; Bs[k * 65 + n4 + 3] = v.w;
        }
        __syncthreads();
        #pragma unroll
        for (int k = 0; k < 16; k++) {
            float a[4], bb[4];
            #pragma unroll
            for (int j = 0; j < 4; j++) a[j] = As[(ty * 4 + j) * 17 + k];
            #pragma unroll
            for (int j = 0; j < 4; j++) bb[j] = Bs[k * 65 + tx * 4 + j];
            #pragma unroll
            for (int j = 0; j < 4; j++)
                #pragma unroll
                for (int jj = 0; jj < 4; jj++)
                    acc[j][jj] = fmaf(a[j], bb[jj], acc[j][jj]);
        }
        __syncthreads();
    }
    #pragma unroll
    for (int j = 0; j < 4; j++) {
        int m = m0 + ty * 4 + j;           // 0..1023
        float v4[4] = {0.f, 0.f, 0.f, 0.f};
        if (m < D_DIM) {
            float bias = cb[m];
            #pragma unroll
            for (int jj = 0; jj < 4; jj++) v4[jj] = acc[j][jj] + bias;
        }
        int s = half_ * 256 + n0 + tx * 4;
        ushort4 h, lo;
        u16* ph = (u16*)&h; u16* pl = (u16*)&lo;
        #pragma unroll
        for (int jj = 0; jj < 4; jj++) {
            u16 hh = f2b(v4[jj]);
            ph[jj] = hh;
            pl[jj] = f2b(v4[jj] - b2f(hh));
        }
        size_t off = (size_t)b * 1024 * 512 + (size_t)m * 512 + s;
        *reinterpret_cast<ushort4*>(img_hi + off) = h;
        *reinterpret_cast<ushort4*>(img_lo + off) = lo;
    }
}

// ---------------------------------------------------------------------------
// k_trans: img_hi/lo [b][1024 d][512 s] -> imgT_hi/lo [b][512 s][1024 d]
// ---------------------------------------------------------------------------
__global__ __launch_bounds__(256) void k_trans(
    const u16* __restrict__ ih, const u16* __restrict__ il,
    u16* __restrict__ oth, u16* __restrict__ otl)
{
    int bid = blockIdx.x;
    int st = bid & 7, dt = (bid >> 3) & 15, b = bid >> 7;
    const u16* srcH = ih + (size_t)b * 1024 * 512;
    const u16* srcL = il + (size_t)b * 1024 * 512;
    u16* dstH = oth + (size_t)b * 512 * 1024;
    u16* dstL = otl + (size_t)b * 512 * 1024;
    __shared__ u16 Th[64][72], Tl[64][72];
    int tid = threadIdx.x;
    #pragma unroll
    for (int rep = 0; rep < 2; rep++) {
        int idx = tid + rep * 256;
        int dl = idx >> 3, c8 = idx & 7;
        size_t so = (size_t)(dt * 64 + dl) * 512 + st * 64 + c8 * 8;
        bf16x8 vh = *(const bf16x8*)(srcH + so);
        bf16x8 vl = *(const bf16x8*)(srcL + so);
        #pragma unroll
        for (int jj = 0; jj < 8; jj++) { Th[c8 * 8 + jj][dl] = (u16)vh[jj]; Tl[c8 * 8 + jj][dl] = (u16)vl[jj]; }
    }
    __syncthreads();
    #pragma unroll
    for (int rep = 0; rep < 2; rep++) {
        int idx = tid + rep * 256;
        int sl = idx >> 3, c8 = idx & 7;
        bf16x8 vh = *(const bf16x8*)(&Th[sl][c8 * 8]);
        bf16x8 vl = *(const bf16x8*)(&Tl[sl][c8 * 8]);
        size_t doff = (size_t)(st * 64 + sl) * 1024 + dt * 64 + c8 * 8;
        *(bf16x8*)(dstH + doff) = vh;
        *(bf16x8*)(dstL + doff) = vl;
    }
}

// ---------------------------------------------------------------------------
// k_prepw: words [i][1000 d][64 q] fp32 -> wT_hi/lo bf16 [i][64 q][1024 d]
// ---------------------------------------------------------------------------
__global__ __launch_bounds__(256) void k_prepw(
    const float* __restrict__ words, u16* __restrict__ wth, u16* __restrict__ wtl)
{
    int i = blockIdx.x >> 4, dt = blockIdx.x & 15;
    const float* src = words + (size_t)i * D_DIM * Q_DIM;
    __shared__ u16 Th[64][72], Tl[64][72];
    int tid = threadIdx.x;
    #pragma unroll
    for (int rep = 0; rep < 4; rep++) {
        int idx = tid + rep * 256;
        int dl = idx >> 4, q4 = (idx & 15) * 4;
        int d = dt * 64 + dl;
        float4 v = make_float4(0.f, 0.f, 0.f, 0.f);
        if (d < D_DIM) v = *(const float4*)(src + (size_t)d * Q_DIM + q4);
        float a[4] = {v.x, v.y, v.z, v.w};
        #pragma unroll
        for (int jj = 0; jj < 4; jj++) {
            u16 hh = f2b(a[jj]);
            Th[dl][q4 + jj] = hh;
            Tl[dl][q4 + jj] = f2b(a[jj] - b2f(hh));
        }
    }
    __syncthreads();
    #pragma unroll
    for (int rep = 0; rep < 2; rep++) {
        int idx = tid + rep * 256;
        int q = idx >> 3, c8 = idx & 7;
        bf16x8 vh, vl;
        #pragma unroll
        for (int jj = 0; jj < 8; jj++) { vh[jj] = (short)Th[c8 * 8 + jj][q]; vl[jj] = (short)Tl[c8 * 8 + jj][q]; }
        size_t doff = (size_t)i * 65536 + (size_t)q * 1024 + dt * 64 + c8 * 8;
        *(bf16x8*)(wth + doff) = vh;
        *(bf16x8*)(wtl + doff) = vl;
    }
}

// ---------------------------------------------------------------------------
// Kernel B: per (i,b) pair. Stage1 split-bf16 MFMA logits + softmax -> U;
// Stage2 Z; Stage3 MFMA wctx -> vbuf, invn, simave. (unchanged from R3)
// ---------------------------------------------------------------------------
__global__ __launch_bounds__(256) void k_attn(
    const u16* __restrict__ imgT_hi, const u16* __restrict__ imgT_lo,
    const u16* __restrict__ img_hi,
    const u16* __restrict__ wT_hi, const u16* __restrict__ wT_lo,
    const float* __restrict__ words,
    u16* __restrict__ vbuf, float* __restrict__ invn_ws,
    float* __restrict__ simave_ws, float* __restrict__ out)
{
    const int pair = blockIdx.x;
    const int i = pair & 31, b = pair >> 5;
    const u16* iTh = imgT_hi + (size_t)b * 512 * 1024;
    const u16* iTl = imgT_lo + (size_t)b * 512 * 1024;
    const u16* iH  = img_hi  + (size_t)b * 1024 * 512;
    const u16* wTh = wT_hi + (size_t)i * 65536;
    const u16* wTl = wT_lo + (size_t)i * 65536;
    const float* wrd = words + (size_t)i * D_DIM * Q_DIM;
    u16* vb = vbuf + (size_t)pair * 64 * 1024;

    __shared__ char Ubytes[65536] __attribute__((aligned(16)));
    __shared__ char Wt[8192] __attribute__((aligned(16)));
    __shared__ float zred[256];
    __shared__ float invnS[64];

    const int tid = threadIdx.x;
    const int w = tid >> 6, l = tid & 63;
    const int l15 = l & 15, l4 = l >> 4;

    // ---- Stage 1
    {
        f32x4 acc[4][8] = {};
        for (int k0 = 0; k0 < 1024; k0 += 32) {
            bf16x8 ah[4], al[4];
            #pragma unroll
            for (int mf = 0; mf < 4; mf++) {
                int q = mf * 16 + l15;
                ah[mf] = *(const bf16x8*)(wTh + (size_t)q * 1024 + k0 + l4 * 8);
                al[mf] = *(const bf16x8*)(wTl + (size_t)q * 1024 + k0 + l4 * 8);
            }
            #pragma unroll
            for (int nf = 0; nf < 8; nf++) {
                int s = w * 128 + nf * 16 + l15;
                bf16x8 bh = *(const bf16x8*)(iTh + (size_t)s * 1024 + k0 + l4 * 8);
                bf16x8 blo = *(const bf16x8*)(iTl + (size_t)s * 1024 + k0 + l4 * 8);
                #pragma unroll
                for (int mf = 0; mf < 4; mf++)
                    acc[mf][nf] = __builtin_amdgcn_mfma_f32_16x16x32_bf16(ah[mf], bh, acc[mf][nf], 0, 0, 0);
                #pragma unroll
                for (int mf = 0; mf < 4; mf++)
                    acc[mf][nf] = __builtin_amdgcn_mfma_f32_16x16x32_bf16(al[mf], bh, acc[mf][nf], 0, 0, 0);
                #pragma unroll
                for (int mf = 0; mf < 4; mf++)
                    acc[mf][nf] = __builtin_amdgcn_mfma_f32_16x16x32_bf16(ah[mf], blo, acc[mf][nf], 0, 0, 0);
            }
        }
        const bool diag = (i == b);
        float* am = out + 1024 + (size_t)i * Q_DIM * S_DIM;
        #pragma unroll
        for (int nf = 0; nf < 8; nf++) {
            int s = w * 128 + nf * 16 + l15;
            float m = -3.4e38f;
            #pragma unroll
            for (int mf = 0; mf < 4; mf++)
                #pragma unroll
                for (int r = 0; r < 4; r++) m = fmaxf(m, acc[mf][nf][r]);
            m = fmaxf(m, __shfl_xor(m, 16));
            m = fmaxf(m, __shfl_xor(m, 32));
            float e[16], sum = 0.f;
            #pragma unroll
            for (int mf = 0; mf < 4; mf++)
                #pragma unroll
                for (int r = 0; r < 4; r++) {
                    float ev = __expf(acc[mf][nf][r] - m);
                    e[mf * 4 + r] = ev; sum += ev;
                }
            sum += __shfl_xor(sum, 16);
            sum += __shfl_xor(sum, 32);
            float inv = 1.f / sum;
            #pragma unroll
            for (int mf = 0; mf < 4; mf++)
                #pragma unroll
                for (int r = 0; r < 4; r++) {
                    int q = mf * 16 + l4 * 4 + r;
                    float u = __expf(4.f * e[mf * 4 + r] * inv);
                    *(u16*)(Ubytes + q * 1024 + ((2 * s) ^ ((q & 7) << 4))) = f2b(u);
                    if (diag) am[(size_t)q * S_DIM + s] = u;
                }
        }
    }
    __syncthreads();

    // ---- Stage 2
    {
        int q = tid & 63, ch = tid >> 6;
        float zp = 0.f;
        for (int s = ch * 128; s < ch * 128 + 128; s++)
            zp += b2f(*(const u16*)(Ubytes + q * 1024 + ((2 * s) ^ ((q & 7) << 4))));
        zred[ch * 64 + q] = zp;
        __syncthreads();
        float Z = zred[q] + zred[64 + q] + zred[128 + q] + zred[192 + q];
        float iz = 1.f / Z;
        for (int s = ch * 128; s < ch * 128 + 128; s++) {
            u16* p = (u16*)(Ubytes + q * 1024 + ((2 * s) ^ ((q & 7) << 4)));
            *p = f2b(b2f(*p) * iz);
        }
    }

    // ---- Stage 3
    float ssq[4] = {0.f, 0.f, 0.f, 0.f};
    for (int dt = 0; dt < 16; dt++) {
        __syncthreads();
        {
            int dd = tid >> 2, qg = (tid & 3) * 16;
            int d = dt * 64 + dd;
            float4 p0, p1, p2, p3;
            if (d < D_DIM) {
                const float* src = wrd + (size_t)d * Q_DIM + qg;
                p0 = *(const float4*)(src);      p1 = *(const float4*)(src + 4);
                p2 = *(const float4*)(src + 8);  p3 = *(const float4*)(src + 12);
            } else {
                p0 = p1 = p2 = p3 = make_float4(0.f, 0.f, 0.f, 0.f);
            }
            bf16x8 h0, h1;
            h0[0]=(short)f2b(p0.x); h0[1]=(short)f2b(p0.y); h0[2]=(short)f2b(p0.z); h0[3]=(short)f2b(p0.w);
            h0[4]=(short)f2b(p1.x); h0[5]=(short)f2b(p1.y); h0[6]=(short)f2b(p1.z); h0[7]=(short)f2b(p1.w);
            h1[0]=(short)f2b(p2.x); h1[1]=(short)f2b(p2.y); h1[2]=(short)f2b(p2.z); h1[3]=(short)f2b(p2.w);
            h1[4]=(short)f2b(p3.x); h1[5]=(short)f2b(p3.y); h1[6]=(short)f2b(p3.z); h1[7]=(short)f2b(p3.w);
            int c0 = (qg >> 3) ^ (dd & 7);
            int c1 = ((qg >> 3) + 1) ^ (dd & 7);
            *(bf16x8*)(Wt + dd * 128 + c0 * 16) = h0;
            *(bf16x8*)(Wt + dd * 128 + c1 * 16) = h1;
        }
        __syncthreads();
        f32x4 acc[4] = {};
        #pragma unroll
        for (int ss = 0; ss < 8; ss++) {
            #pragma unroll
            for (int kf = 0; kf < 2; kf++) {
                int q = w * 16 + l15;
                int ks = ss * 64 + kf * 32 + l4 * 8;
                bf16x8 af = *(const bf16x8*)(Ubytes + q * 1024 + ((2 * ks) ^ ((q & 7) << 4)));
                #pragma unroll
                for (int nf = 0; nf < 4; nf++) {
                    int d = dt * 64 + nf * 16 + l15;
                    bf16x8 bfr = *(const bf16x8*)(iH + (size_t)d * 512 + ks);
                    acc[nf] = __builtin_amdgcn_mfma_f32_16x16x32_bf16(af, bfr, acc[nf], 0, 0, 0);
                }
            }
        }
        #pragma unroll
        for (int nf = 0; nf < 4; nf++) {
            int dd = nf * 16 + l15;
            int d = dt * 64 + dd;
            #pragma unroll
            for (int r = 0; r < 4; r++) {
                int q = w * 16 + l4 * 4 + r;
                float wctx = acc[nf][r];
                float wv = b2f(*(const u16*)(Wt + dd * 128 + ((((q >> 3) ^ (dd & 7)) << 4)) + (q & 7) * 2));
                float vv = wctx * wv;
                ssq[r] = fmaf(vv, vv, ssq[r]);
                if (d < D_DIM) vb[(size_t)q * 1024 + d] = f2b(vv);
            }
        }
    }
    __syncthreads();
    #pragma unroll
    for (int r = 0; r < 4; r++) {
        float s = ssq[r];
        #pragma unroll
        for (int mk = 1; mk < 16; mk <<= 1) s += __shfl_xor(s, mk);
        if (l15 == 0) {
            int q = w * 16 + l4 * 4 + r;
            float n = 1.f / (sqrtf(s) + 1e-8f);
            invnS[q] = n;
            invn_ws[pair * 64 + q] = n;
        }
    }
    __syncthreads();

    for (int d = tid; d < D_DIM; d += 256) {
        float s = 0.f;
        for (int q = 0; q < 64; q++) s = fmaf(b2f(vb[(size_t)q * 1024 + d]), invnS[q], s);
        simave_ws[(size_t)pair * D_DIM + d] = s * (1.f / 64.f);
    }
}

// normalize att_maps rows in place: a2 = u / sum_s u.  32 blocks.
__global__ __launch_bounds__(256) void k_attmap2(float* __restrict__ out)
{
    const int i = blockIdx.x;
    float* am = out + 1024 + (size_t)i * Q_DIM * S_DIM;
    int q = threadIdx.x >> 2, ch = threadIdx.x & 3;
    float s = 0.f;
    for (int ss = ch * 128; ss < ch * 128 + 128; ss++) s += am[(size_t)q * S_DIM + ss];
    s += __shfl_xor(s, 1);
    s += __shfl_xor(s, 2);
    float iz = 1.f / s;
    for (int ss = ch * 128; ss < ch * 128 + 128; ss++) am[(size_t)q * S_DIM + ss] *= iz;
}

// ---------------------------------------------------------------------------
// k_prep: wlT_bf16[e][d] = bf16(wl[d][e]); [1024][1024], zero-padded.
// ---------------------------------------------------------------------------
__global__ __launch_bounds__(256) void k_prep(const float* __restrict__ wl, u16* __restrict__ wlT)
{
    __shared__ float t[64][65];
    int bd = blockIdx.x & 15, be = blockIdx.x >> 4;
    int tx = threadIdx.x & 15, ty = threadIdx.x >> 4;
    #pragma unroll
    for (int rr = 0; rr < 4; rr++) {
        int r = ty * 4 + rr;
        int d = bd * 64 + r;
        int e4 = be * 64 + tx * 4;
        float v0 = 0.f, v1 = 0.f, v2 = 0.f, v3 = 0.f;
        if (d < D_DIM) {
            if (e4 + 3 < D_DIM) {
                float4 v = *reinterpret_cast<const float4*>(wl + (size_t)d * D_DIM + e4);
                v0 = v.x; v1 = v.y; v2 = v.z; v3 = v.w;
            } else {
                if (e4 + 0 < D_DIM) v0 = wl[(size_t)d * D_DIM + e4 + 0];
                if (e4 + 1 < D_DIM) v1 = wl[(size_t)d * D_DIM + e4 + 1];
                if (e4 + 2 < D_DIM) v2 = wl[(size_t)d * D_DIM + e4 + 2];
                if (e4 + 3 < D_DIM) v3 = wl[(size_t)d * D_DIM + e4 + 3];
            }
        }
        t[r][tx * 4 + 0] = v0; t[r][tx * 4 + 1] = v1;
        t[r][tx * 4 + 2] = v2; t[r][tx * 4 + 3] = v3;
    }
    __syncthreads();
    #pragma unroll
    for (int rr = 0; rr < 4; rr++) {
        int r2 = ty * 4 + rr;          // e within tile
        int e = be * 64 + r2;
        int d0 = bd * 64 + tx * 4;
        ushort4 h;
        h.x = f2b(t[tx * 4 + 0][r2]); h.y = f2b(t[tx * 4 + 1][r2]);
        h.z = f2b(t[tx * 4 + 2][r2]); h.w = f2b(t[tx * 4 + 3][r2]);
        *reinterpret_cast<ushort4*>(wlT + (size_t)e * 1024 + d0) = h;
    }
}

// ---------------------------------------------------------------------------
// Kernel D: g2[pair][e] = tanh(simave . wg + bg) * wc  (fp32)
// ---------------------------------------------------------------------------
__global__ __launch_bounds__(256) void k_g2(
    const float* __restrict__ simave, const float* __restrict__ wg,
    const float* __restrict__ bg, const float* __restrict__ wc,
    float* __restrict__ g2)
{
    int mt = blockIdx.x & 15;
    int nt = blockIdx.x >> 4;
    __shared__ float As[16 * 65], Bs[16 * 65];
    int tid = threadIdx.x;
    int tx = tid & 15, ty = tid >> 4;
    int m0 = mt * 64, n0 = nt * 64;
    float acc[4][4] = {};
    for (int k0 = 0; k0 < D_DIM; k0 += 16) {
        {
            int mm = tid >> 2, k4 = (tid & 3) << 2;
            float4 v = make_float4(0.f, 0.f, 0.f, 0.f);
            if (k0 + k4 < D_DIM) v = *reinterpret_cast<const float4*>(simave + (size_t)(m0 + mm) * D_DIM + k0 + k4);
            As[(k4 + 0) * 65 + mm] = v.x; As[(k4 + 1) * 65 + mm] = v.y;
            As[(k4 + 2) * 65 + mm] = v.z; As[(k4 + 3) * 65 + mm] = v.w;
        }
        {
            int k = tid >> 4, n4 = (tid & 15) << 2;
            float4 v = make_float4(0.f, 0.f, 0.f, 0.f);
            if (k0 + k < D_DIM && n0 + n4 < D_DIM)
                v = *reinterpret_cast<const float4*>(wg + (size_t)(k0 + k) * D_DIM + n0 + n4);
            Bs[k * 65 + n4 + 0] = v.x; Bs[k * 65 + n4 + 1] = v.y;
            Bs[k * 65 + n4 + 2] = v.z; Bs[k * 65 + n4 + 3] = v.w;
        }
        __syncthreads();
        #pragma unroll
        for (int k = 0; k < 16; k++) {
            float a[4], bb[4];
            #pragma unroll
            for (int j = 0; j < 4; j++) a[j] = As[k * 65 + ty * 4 + j];
            #pragma unroll
            for (int j = 0; j < 4; j++) bb[j] = Bs[k * 65 + tx * 4 + j];
            #pragma unroll
            for (int j = 0; j < 4; j++)
                #pragma unroll
                for (int jj = 0; jj < 4; jj++)
                    acc[j][jj] = fmaf(a[j], bb[jj], acc[j][jj]);
        }
        __syncthreads();
    }
    #pragma unroll
    for (int j = 0; j < 4; j++) {
        int p = m0 + ty * 4 + j;
        #pragma unroll
        for (int jj = 0; jj < 4; jj++) {
            int e = n0 + tx * 4 + jj;
            if (e < D_DIM) g2[(size_t)p * D_DIM + e] = tanhf(acc[j][jj] + bg[e]) * wc[e];
        }
    }
}

// ---------------------------------------------------------------------------
// k_saG: flat GEMM M=65536 (pair*64+q rows of vbuf), N=1024 (e rows of wlT),
// K=1024. BM=BN=256, BK=64, 512 threads (8 waves 2x4), global_load_lds staging.
// Epilogue: partial_w[nchunk=nt*4+wc][row] = sum_{e in 64-col chunk} tanh(acc*invn+bl)*g2
// ---------------------------------------------------------------------------
__global__ __launch_bounds__(512) void k_saG(
    const u16* __restrict__ vbuf, const u16* __restrict__ wlT,
    const float* __restrict__ invn_ws, const float* __restrict__ g2_ws,
    const float* __restrict__ bl, float* __restrict__ wspart)
{
    const int bid = blockIdx.x;
    const int mt = bid & 255, nt = bid >> 8;
    const int m0 = mt * 256, n0 = nt * 256;

    __shared__ char Al[32768] __attribute__((aligned(16)));   // [256 m][64 k] bf16
    __shared__ char Bl[32768] __attribute__((aligned(16)));   // [256 e][64 k] bf16
    __shared__ float invnS[256];
    __shared__ float blS[256];
    __shared__ float g2S[4 * 256];

    const int tid = threadIdx.x;
    const int wid = tid >> 6, lane = tid & 63;
    const int wr = wid >> 2, wc = wid & 3;
    const int l15 = lane & 15, l4 = lane >> 4;

    // stage epilogue constants
    if (tid < 256) {
        invnS[tid] = invn_ws[m0 + tid];
        int e = n0 + tid;
        blS[tid] = (e < D_DIM) ? bl[e] : 0.f;
    }
    #pragma unroll
    for (int rep = 0; rep < 2; rep++) {
        int idx = tid + rep * 512;
        int p = idx >> 8, el = idx & 255;
        int e = n0 + el;
        g2S[idx] = (e < D_DIM) ? g2_ws[(size_t)((m0 >> 6) + p) * D_DIM + e] : 0.f;
    }

    f32x4 acc[8][4] = {};

    for (int k0 = 0; k0 < 1024; k0 += 64) {
        __syncthreads();   // protect LDS from prior iteration's reads (and cover const staging)
        #pragma unroll
        for (int it = 0; it < 4; it++) {
            int chunk = it * 8 + wid;
            int o = chunk * 1024 + lane * 16;
            int m = o >> 7, inrow = o & 127;
            GLOAD(Al + chunk * 1024, (const char*)vbuf + (size_t)(m0 + m) * 2048 + k0 * 2 + inrow);
            GLOAD(Bl + chunk * 1024, (const char*)wlT + (size_t)(n0 + m) * 2048 + k0 * 2 + inrow);
        }
        __syncthreads();
        #pragma unroll
        for (int kf = 0; kf < 2; kf++) {
            bf16x8 a[8], bb[4];
            #pragma unroll
            for (int mf = 0; mf < 8; mf++)
                a[mf] = *(const bf16x8*)(Al + (wr * 128 + mf * 16 + l15) * 128 + kf * 64 + l4 * 16);
            #pragma unroll
            for (int nf = 0; nf < 4; nf++)
                bb[nf] = *(const bf16x8*)(Bl + (wc * 64 + nf * 16 + l15) * 128 + kf * 64 + l4 * 16);
            #pragma unroll
            for (int mf = 0; mf < 8; mf++)
                #pragma unroll
                for (int nf = 0; nf < 4; nf++)
                    acc[mf][nf] = __builtin_amdgcn_mfma_f32_16x16x32_bf16(a[mf], bb[nf], acc[mf][nf], 0, 0, 0);
        }
    }

    // epilogue
    #pragma unroll
    for (int mf = 0; mf < 8; mf++) {
        int mrow = wr * 128 + mf * 16 + l4 * 4;   // + r (block-local row)
        #pragma unroll
        for (int r = 0; r < 4; r++) {
            float inv = invnS[mrow + r];
            int p = (mrow + r) >> 6;
            float s = 0.f;
            #pragma unroll
            for (int nf = 0; nf < 4; nf++) {
                int el = wc * 64 + nf * 16 + l15;
                float x = acc[mf][nf][r] * inv + blS[el];
                s += ftanh(x) * g2S[p * 256 + el];
            }
            s += __shfl_xor(s, 1);
            s += __shfl_xor(s, 2);
            s += __shfl_xor(s, 4);
            s += __shfl_xor(s, 8);
            if (l15 == 0)
                wspart[(size_t)(nt * 4 + wc) * 65536 + m0 + mrow + r] = s;
        }
    }
}

// ---------------------------------------------------------------------------
// k_sa2: per pair: w[q] = sum of 16 partials -> softmax -> fold invn ->
// new_global -> l2norm -> sigmoid -> out[pair]
// ---------------------------------------------------------------------------
__global__ __launch_bounds__(256) void k_sa2(
    const float* __restrict__ wspart, const float* __restrict__ invn_ws,
    const u16* __restrict__ vbuf, const float* __restrict__ capw,
    const float* __restrict__ capb, float* __restrict__ out)
{
    const int pair = blockIdx.x;
    const u16* vb = vbuf + (size_t)pair * 64 * 1024;

    __shared__ float wiS[64];
    __shared__ float red[8];

    const int tid = threadIdx.x;

    if (tid < 64) {
        float x = 0.f;
        #pragma unroll
        for (int c = 0; c < 16; c++) x += wspart[(size_t)c * 65536 + pair * 64 + tid];
        float m = x;
        #pragma unroll
        for (int mk = 1; mk < 64; mk <<= 1) m = fmaxf(m, __shfl_xor(m, mk));
        float e = __expf(x - m);
        float Z = e;
        #pragma unroll
        for (int mk = 1; mk < 64; mk <<= 1) Z += __shfl_xor(Z, mk);
        wiS[tid] = (e / Z) * invn_ws[pair * 64 + tid];
    }
    __syncthreads();

    float s1 = 0.f, s2 = 0.f;
    for (int d = tid; d < D_DIM; d += 256) {
        float ng = 0.f;
        for (int q = 0; q < 64; q++) ng = fmaf(wiS[q], b2f(vb[(size_t)q * 1024 + d]), ng);
        s1 = fmaf(ng, capw[d], s1);
        s2 = fmaf(ng, ng, s2);
    }
    #pragma unroll
    for (int mk = 1; mk < 64; mk <<= 1) { s1 += __shfl_xor(s1, mk); s2 += __shfl_xor(s2, mk); }
    if ((tid & 63) == 0) { red[tid >> 6] = s1; red[4 + (tid >> 6)] = s2; }
    __syncthreads();
    if (tid == 0) {
        float S1 = red[0] + red[1] + red[2] + red[3];
        float S2 = red[4] + red[5] + red[6] + red[7];
        float val = S1 / (sqrtf(S2) + 1e-8f) + capb[0];
        out[pair] = 1.f / (1.f + __expf(-val));
    }
}

// ---------------------------------------------------------------------------
extern "C" void kernel_launch(void* const* d_in, const int* in_sizes, int n_in,
                              void* d_out, int out_size, void* d_ws, size_t ws_size,
                              hipStream_t stream)
{
    const float* feat_l = (const float*)d_in[0];
    const float* feat_f = (const float*)d_in[1];
    const float* words  = (const float*)d_in[2];
    const float* conv_w = (const float*)d_in[3];
    const float* conv_b = (const float*)d_in[4];
    const float* sa_wl  = (const float*)d_in[5];
    const float* sa_bl  = (const float*)d_in[6];
    const float* sa_wg  = (const float*)d_in[7];
    const float* sa_bg  = (const float*)d_in[8];
    const float* sa_wc  = (const float*)d_in[9];
    // d_in[10] = sa_bc: constant pre-softmax shift -> result-invariant
    const float* cap_w  = (const float*)d_in[11];
    const float* cap_b  = (const float*)d_in[12];
    float* out = (float*)d_out;

    char* ws = (char*)d_ws;
    // ws layout (bytes), total ~253.8 MB:
    //   vbuf    : [0, 134,217,728)           bf16 [65536][1024]  ([pair][q][d])
    //   img_lo  : [0, 33,554,432)            OVERLAYS vbuf head (dead before attn)
    //   img_hi  : [134,217,728, +33,554,432) bf16 [32][1024][512]
    //   imgT_hi : [167,772,160, +33,554,432) bf16 [32][512][1024]
    //   imgT_lo : [201,326,592, +33,554,432)
    //   wspart  : [201,326,592, +4,194,304)  OVERLAYS imgT_lo (dead after k_attn)
    //   wT_hi   : [234,881,024, +4,194,304)  bf16 [32][64][1024]
    //   wT_lo   : [239,075,328, +4,194,304)
    //   wlT     : [243,269,632, +2,097,152)  bf16 [1024][1024]
    //   g2      : [245,366,784, +4,096,000)  f32 [1024][1000]
    //   invn    : [249,462,784, +262,144)
    //   simave  : [249,724,928, +4,096,000)
    u16*   img_lo  = (u16*)(ws);
    u16*   vbuf    = (u16*)(ws);
    u16*   img_hi  = (u16*)(ws + 134217728);
    u16*   imgT_hi = (u16*)(ws + 167772160);
    u16*   imgT_lo = (u16*)(ws + 201326592);
    float* wspart  = (float*)(ws + 201326592);
    u16*   wT_hi   = (u16*)(ws + 234881024);
    u16*   wT_lo   = (u16*)(ws + 239075328);
    u16*   wlT     = (u16*)(ws + 243269632);
    float* g2      = (float*)(ws + 245366784);
    float* invn    = (float*)(ws + 249462784);
    float* simave  = (float*)(ws + 249724928);

    hipLaunchKernelGGL(k_conv, dim3(4096), dim3(256), 0, stream,
                       feat_l, feat_f, conv_w, conv_b, img_hi, img_lo);
    hipLaunchKernelGGL(k_trans, dim3(4096), dim3(256), 0, stream,
                       img_hi, img_lo, imgT_hi, imgT_lo);
    hipLaunchKernelGGL(k_prepw, dim3(512), dim3(256), 0, stream,
                       words, wT_hi, wT_lo);
    hipLaunchKernelGGL(k_prep, dim3(256), dim3(256), 0, stream, sa_wl, wlT);
    hipLaunchKernelGGL(k_attn, dim3(1024), dim3(256), 0, stream,
                       imgT_hi, imgT_lo, img_hi, wT_hi, wT_lo, words,
                       vbuf, invn, simave, out);
    hipLaunchKernelGGL(k_attmap2, dim3(32), dim3(256), 0, stream, out);
    hipLaunchKernelGGL(k_g2, dim3(256), dim3(256), 0, stream,
                       simave, sa_wg, sa_bg, sa_wc, g2);
    hipLaunchKernelGGL(k_saG, dim3(1024), dim3(512), 0, stream,
                       vbuf, wlT, invn, g2, sa_bl, wspart);
    hipLaunchKernelGGL(k_sa2, dim3(1024), dim3(256), 0, stream,
                       wspart, invn, vbuf, cap_w, cap_b, out);
}

// Round 5
// 1025.558 us; speedup vs baseline: 6.4044x; 2.0224x over previous
//
#include <hip/hip_runtime.h>
#include <cstdint>

typedef unsigned short u16;
typedef unsigned int   u32;
typedef __attribute__((ext_vector_type(8))) short bf16x8;
typedef __attribute__((ext_vector_type(4))) float f32x4;

#define D_DIM 1000
#define C_IN  1024
#define HW    256
#define S_DIM 512
#define Q_DIM 64

__device__ __forceinline__ u16 f2b(float x) {
    u32 u = __builtin_bit_cast(u32, x);
    u32 r = (u + 0x7FFFu + ((u >> 16) & 1u)) >> 16;
    return (u16)r;
}
__device__ __forceinline__ float b2f(u16 h) {
    u32 u = ((u32)h) << 16;
    return __builtin_bit_cast(float, u);
}
__device__ __forceinline__ float ftanh(float x) {
    float e = __expf(2.f * x);
    return 1.f - 2.f / (e + 1.f);
}

#define GLOAD(ldsptr, gptr) \
    __builtin_amdgcn_global_load_lds( \
        (const __attribute__((address_space(1))) unsigned int*)(gptr), \
        (__attribute__((address_space(3))) unsigned int*)(ldsptr), 16, 0, 0)

// ---------------------------------------------------------------------------
// k_prepf: feat [b][1024 c][256 hw] fp32 -> featT_hi/lo bf16 [b][512 s][1024 c]
// s = half*256 + hw  (half 0 = frontal = feat_f, half 1 = lateral = feat_l)
// grid 32*2*4*16 = 4096 blocks
// ---------------------------------------------------------------------------
__global__ __launch_bounds__(256) void k_prepf(
    const float* __restrict__ feat_l, const float* __restrict__ feat_f,
    u16* __restrict__ fT_hi, u16* __restrict__ fT_lo)
{
    int bid = blockIdx.x;
    int ct = bid & 15, ht = (bid >> 4) & 3, half_ = (bid >> 6) & 1, b = bid >> 7;
    const float* src = (half_ ? feat_l : feat_f) + (size_t)b * C_IN * HW;
    __shared__ float T[64][65];   // [hw][c]
    int tid = threadIdx.x;
    {
        int cl = tid >> 2, h16 = (tid & 3) * 16;
        const float* p = src + (size_t)(ct * 64 + cl) * 256 + ht * 64 + h16;
        #pragma unroll
        for (int j = 0; j < 4; j++) {
            float4 v = *(const float4*)(p + j * 4);
            T[h16 + j * 4 + 0][cl] = v.x;
            T[h16 + j * 4 + 1][cl] = v.y;
            T[h16 + j * 4 + 2][cl] = v.z;
            T[h16 + j * 4 + 3][cl] = v.w;
        }
    }
    __syncthreads();
    {
        int hl = tid >> 2, c16 = (tid & 3) * 16;
        int srow = b * 512 + half_ * 256 + ht * 64 + hl;
        bf16x8 vh[2], vl[2];
        #pragma unroll
        for (int g = 0; g < 2; g++)
            #pragma unroll
            for (int j = 0; j < 8; j++) {
                float x = T[hl][c16 + g * 8 + j];
                u16 hh = f2b(x);
                vh[g][j] = (short)hh;
                vl[g][j] = (short)f2b(x - b2f(hh));
            }
        size_t o = (size_t)srow * 1024 + ct * 64 + c16;
        *(bf16x8*)(fT_hi + o) = vh[0];
        *(bf16x8*)(fT_hi + o + 8) = vh[1];
        *(bf16x8*)(fT_lo + o) = vl[0];
        *(bf16x8*)(fT_lo + o + 8) = vl[1];
    }
}

// ---------------------------------------------------------------------------
// k_prepcw: cw [1000][1024] fp32 -> cw_hi/lo [1024][1024] bf16 (rows >=1000 zero)
// ---------------------------------------------------------------------------
__global__ __launch_bounds__(256) void k_prepcw(
    const float* __restrict__ cw, u16* __restrict__ cwh, u16* __restrict__ cwl)
{
    int d = blockIdx.x;
    int c4 = threadIdx.x * 4;
    ushort4 h = make_ushort4(0, 0, 0, 0), lo = make_ushort4(0, 0, 0, 0);
    if (d < D_DIM) {
        float4 v = *(const float4*)(cw + (size_t)d * 1024 + c4);
        float a[4] = {v.x, v.y, v.z, v.w};
        u16* ph = (u16*)&h; u16* pl = (u16*)&lo;
        #pragma unroll
        for (int j = 0; j < 4; j++) {
            ph[j] = f2b(a[j]);
            pl[j] = f2b(a[j] - b2f(ph[j]));
        }
    }
    *(ushort4*)(cwh + (size_t)d * 1024 + c4) = h;
    *(ushort4*)(cwl + (size_t)d * 1024 + c4) = lo;
}

// ---------------------------------------------------------------------------
// k_prepw: words [i][1000 d][64 q] fp32 -> wT_hi/lo bf16 [i][64 q][1024 d]
// ---------------------------------------------------------------------------
__global__ __launch_bounds__(256) void k_prepw(
    const float* __restrict__ words, u16* __restrict__ wth, u16* __restrict__ wtl)
{
    int i = blockIdx.x >> 4, dt = blockIdx.x & 15;
    const float* src = words + (size_t)i * D_DIM * Q_DIM;
    __shared__ u16 Th[64][72], Tl[64][72];
    int tid = threadIdx.x;
    #pragma unroll
    for (int rep = 0; rep < 4; rep++) {
        int idx = tid + rep * 256;
        int dl = idx >> 4, q4 = (idx & 15) * 4;
        int d = dt * 64 + dl;
        float4 v = make_float4(0.f, 0.f, 0.f, 0.f);
        if (d < D_DIM) v = *(const float4*)(src + (size_t)d * Q_DIM + q4);
        float a[4] = {v.x, v.y, v.z, v.w};
        #pragma unroll
        for (int jj = 0; jj < 4; jj++) {
            u16 hh = f2b(a[jj]);
            Th[dl][q4 + jj] = hh;
            Tl[dl][q4 + jj] = f2b(a[jj] - b2f(hh));
        }
    }
    __syncthreads();
    #pragma unroll
    for (int rep = 0; rep < 2; rep++) {
        int idx = tid + rep * 256;
        int q = idx >> 3, c8 = idx & 7;
        bf16x8 vh, vl;
        #pragma unroll
        for (int jj = 0; jj < 8; jj++) { vh[jj] = (short)Th[c8 * 8 + jj][q]; vl[jj] = (short)Tl[c8 * 8 + jj][q]; }
        size_t doff = (size_t)i * 65536 + (size_t)q * 1024 + dt * 64 + c8 * 8;
        *(bf16x8*)(wth + doff) = vh;
        *(bf16x8*)(wtl + doff) = vl;
    }
}

// ---------------------------------------------------------------------------
// k_prep: wlT_bf16[e][d] = bf16(wl[d][e]); [1024][1024], zero-padded.
// ---------------------------------------------------------------------------
__global__ __launch_bounds__(256) void k_prep(const float* __restrict__ wl, u16* __restrict__ wlT)
{
    __shared__ float t[64][65];
    int bd = blockIdx.x & 15, be = blockIdx.x >> 4;
    int tx = threadIdx.x & 15, ty = threadIdx.x >> 4;
    #pragma unroll
    for (int rr = 0; rr < 4; rr++) {
        int r = ty * 4 + rr;
        int d = bd * 64 + r;
        int e4 = be * 64 + tx * 4;
        float v0 = 0.f, v1 = 0.f, v2 = 0.f, v3 = 0.f;
        if (d < D_DIM) {
            if (e4 + 3 < D_DIM) {
                float4 v = *reinterpret_cast<const float4*>(wl + (size_t)d * D_DIM + e4);
                v0 = v.x; v1 = v.y; v2 = v.z; v3 = v.w;
            } else {
                if (e4 + 0 < D_DIM) v0 = wl[(size_t)d * D_DIM + e4 + 0];
                if (e4 + 1 < D_DIM) v1 = wl[(size_t)d * D_DIM + e4 + 1];
                if (e4 + 2 < D_DIM) v2 = wl[(size_t)d * D_DIM + e4 + 2];
                if (e4 + 3 < D_DIM) v3 = wl[(size_t)d * D_DIM + e4 + 3];
            }
        }
        t[r][tx * 4 + 0] = v0; t[r][tx * 4 + 1] = v1;
        t[r][tx * 4 + 2] = v2; t[r][tx * 4 + 3] = v3;
    }
    __syncthreads();
    #pragma unroll
    for (int rr = 0; rr < 4; rr++) {
        int r2 = ty * 4 + rr;
        int e = be * 64 + r2;
        int d0 = bd * 64 + tx * 4;
        ushort4 h;
        h.x = f2b(t[tx * 4 + 0][r2]); h.y = f2b(t[tx * 4 + 1][r2]);
        h.z = f2b(t[tx * 4 + 2][r2]); h.w = f2b(t[tx * 4 + 3][r2]);
        *reinterpret_cast<ushort4*>(wlT + (size_t)e * 1024 + d0) = h;
    }
}

// ---------------------------------------------------------------------------
// k_convG: img[s-rows][d-cols] = featT . cw^T (split-bf16 3-pass) + cb
// M = 16384 (b*512+s), N = 1024 d, K = 1024 c. BM=BN=256, BK=32, 512 thr.
// Writes img_hi/lo [b][1024 d][512 s].  grid 64*4 = 256 blocks.
// ---------------------------------------------------------------------------
__global__ __launch_bounds__(512) void k_convG(
    const u16* __restrict__ fT_hi, const u16* __restrict__ fT_lo,
    const u16* __restrict__ cwh, const u16* __restrict__ cwl,
    const float* __restrict__ cb,
    u16* __restrict__ img_hi, u16* __restrict__ img_lo)
{
    const int bid = blockIdx.x;
    const int mblk = bid >> 2, nt = bid & 3;
    const int m0 = mblk * 256, n0 = nt * 256;

    __shared__ char Ah[16384] __attribute__((aligned(16)));
    __shared__ char Alo[16384] __attribute__((aligned(16)));
    __shared__ char Bh[16384] __attribute__((aligned(16)));
    __shared__ char Blo[16384] __attribute__((aligned(16)));
    __shared__ float cbS[256];

    const int tid = threadIdx.x;
    const int wid = tid >> 6, lane = tid & 63;
    const int wr = wid >> 2, wc = wid & 3;
    const int l15 = lane & 15, l4 = lane >> 4;

    if (tid < 256) {
        int d = n0 + tid;
        cbS[tid] = (d < D_DIM) ? cb[d] : 0.f;
    }

    f32x4 acc[8][4] = {};

    for (int k0 = 0; k0 < 1024; k0 += 32) {
        __syncthreads();
        #pragma unroll
        for (int rep = 0; rep < 2; rep++) {
            int idx = tid + rep * 512;
            int row = idx >> 2, kb = (idx & 3) * 16;
            size_t ao = (size_t)(m0 + row) * 2048 + (size_t)k0 * 2 + kb;
            size_t bo = (size_t)(n0 + row) * 2048 + (size_t)k0 * 2 + kb;
            GLOAD(Ah + idx * 16, (const char*)fT_hi + ao);
            GLOAD(Alo + idx * 16, (const char*)fT_lo + ao);
            GLOAD(Bh + idx * 16, (const char*)cwh + bo);
            GLOAD(Blo + idx * 16, (const char*)cwl + bo);
        }
        __syncthreads();
        bf16x8 ah[8], bh[4];
        #pragma unroll
        for (int mf = 0; mf < 8; mf++)
            ah[mf] = *(const bf16x8*)(Ah + (wr * 128 + mf * 16 + l15) * 64 + l4 * 16);
        #pragma unroll
        for (int nf = 0; nf < 4; nf++)
            bh[nf] = *(const bf16x8*)(Bh + (wc * 64 + nf * 16 + l15) * 64 + l4 * 16);
        #pragma unroll
        for (int mf = 0; mf < 8; mf++)
            #pragma unroll
            for (int nf = 0; nf < 4; nf++)
                acc[mf][nf] = __builtin_amdgcn_mfma_f32_16x16x32_bf16(ah[mf], bh[nf], acc[mf][nf], 0, 0, 0);
        #pragma unroll
        for (int mf = 0; mf < 8; mf++) {
            bf16x8 al = *(const bf16x8*)(Alo + (wr * 128 + mf * 16 + l15) * 64 + l4 * 16);
            #pragma unroll
            for (int nf = 0; nf < 4; nf++)
                acc[mf][nf] = __builtin_amdgcn_mfma_f32_16x16x32_bf16(al, bh[nf], acc[mf][nf], 0, 0, 0);
        }
        #pragma unroll
        for (int nf = 0; nf < 4; nf++) {
            bf16x8 bl = *(const bf16x8*)(Blo + (wc * 64 + nf * 16 + l15) * 64 + l4 * 16);
            #pragma unroll
            for (int mf = 0; mf < 8; mf++)
                acc[mf][nf] = __builtin_amdgcn_mfma_f32_16x16x32_bf16(ah[mf], bl, acc[mf][nf], 0, 0, 0);
        }
    }
    const int b = m0 >> 9;
    const int sbase = m0 & 511;
    #pragma unroll
    for (int mf = 0; mf < 8; mf++) {
        int srow = sbase + wr * 128 + mf * 16 + l4 * 4;
        #pragma unroll
        for (int nf = 0; nf < 4; nf++) {
            int dcol = n0 + wc * 64 + nf * 16 + l15;
            float bias = cbS[wc * 64 + nf * 16 + l15];
            ushort4 h4, lo4;
            u16* ph = (u16*)&h4; u16* pl = (u16*)&lo4;
            #pragma unroll
            for (int r = 0; r < 4; r++) {
                float v = acc[mf][nf][r] + bias;
                u16 hh = f2b(v);
                ph[r] = hh;
                pl[r] = f2b(v - b2f(hh));
            }
            size_t off = ((size_t)b * 1024 + dcol) * 512 + srow;
            *(ushort4*)(img_hi + off) = h4;
            *(ushort4*)(img_lo + off) = lo4;
        }
    }
}

// ---------------------------------------------------------------------------
// k_trans: img_hi/lo [b][1024 d][512 s] -> imgT_hi/lo [b][512 s][1024 d]
// ---------------------------------------------------------------------------
__global__ __launch_bounds__(256) void k_trans(
    const u16* __restrict__ ih, const u16* __restrict__ il,
    u16* __restrict__ oth, u16* __restrict__ otl)
{
    int bid = blockIdx.x;
    int st = bid & 7, dt = (bid >> 3) & 15, b = bid >> 7;
    const u16* srcH = ih + (size_t)b * 1024 * 512;
    const u16* srcL = il + (size_t)b * 1024 * 512;
    u16* dstH = oth + (size_t)b * 512 * 1024;
    u16* dstL = otl + (size_t)b * 512 * 1024;
    __shared__ u16 Th[64][72], Tl[64][72];
    int tid = threadIdx.x;
    #pragma unroll
    for (int rep = 0; rep < 2; rep++) {
        int idx = tid + rep * 256;
        int dl = idx >> 3, c8 = idx & 7;
        size_t so = (size_t)(dt * 64 + dl) * 512 + st * 64 + c8 * 8;
        bf16x8 vh = *(const bf16x8*)(srcH + so);
        bf16x8 vl = *(const bf16x8*)(srcL + so);
        #pragma unroll
        for (int jj = 0; jj < 8; jj++) { Th[c8 * 8 + jj][dl] = (u16)vh[jj]; Tl[c8 * 8 + jj][dl] = (u16)vl[jj]; }
    }
    __syncthreads();
    #pragma unroll
    for (int rep = 0; rep < 2; rep++) {
        int idx = tid + rep * 256;
        int sl = idx >> 3, c8 = idx & 7;
        bf16x8 vh = *(const bf16x8*)(&Th[sl][c8 * 8]);
        bf16x8 vl = *(const bf16x8*)(&Tl[sl][c8 * 8]);
        size_t doff = (size_t)(st * 64 + sl) * 1024 + dt * 64 + c8 * 8;
        *(bf16x8*)(dstH + doff) = vh;
        *(bf16x8*)(dstL + doff) = vl;
    }
}

// ---------------------------------------------------------------------------
// k_logits: per b: C[iq][s] = wT . imgT^T (3-pass split), softmax over q,
// U[iq][s] = bf16(exp(4*a1)) -> global; Zp partials; diag u -> out.
// M=2048 iq, N=512 s, K=1024. grid 32*8*2 = 512 blocks, 512 thr.
// ---------------------------------------------------------------------------
__global__ __launch_bounds__(512) void k_logits(
    const u16* __restrict__ wTh, const u16* __restrict__ wTl,
    const u16* __restrict__ iTh, const u16* __restrict__ iTl,
    u16* __restrict__ U, float* __restrict__ Zp, float* __restrict__ out)
{
    const int bid = blockIdx.x;
    const int b = bid >> 4, mt = (bid >> 1) & 7, nt = bid & 1;
    const int m0 = mt * 256, n0 = nt * 256;

    __shared__ char Ah[16384] __attribute__((aligned(16)));
    __shared__ char Alo[16384] __attribute__((aligned(16)));
    __shared__ char Bh[16384] __attribute__((aligned(16)));
    __shared__ char Blo[16384] __attribute__((aligned(16)));

    const int tid = threadIdx.x;
    const int wid = tid >> 6, lane = tid & 63;
    const int wr = wid >> 2, wc = wid & 3;
    const int l15 = lane & 15, l4 = lane >> 4;

    f32x4 acc[8][4] = {};

    for (int k0 = 0; k0 < 1024; k0 += 32) {
        __syncthreads();
        #pragma unroll
        for (int rep = 0; rep < 2; rep++) {
            int idx = tid + rep * 512;
            int row = idx >> 2, kb = (idx & 3) * 16;
            size_t ao = (size_t)(m0 + row) * 2048 + (size_t)k0 * 2 + kb;
            size_t bo = ((size_t)b * 512 + n0 + row) * 2048 + (size_t)k0 * 2 + kb;
            GLOAD(Ah + idx * 16, (const char*)wTh + ao);
            GLOAD(Alo + idx * 16, (const char*)wTl + ao);
            GLOAD(Bh + idx * 16, (const char*)iTh + bo);
            GLOAD(Blo + idx * 16, (const char*)iTl + bo);
        }
        __syncthreads();
        bf16x8 ah[8], bh[4];
        #pragma unroll
        for (int mf = 0; mf < 8; mf++)
            ah[mf] = *(const bf16x8*)(Ah + (wr * 128 + mf * 16 + l15) * 64 + l4 * 16);
        #pragma unroll
        for (int nf = 0; nf < 4; nf++)
            bh[nf] = *(const bf16x8*)(Bh + (wc * 64 + nf * 16 + l15) * 64 + l4 * 16);
        #pragma unroll
        for (int mf = 0; mf < 8; mf++)
            #pragma unroll
            for (int nf = 0; nf < 4; nf++)
                acc[mf][nf] = __builtin_amdgcn_mfma_f32_16x16x32_bf16(ah[mf], bh[nf], acc[mf][nf], 0, 0, 0);
        #pragma unroll
        for (int mf = 0; mf < 8; mf++) {
            bf16x8 al = *(const bf16x8*)(Alo + (wr * 128 + mf * 16 + l15) * 64 + l4 * 16);
            #pragma unroll
            for (int nf = 0; nf < 4; nf++)
                acc[mf][nf] = __builtin_amdgcn_mfma_f32_16x16x32_bf16(al, bh[nf], acc[mf][nf], 0, 0, 0);
        }
        #pragma unroll
        for (int nf = 0; nf < 4; nf++) {
            bf16x8 bl = *(const bf16x8*)(Blo + (wc * 64 + nf * 16 + l15) * 64 + l4 * 16);
            #pragma unroll
            for (int mf = 0; mf < 8; mf++)
                acc[mf][nf] = __builtin_amdgcn_mfma_f32_16x16x32_bf16(ah[mf], bl, acc[mf][nf], 0, 0, 0);
        }
    }

    // epilogue: softmax over q per (i, col); U, Zp, diag am
    float zacc[8][4] = {};
    #pragma unroll
    for (int il = 0; il < 2; il++) {
        int i_glob = mt * 4 + wr * 2 + il;
        bool diag = (i_glob == b);
        #pragma unroll
        for (int nf = 0; nf < 4; nf++) {
            int scol = n0 + wc * 64 + nf * 16 + l15;
            float m = -3.4e38f;
            #pragma unroll
            for (int mm = 0; mm < 4; mm++)
                #pragma unroll
                for (int r = 0; r < 4; r++)
                    m = fmaxf(m, acc[il * 4 + mm][nf][r]);
            m = fmaxf(m, __shfl_xor(m, 16));
            m = fmaxf(m, __shfl_xor(m, 32));
            float e[16], sum = 0.f;
            #pragma unroll
            for (int mm = 0; mm < 4; mm++)
                #pragma unroll
                for (int r = 0; r < 4; r++) {
                    float ev = __expf(acc[il * 4 + mm][nf][r] - m);
                    e[mm * 4 + r] = ev; sum += ev;
                }
            sum += __shfl_xor(sum, 16);
            sum += __shfl_xor(sum, 32);
            float inv = 1.f / sum;
            #pragma unroll
            for (int mm = 0; mm < 4; mm++)
                #pragma unroll
                for (int r = 0; r < 4; r++) {
                    float u = __expf(4.f * e[mm * 4 + r] * inv);   // in [1, e^4]
                    u16 ub = f2b(u);
                    zacc[il * 4 + mm][r] += b2f(ub);
                    int iqrow = m0 + wr * 128 + (il * 4 + mm) * 16 + l4 * 4 + r;
                    U[((size_t)b * 2048 + iqrow) * 512 + scol] = ub;
                    if (diag) {
                        int q = iqrow & 63;
                        out[1024 + ((size_t)i_glob * 64 + q) * 512 + scol] = u;
                    }
                }
        }
    }
    #pragma unroll
    for (int mf = 0; mf < 8; mf++)
        #pragma unroll
        for (int r = 0; r < 4; r++) {
            float z = zacc[mf][r];
            z += __shfl_xor(z, 1); z += __shfl_xor(z, 2);
            z += __shfl_xor(z, 4); z += __shfl_xor(z, 8);
            if (l15 == 0) {
                int iqrow = m0 + wr * 128 + mf * 16 + l4 * 4 + r;
                Zp[((size_t)b * 2048 + iqrow) * 8 + nt * 4 + wc] = z;
            }
        }
}

// k_zred: invZf[gi] = 1 / sum of 8 Zp partials
__global__ __launch_bounds__(256) void k_zred(const float* __restrict__ Zp, float* __restrict__ invZf)
{
    int gi = blockIdx.x * 256 + threadIdx.x;
    float4 z0 = *(const float4*)(Zp + (size_t)gi * 8);
    float4 z1 = *(const float4*)(Zp + (size_t)gi * 8 + 4);
    invZf[gi] = 1.f / (z0.x + z0.y + z0.z + z0.w + z1.x + z1.y + z1.z + z1.w);
}

// normalize att_maps rows in place: a2 = u / sum_s u.  32 blocks.
__global__ __launch_bounds__(256) void k_attmap2(float* __restrict__ out)
{
    const int i = blockIdx.x;
    float* am = out + 1024 + (size_t)i * Q_DIM * S_DIM;
    int q = threadIdx.x >> 2, ch = threadIdx.x & 3;
    float s = 0.f;
    for (int ss = ch * 128; ss < ch * 128 + 128; ss++) s += am[(size_t)q * S_DIM + ss];
    s += __shfl_xor(s, 1);
    s += __shfl_xor(s, 2);
    float iz = 1.f / s;
    for (int ss = ch * 128; ss < ch * 128 + 128; ss++) am[(size_t)q * S_DIM + ss] *= iz;
}

// ---------------------------------------------------------------------------
// k_wctx: per b: C[d rows][iq cols] = img_hi . U^T, K=512.
// Epilogue: v = acc*invZ[iq]*(wThi+wTlo) -> vbuf bf16; ssq partials.
// grid 32*4*8 = 1024 blocks, 512 thr, BK=64.
// ---------------------------------------------------------------------------
__global__ __launch_bounds__(512) void k_wctx(
    const u16* __restrict__ img_hi, const u16* __restrict__ U,
    const float* __restrict__ invZf,
    const u16* __restrict__ wTh, const u16* __restrict__ wTl,
    u16* __restrict__ vbuf, float* __restrict__ ssqp)
{
    const int bid = blockIdx.x;
    const int b = bid >> 5, mt = (bid >> 3) & 3, nt = bid & 7;
    const int m0 = mt * 256, n0 = nt * 256;

    __shared__ char At[32768] __attribute__((aligned(16)));
    __shared__ char Bt[32768] __attribute__((aligned(16)));
    __shared__ float izS[256];

    const int tid = threadIdx.x;
    const int wid = tid >> 6, lane = tid & 63;
    const int wr = wid >> 2, wc = wid & 3;
    const int l15 = lane & 15, l4 = lane >> 4;

    if (tid < 256) izS[tid] = invZf[b * 2048 + n0 + tid];

    f32x4 acc[8][4] = {};

    for (int k0 = 0; k0 < 512; k0 += 64) {
        __syncthreads();
        #pragma unroll
        for (int rep = 0; rep < 4; rep++) {
            int idx = tid + rep * 512;
            int row = idx >> 3, kb = (idx & 7) * 16;
            GLOAD(At + idx * 16, (const char*)img_hi + ((size_t)b * 1024 + m0 + row) * 1024 + (size_t)k0 * 2 + kb);
            GLOAD(Bt + idx * 16, (const char*)U + ((size_t)b * 2048 + n0 + row) * 1024 + (size_t)k0 * 2 + kb);
        }
        __syncthreads();
        #pragma unroll
        for (int kf = 0; kf < 2; kf++) {
            bf16x8 a[8], bb[4];
            #pragma unroll
            for (int mf = 0; mf < 8; mf++)
                a[mf] = *(const bf16x8*)(At + (wr * 128 + mf * 16 + l15) * 128 + kf * 64 + l4 * 16);
            #pragma unroll
            for (int nf = 0; nf < 4; nf++)
                bb[nf] = *(const bf16x8*)(Bt + (wc * 64 + nf * 16 + l15) * 128 + kf * 64 + l4 * 16);
            #pragma unroll
            for (int mf = 0; mf < 8; mf++)
                #pragma unroll
                for (int nf = 0; nf < 4; nf++)
                    acc[mf][nf] = __builtin_amdgcn_mfma_f32_16x16x32_bf16(a[mf], bb[nf], acc[mf][nf], 0, 0, 0);
        }
    }

    #pragma unroll
    for (int nf = 0; nf < 4; nf++) {
        int col = wc * 64 + nf * 16 + l15;
        int iq = n0 + col;
        float iz = izS[col];
        size_t wtoff = (size_t)iq * 1024;
        float s_nf = 0.f;
        #pragma unroll
        for (int mf = 0; mf < 8; mf++) {
            int d0 = m0 + wr * 128 + mf * 16 + l4 * 4;
            ushort4 wh = *(const ushort4*)(wTh + wtoff + d0);
            ushort4 wl = *(const ushort4*)(wTl + wtoff + d0);
            const u16* pwh = (const u16*)&wh;
            const u16* pwl = (const u16*)&wl;
            ushort4 vo;
            u16* pv = (u16*)&vo;
            #pragma unroll
            for (int r = 0; r < 4; r++) {
                float wv = b2f(pwh[r]) + b2f(pwl[r]);
                float v = acc[mf][nf][r] * iz * wv;
                s_nf = fmaf(v, v, s_nf);
                pv[r] = f2b(v);
            }
            *(ushort4*)(vbuf + ((size_t)b * 2048 + iq) * 1024 + d0) = vo;
        }
        s_nf += __shfl_xor(s_nf, 16);
        s_nf += __shfl_xor(s_nf, 32);
        if (l4 == 0) ssqp[((size_t)b * 2048 + iq) * 4 + mt] = s_nf;
    }
}

// ---------------------------------------------------------------------------
// k_post: per pair: invn from ssqp; simave[d] = sum_q v*invn /64
// ---------------------------------------------------------------------------
__global__ __launch_bounds__(256) void k_post(
    const u16* __restrict__ vbuf, const float* __restrict__ ssqp,
    float* __restrict__ invn_ws, float* __restrict__ simave)
{
    const int pair = blockIdx.x;
    __shared__ float invnS[64];
    const int tid = threadIdx.x;
    if (tid < 64) {
        size_t o = ((size_t)pair * 64 + tid) * 4;
        float s = ssqp[o] + ssqp[o + 1] + ssqp[o + 2] + ssqp[o + 3];
        float n = 1.f / (sqrtf(s) + 1e-8f);
        invnS[tid] = n;
        invn_ws[pair * 64 + tid] = n;
    }
    __syncthreads();
    int d0 = tid * 4;
    if (d0 < D_DIM) {
        float a0 = 0.f, a1 = 0.f, a2 = 0.f, a3 = 0.f;
        const u16* vb = vbuf + (size_t)pair * 65536;
        for (int q = 0; q < 64; q++) {
            float n = invnS[q];
            ushort4 v = *(const ushort4*)(vb + q * 1024 + d0);
            a0 = fmaf(b2f(v.x), n, a0); a1 = fmaf(b2f(v.y), n, a1);
            a2 = fmaf(b2f(v.z), n, a2); a3 = fmaf(b2f(v.w), n, a3);
        }
        float4 o;
        o.x = a0 * (1.f / 64.f); o.y = a1 * (1.f / 64.f);
        o.z = a2 * (1.f / 64.f); o.w = a3 * (1.f / 64.f);
        *(float4*)(simave + (size_t)pair * D_DIM + d0) = o;
    }
}

// ---------------------------------------------------------------------------
// Kernel D: g2[pair][e] = tanh(simave . wg + bg) * wc  (fp32)
// ---------------------------------------------------------------------------
__global__ __launch_bounds__(256) void k_g2(
    const float* __restrict__ simave, const float* __restrict__ wg,
    const float* __restrict__ bg, const float* __restrict__ wc,
    float* __restrict__ g2)
{
    int mt = blockIdx.x & 15;
    int nt = blockIdx.x >> 4;
    __shared__ float As[16 * 65], Bs[16 * 65];
    int tid = threadIdx.x;
    int tx = tid & 15, ty = tid >> 4;
    int m0 = mt * 64, n0 = nt * 64;
    float acc[4][4] = {};
    for (int k0 = 0; k0 < D_DIM; k0 += 16) {
        {
            int mm = tid >> 2, k4 = (tid & 3) << 2;
            float4 v = make_float4(0.f, 0.f, 0.f, 0.f);
            if (k0 + k4 < D_DIM) v = *reinterpret_cast<const float4*>(simave + (size_t)(m0 + mm) * D_DIM + k0 + k4);
            As[(k4 + 0) * 65 + mm] = v.x; As[(k4 + 1) * 65 + mm] = v.y;
            As[(k4 + 2) * 65 + mm] = v.z; As[(k4 + 3) * 65 + mm] = v.w;
        }
        {
            int k = tid >> 4, n4 = (tid & 15) << 2;
            float4 v = make_float4(0.f, 0.f, 0.f, 0.f);
            if (k0 + k < D_DIM && n0 + n4 < D_DIM)
                v = *reinterpret_cast<const float4*>(wg + (size_t)(k0 + k) * D_DIM + n0 + n4);
            Bs[k * 65 + n4 + 0] = v.x; Bs[k * 65 + n4 + 1] = v.y;
            Bs[k * 65 + n4 + 2] = v.z; Bs[k * 65 + n4 + 3] = v.w;
        }
        __syncthreads();
        #pragma unroll
        for (int k = 0; k < 16; k++) {
            float a[4], bb[4];
            #pragma unroll
            for (int j = 0; j < 4; j++) a[j] = As[k * 65 + ty * 4 + j];
            #pragma unroll
            for (int j = 0; j < 4; j++) bb[j] = Bs[k * 65 + tx * 4 + j];
            #pragma unroll
            for (int j = 0; j < 4; j++)
                #pragma unroll
                for (int jj = 0; jj < 4; jj++)
                    acc[j][jj] = fmaf(a[j], bb[jj], acc[j][jj]);
        }
        __syncthreads();
    }
    #pragma unroll
    for (int j = 0; j < 4; j++) {
        int p = m0 + ty * 4 + j;
        #pragma unroll
        for (int jj = 0; jj < 4; jj++) {
            int e = n0 + tx * 4 + jj;
            if (e < D_DIM) g2[(size_t)p * D_DIM + e] = tanhf(acc[j][jj] + bg[e]) * wc[e];
        }
    }
}

// ---------------------------------------------------------------------------
// k_saG: flat GEMM M=65536 (vbuf rows), N=1024 (wlT rows), K=1024.
// ---------------------------------------------------------------------------
__global__ __launch_bounds__(512) void k_saG(
    const u16* __restrict__ vbuf, const u16* __restrict__ wlT,
    const float* __restrict__ invn_ws, const float* __restrict__ g2_ws,
    const float* __restrict__ bl, float* __restrict__ wspart)
{
    const int bid = blockIdx.x;
    const int mt = bid & 255, nt = bid >> 8;
    const int m0 = mt * 256, n0 = nt * 256;

    __shared__ char Al[32768] __attribute__((aligned(16)));
    __shared__ char Bl[32768] __attribute__((aligned(16)));
    __shared__ float invnS[256];
    __shared__ float blS[256];
    __shared__ float g2S[4 * 256];

    const int tid = threadIdx.x;
    const int wid = tid >> 6, lane = tid & 63;
    const int wr = wid >> 2, wc = wid & 3;
    const int l15 = lane & 15, l4 = lane >> 4;

    if (tid < 256) {
        invnS[tid] = invn_ws[m0 + tid];
        int e = n0 + tid;
        blS[tid] = (e < D_DIM) ? bl[e] : 0.f;
    }
    #pragma unroll
    for (int rep = 0; rep < 2; rep++) {
        int idx = tid + rep * 512;
        int p = idx >> 8, el = idx & 255;
        int e = n0 + el;
        g2S[idx] = (e < D_DIM) ? g2_ws[(size_t)((m0 >> 6) + p) * D_DIM + e] : 0.f;
    }

    f32x4 acc[8][4] = {};

    for (int k0 = 0; k0 < 1024; k0 += 64) {
        __syncthreads();
        #pragma unroll
        for (int it = 0; it < 4; it++) {
            int chunk = it * 8 + wid;
            int o = chunk * 1024 + lane * 16;
            int m = o >> 7, inrow = o & 127;
            GLOAD(Al + chunk * 1024, (const char*)vbuf + (size_t)(m0 + m) * 2048 + (size_t)k0 * 2 + inrow);
            GLOAD(Bl + chunk * 1024, (const char*)wlT + (size_t)(n0 + m) * 2048 + (size_t)k0 * 2 + inrow);
        }
        __syncthreads();
        #pragma unroll
        for (int kf = 0; kf < 2; kf++) {
            bf16x8 a[8], bb[4];
            #pragma unroll
            for (int mf = 0; mf < 8; mf++)
                a[mf] = *(const bf16x8*)(Al + (wr * 128 + mf * 16 + l15) * 128 + kf * 64 + l4 * 16);
            #pragma unroll
            for (int nf = 0; nf < 4; nf++)
                bb[nf] = *(const bf16x8*)(Bl + (wc * 64 + nf * 16 + l15) * 128 + kf * 64 + l4 * 16);
            #pragma unroll
            for (int mf = 0; mf < 8; mf++)
                #pragma unroll
                for (int nf = 0; nf < 4; nf++)
                    acc[mf][nf] = __builtin_amdgcn_mfma_f32_16x16x32_bf16(a[mf], bb[nf], acc[mf][nf], 0, 0, 0);
        }
    }

    #pragma unroll
    for (int mf = 0; mf < 8; mf++) {
        int mrow = wr * 128 + mf * 16 + l4 * 4;
        #pragma unroll
        for (int r = 0; r < 4; r++) {
            float inv = invnS[mrow + r];
            int p = (mrow + r) >> 6;
            float s = 0.f;
            #pragma unroll
            for (int nf = 0; nf < 4; nf++) {
                int el = wc * 64 + nf * 16 + l15;
                float x = acc[mf][nf][r] * inv + blS[el];
                s += ftanh(x) * g2S[p * 256 + el];
            }
            s += __shfl_xor(s, 1);
            s += __shfl_xor(s, 2);
            s += __shfl_xor(s, 4);
            s += __shfl_xor(s, 8);
            if (l15 == 0)
                wspart[(size_t)(nt * 4 + wc) * 65536 + m0 + mrow + r] = s;
        }
    }
}

// ---------------------------------------------------------------------------
// k_sa2: per pair: w[q] -> softmax -> new_global -> l2norm -> sigmoid -> out
// ---------------------------------------------------------------------------
__global__ __launch_bounds__(256) void k_sa2(
    const float* __restrict__ wspart, const float* __restrict__ invn_ws,
    const u16* __restrict__ vbuf, const float* __restrict__ capw,
    const float* __restrict__ capb, float* __restrict__ out)
{
    const int pair = blockIdx.x;
    const u16* vb = vbuf + (size_t)pair * 65536;

    __shared__ float wiS[64];
    __shared__ float red[8];

    const int tid = threadIdx.x;

    if (tid < 64) {
        float x = 0.f;
        #pragma unroll
        for (int c = 0; c < 16; c++) x += wspart[(size_t)c * 65536 + pair * 64 + tid];
        float m = x;
        #pragma unroll
        for (int mk = 1; mk < 64; mk <<= 1) m = fmaxf(m, __shfl_xor(m, mk));
        float e = __expf(x - m);
        float Z = e;
        #pragma unroll
        for (int mk = 1; mk < 64; mk <<= 1) Z += __shfl_xor(Z, mk);
        wiS[tid] = (e / Z) * invn_ws[pair * 64 + tid];
    }
    __syncthreads();

    float s1 = 0.f, s2 = 0.f;
    for (int d = tid; d < D_DIM; d += 256) {
        float ng = 0.f;
        for (int q = 0; q < 64; q++) ng = fmaf(wiS[q], b2f(vb[(size_t)q * 1024 + d]), ng);
        s1 = fmaf(ng, capw[d], s1);
        s2 = fmaf(ng, ng, s2);
    }
    #pragma unroll
    for (int mk = 1; mk < 64; mk <<= 1) { s1 += __shfl_xor(s1, mk); s2 += __shfl_xor(s2, mk); }
    if ((tid & 63) == 0) { red[tid >> 6] = s1; red[4 + (tid >> 6)] = s2; }
    __syncthreads();
    if (tid == 0) {
        float S1 = red[0] + red[1] + red[2] + red[3];
        float S2 = red[4] + red[5] + red[6] + red[7];
        float val = S1 / (sqrtf(S2) + 1e-8f) + capb[0];
        out[pair] = 1.f / (1.f + __expf(-val));
    }
}

// ---------------------------------------------------------------------------
extern "C" void kernel_launch(void* const* d_in, const int* in_sizes, int n_in,
                              void* d_out, int out_size, void* d_ws, size_t ws_size,
                              hipStream_t stream)
{
    const float* feat_l = (const float*)d_in[0];
    const float* feat_f = (const float*)d_in[1];
    const float* words  = (const float*)d_in[2];
    const float* conv_w = (const float*)d_in[3];
    const float* conv_b = (const float*)d_in[4];
    const float* sa_wl  = (const float*)d_in[5];
    const float* sa_bl  = (const float*)d_in[6];
    const float* sa_wg  = (const float*)d_in[7];
    const float* sa_bg  = (const float*)d_in[8];
    const float* sa_wc  = (const float*)d_in[9];
    // d_in[10] = sa_bc: constant pre-softmax shift -> result-invariant
    const float* cap_w  = (const float*)d_in[11];
    const float* cap_b  = (const float*)d_in[12];
    float* out = (float*)d_out;

    char* ws = (char*)d_ws;
    // Overlay layout (bytes), peak 253,657,088 (< 253,820,928 known-safe):
    //   [0,134.2M): featT_hi@0, featT_lo@33.5M (prepf->convG);
    //               imgT_hi@67.1M, imgT_lo@100.7M (trans->kL); vbuf@0 (kW->sa2)
    //   [134.2M,167.8M): img_hi (convG->kW)
    //   [167.8M,234.9M): img_lo@167.8M (convG->trans); U@167.8M (kL->kW);
    //                    wspart@167.8M (saG->sa2)
    //   [234.9M,243.3M): wT_hi, wT_lo (prepw->kW); simave@234.9M (post->g2)
    //   [243.3M,247.5M): cw_hi,cw_lo (prepcw->convG); then Zp@243.3M,
    //                    invZf@245.37M, ssqp@245.63M, invn@246.68M
    //   [247.5M,249.6M): wlT ; [249.6M,253.7M): g2
    u16*   featT_hi = (u16*)(ws);
    u16*   featT_lo = (u16*)(ws + 33554432);
    u16*   imgT_hi  = (u16*)(ws + 67108864);
    u16*   imgT_lo  = (u16*)(ws + 100663296);
    u16*   vbuf     = (u16*)(ws);
    u16*   img_hi   = (u16*)(ws + 134217728);
    u16*   img_lo   = (u16*)(ws + 167772160);
    u16*   U        = (u16*)(ws + 167772160);
    float* wspart   = (float*)(ws + 167772160);
    u16*   wT_hi    = (u16*)(ws + 234881024);
    float* simave   = (float*)(ws + 234881024);
    u16*   wT_lo    = (u16*)(ws + 239075328);
    u16*   cw_hi    = (u16*)(ws + 243269632);
    float* Zp       = (float*)(ws + 243269632);
    u16*   cw_lo    = (u16*)(ws + 245366784);
    float* invZf    = (float*)(ws + 245366784);
    float* ssqp     = (float*)(ws + 245628928);
    float* invn     = (float*)(ws + 246677504);
    u16*   wlT      = (u16*)(ws + 247463936);
    float* g2       = (float*)(ws + 249561088);

    hipLaunchKernelGGL(k_prepf, dim3(4096), dim3(256), 0, stream,
                       feat_l, feat_f, featT_hi, featT_lo);
    hipLaunchKernelGGL(k_prepcw, dim3(1024), dim3(256), 0, stream,
                       conv_w, cw_hi, cw_lo);
    hipLaunchKernelGGL(k_prepw, dim3(512), dim3(256), 0, stream,
                       words, wT_hi, wT_lo);
    hipLaunchKernelGGL(k_prep, dim3(256), dim3(256), 0, stream, sa_wl, wlT);
    hipLaunchKernelGGL(k_convG, dim3(256), dim3(512), 0, stream,
                       featT_hi, featT_lo, cw_hi, cw_lo, conv_b, img_hi, img_lo);
    hipLaunchKernelGGL(k_trans, dim3(4096), dim3(256), 0, stream,
                       img_hi, img_lo, imgT_hi, imgT_lo);
    hipLaunchKernelGGL(k_logits, dim3(512), dim3(512), 0, stream,
                       wT_hi, wT_lo, imgT_hi, imgT_lo, U, Zp, out);
    hipLaunchKernelGGL(k_zred, dim3(256), dim3(256), 0, stream, Zp, invZf);
    hipLaunchKernelGGL(k_attmap2, dim3(32), dim3(256), 0, stream, out);
    hipLaunchKernelGGL(k_wctx, dim3(1024), dim3(512), 0, stream,
                       img_hi, U, invZf, wT_hi, wT_lo, vbuf, ssqp);
    hipLaunchKernelGGL(k_post, dim3(1024), dim3(256), 0, stream,
                       vbuf, ssqp, invn, simave);
    hipLaunchKernelGGL(k_g2, dim3(256), dim3(256), 0, stream,
                       simave, sa_wg, sa_bg, sa_wc, g2);
    hipLaunchKernelGGL(k_saG, dim3(1024), dim3(512), 0, stream,
                       vbuf, wlT, invn, g2, sa_bl, wspart);
    hipLaunchKernelGGL(k_sa2, dim3(1024), dim3(256), 0, stream,
                       wspart, invn, vbuf, cap_w, cap_b, out);
}

// Round 6
// 835.705 us; speedup vs baseline: 7.8593x; 1.2272x over previous
//
#include <hip/hip_runtime.h>
#include <cstdint>

typedef unsigned short u16;
typedef unsigned int   u32;
typedef __attribute__((ext_vector_type(8))) short bf16x8;
typedef __attribute__((ext_vector_type(4))) float f32x4;

#define D_DIM 1000
#define C_IN  1024
#define HW    256
#define S_DIM 512
#define Q_DIM 64

__device__ __forceinline__ u16 f2b(float x) {
    u32 u = __builtin_bit_cast(u32, x);
    u32 r = (u + 0x7FFFu + ((u >> 16) & 1u)) >> 16;
    return (u16)r;
}
__device__ __forceinline__ float b2f(u16 h) {
    u32 u = ((u32)h) << 16;
    return __builtin_bit_cast(float, u);
}
__device__ __forceinline__ float ftanh(float x) {
    float e = __expf(2.f * x);
    return 1.f - 2.f / (e + 1.f);
}

#define GLOAD(ldsptr, gptr) \
    __builtin_amdgcn_global_load_lds( \
        (const __attribute__((address_space(1))) unsigned int*)(gptr), \
        (__attribute__((address_space(3))) unsigned int*)(ldsptr), 16, 0, 0)

// ---------------------------------------------------------------------------
// k_prepf: feat [b][1024 c][256 hw] fp32 -> featT_hi/lo bf16 [b][512 s][1024 c]
// ---------------------------------------------------------------------------
__global__ __launch_bounds__(256) void k_prepf(
    const float* __restrict__ feat_l, const float* __restrict__ feat_f,
    u16* __restrict__ fT_hi, u16* __restrict__ fT_lo)
{
    int bid = blockIdx.x;
    int ct = bid & 15, ht = (bid >> 4) & 3, half_ = (bid >> 6) & 1, b = bid >> 7;
    const float* src = (half_ ? feat_l : feat_f) + (size_t)b * C_IN * HW;
    __shared__ float T[64][65];
    int tid = threadIdx.x;
    {
        int cl = tid >> 2, h16 = (tid & 3) * 16;
        const float* p = src + (size_t)(ct * 64 + cl) * 256 + ht * 64 + h16;
        #pragma unroll
        for (int j = 0; j < 4; j++) {
            float4 v = *(const float4*)(p + j * 4);
            T[h16 + j * 4 + 0][cl] = v.x;
            T[h16 + j * 4 + 1][cl] = v.y;
            T[h16 + j * 4 + 2][cl] = v.z;
            T[h16 + j * 4 + 3][cl] = v.w;
        }
    }
    __syncthreads();
    {
        int hl = tid >> 2, c16 = (tid & 3) * 16;
        int srow = b * 512 + half_ * 256 + ht * 64 + hl;
        bf16x8 vh[2], vl[2];
        #pragma unroll
        for (int g = 0; g < 2; g++)
            #pragma unroll
            for (int j = 0; j < 8; j++) {
                float x = T[hl][c16 + g * 8 + j];
                u16 hh = f2b(x);
                vh[g][j] = (short)hh;
                vl[g][j] = (short)f2b(x - b2f(hh));
            }
        size_t o = (size_t)srow * 1024 + ct * 64 + c16;
        *(bf16x8*)(fT_hi + o) = vh[0];
        *(bf16x8*)(fT_hi + o + 8) = vh[1];
        *(bf16x8*)(fT_lo + o) = vl[0];
        *(bf16x8*)(fT_lo + o + 8) = vl[1];
    }
}

// ---------------------------------------------------------------------------
// k_prepcw: cw [1000][1024] fp32 -> cw_hi/lo [1024][1024] bf16
// ---------------------------------------------------------------------------
__global__ __launch_bounds__(256) void k_prepcw(
    const float* __restrict__ cw, u16* __restrict__ cwh, u16* __restrict__ cwl)
{
    int d = blockIdx.x;
    int c4 = threadIdx.x * 4;
    ushort4 h = make_ushort4(0, 0, 0, 0), lo = make_ushort4(0, 0, 0, 0);
    if (d < D_DIM) {
        float4 v = *(const float4*)(cw + (size_t)d * 1024 + c4);
        float a[4] = {v.x, v.y, v.z, v.w};
        u16* ph = (u16*)&h; u16* pl = (u16*)&lo;
        #pragma unroll
        for (int j = 0; j < 4; j++) {
            ph[j] = f2b(a[j]);
            pl[j] = f2b(a[j] - b2f(ph[j]));
        }
    }
    *(ushort4*)(cwh + (size_t)d * 1024 + c4) = h;
    *(ushort4*)(cwl + (size_t)d * 1024 + c4) = lo;
}

// ---------------------------------------------------------------------------
// k_prepw: words [i][1000 d][64 q] fp32 -> wT_hi/lo bf16 [i][64 q][1024 d]
// ---------------------------------------------------------------------------
__global__ __launch_bounds__(256) void k_prepw(
    const float* __restrict__ words, u16* __restrict__ wth, u16* __restrict__ wtl)
{
    int i = blockIdx.x >> 4, dt = blockIdx.x & 15;
    const float* src = words + (size_t)i * D_DIM * Q_DIM;
    __shared__ u16 Th[64][72], Tl[64][72];
    int tid = threadIdx.x;
    #pragma unroll
    for (int rep = 0; rep < 4; rep++) {
        int idx = tid + rep * 256;
        int dl = idx >> 4, q4 = (idx & 15) * 4;
        int d = dt * 64 + dl;
        float4 v = make_float4(0.f, 0.f, 0.f, 0.f);
        if (d < D_DIM) v = *(const float4*)(src + (size_t)d * Q_DIM + q4);
        float a[4] = {v.x, v.y, v.z, v.w};
        #pragma unroll
        for (int jj = 0; jj < 4; jj++) {
            u16 hh = f2b(a[jj]);
            Th[dl][q4 + jj] = hh;
            Tl[dl][q4 + jj] = f2b(a[jj] - b2f(hh));
        }
    }
    __syncthreads();
    #pragma unroll
    for (int rep = 0; rep < 2; rep++) {
        int idx = tid + rep * 256;
        int q = idx >> 3, c8 = idx & 7;
        bf16x8 vh, vl;
        #pragma unroll
        for (int jj = 0; jj < 8; jj++) { vh[jj] = (short)Th[c8 * 8 + jj][q]; vl[jj] = (short)Tl[c8 * 8 + jj][q]; }
        size_t doff = (size_t)i * 65536 + (size_t)q * 1024 + dt * 64 + c8 * 8;
        *(bf16x8*)(wth + doff) = vh;
        *(bf16x8*)(wtl + doff) = vl;
    }
}

// ---------------------------------------------------------------------------
// k_prep: T[e][d] = bf16(W[d][e]); [1024][1024], zero-padded. (used for wl AND wg)
// ---------------------------------------------------------------------------
__global__ __launch_bounds__(256) void k_prep(const float* __restrict__ wl, u16* __restrict__ wlT)
{
    __shared__ float t[64][65];
    int bd = blockIdx.x & 15, be = blockIdx.x >> 4;
    int tx = threadIdx.x & 15, ty = threadIdx.x >> 4;
    #pragma unroll
    for (int rr = 0; rr < 4; rr++) {
        int r = ty * 4 + rr;
        int d = bd * 64 + r;
        int e4 = be * 64 + tx * 4;
        float v0 = 0.f, v1 = 0.f, v2 = 0.f, v3 = 0.f;
        if (d < D_DIM) {
            if (e4 + 3 < D_DIM) {
                float4 v = *reinterpret_cast<const float4*>(wl + (size_t)d * D_DIM + e4);
                v0 = v.x; v1 = v.y; v2 = v.z; v3 = v.w;
            } else {
                if (e4 + 0 < D_DIM) v0 = wl[(size_t)d * D_DIM + e4 + 0];
                if (e4 + 1 < D_DIM) v1 = wl[(size_t)d * D_DIM + e4 + 1];
                if (e4 + 2 < D_DIM) v2 = wl[(size_t)d * D_DIM + e4 + 2];
                if (e4 + 3 < D_DIM) v3 = wl[(size_t)d * D_DIM + e4 + 3];
            }
        }
        t[r][tx * 4 + 0] = v0; t[r][tx * 4 + 1] = v1;
        t[r][tx * 4 + 2] = v2; t[r][tx * 4 + 3] = v3;
    }
    __syncthreads();
    #pragma unroll
    for (int rr = 0; rr < 4; rr++) {
        int r2 = ty * 4 + rr;
        int e = be * 64 + r2;
        int d0 = bd * 64 + tx * 4;
        ushort4 h;
        h.x = f2b(t[tx * 4 + 0][r2]); h.y = f2b(t[tx * 4 + 1][r2]);
        h.z = f2b(t[tx * 4 + 2][r2]); h.w = f2b(t[tx * 4 + 3][r2]);
        *reinterpret_cast<ushort4*>(wlT + (size_t)e * 1024 + d0) = h;
    }
}

// ---------------------------------------------------------------------------
// k_convG: img = featT . cw^T (split-bf16 3-pass) + cb.  BK=32, XOR-swizzled LDS.
// ---------------------------------------------------------------------------
__global__ __launch_bounds__(512) void k_convG(
    const u16* __restrict__ fT_hi, const u16* __restrict__ fT_lo,
    const u16* __restrict__ cwh, const u16* __restrict__ cwl,
    const float* __restrict__ cb,
    u16* __restrict__ img_hi, u16* __restrict__ img_lo)
{
    const int bid = blockIdx.x;
    const int mblk = bid >> 2, nt = bid & 3;
    const int m0 = mblk * 256, n0 = nt * 256;

    __shared__ char Ah[16384] __attribute__((aligned(16)));
    __shared__ char Alo[16384] __attribute__((aligned(16)));
    __shared__ char Bh[16384] __attribute__((aligned(16)));
    __shared__ char Blo[16384] __attribute__((aligned(16)));
    __shared__ float cbS[256];

    const int tid = threadIdx.x;
    const int wid = tid >> 6, lane = tid & 63;
    const int wr = wid >> 2, wc = wid & 3;
    const int l15 = lane & 15, l4 = lane >> 4;
    const int sw = (l15 >> 1) & 3;

    if (tid < 256) {
        int d = n0 + tid;
        cbS[tid] = (d < D_DIM) ? cb[d] : 0.f;
    }

    f32x4 acc[8][4] = {};

    for (int k0 = 0; k0 < 1024; k0 += 32) {
        __syncthreads();
        #pragma unroll
        for (int rep = 0; rep < 2; rep++) {
            int idx = tid + rep * 512;
            int row = idx >> 2, slot = idx & 3;
            int kb = (slot ^ ((row >> 1) & 3)) * 16;
            size_t ao = (size_t)(m0 + row) * 2048 + (size_t)k0 * 2 + kb;
            size_t bo = (size_t)(n0 + row) * 2048 + (size_t)k0 * 2 + kb;
            GLOAD(Ah + idx * 16, (const char*)fT_hi + ao);
            GLOAD(Alo + idx * 16, (const char*)fT_lo + ao);
            GLOAD(Bh + idx * 16, (const char*)cwh + bo);
            GLOAD(Blo + idx * 16, (const char*)cwl + bo);
        }
        __syncthreads();
        bf16x8 ah[8], bh[4];
        #pragma unroll
        for (int mf = 0; mf < 8; mf++)
            ah[mf] = *(const bf16x8*)(Ah + (wr * 128 + mf * 16 + l15) * 64 + ((l4 ^ sw) * 16));
        #pragma unroll
        for (int nf = 0; nf < 4; nf++)
            bh[nf] = *(const bf16x8*)(Bh + (wc * 64 + nf * 16 + l15) * 64 + ((l4 ^ sw) * 16));
        #pragma unroll
        for (int mf = 0; mf < 8; mf++)
            #pragma unroll
            for (int nf = 0; nf < 4; nf++)
                acc[mf][nf] = __builtin_amdgcn_mfma_f32_16x16x32_bf16(ah[mf], bh[nf], acc[mf][nf], 0, 0, 0);
        #pragma unroll
        for (int mf = 0; mf < 8; mf++) {
            bf16x8 al = *(const bf16x8*)(Alo + (wr * 128 + mf * 16 + l15) * 64 + ((l4 ^ sw) * 16));
            #pragma unroll
            for (int nf = 0; nf < 4; nf++)
                acc[mf][nf] = __builtin_amdgcn_mfma_f32_16x16x32_bf16(al, bh[nf], acc[mf][nf], 0, 0, 0);
        }
        #pragma unroll
        for (int nf = 0; nf < 4; nf++) {
            bf16x8 bl = *(const bf16x8*)(Blo + (wc * 64 + nf * 16 + l15) * 64 + ((l4 ^ sw) * 16));
            #pragma unroll
            for (int mf = 0; mf < 8; mf++)
                acc[mf][nf] = __builtin_amdgcn_mfma_f32_16x16x32_bf16(ah[mf], bl, acc[mf][nf], 0, 0, 0);
        }
    }
    const int b = m0 >> 9;
    const int sbase = m0 & 511;
    #pragma unroll
    for (int mf = 0; mf < 8; mf++) {
        int srow = sbase + wr * 128 + mf * 16 + l4 * 4;
        #pragma unroll
        for (int nf = 0; nf < 4; nf++) {
            int dcol = n0 + wc * 64 + nf * 16 + l15;
            float bias = cbS[wc * 64 + nf * 16 + l15];
            ushort4 h4, lo4;
            u16* ph = (u16*)&h4; u16* pl = (u16*)&lo4;
            #pragma unroll
            for (int r = 0; r < 4; r++) {
                float v = acc[mf][nf][r] + bias;
                u16 hh = f2b(v);
                ph[r] = hh;
                pl[r] = f2b(v - b2f(hh));
            }
            size_t off = ((size_t)b * 1024 + dcol) * 512 + srow;
            *(ushort4*)(img_hi + off) = h4;
            *(ushort4*)(img_lo + off) = lo4;
        }
    }
}

// ---------------------------------------------------------------------------
// k_trans: img_hi/lo [b][1024 d][512 s] -> imgT_hi/lo [b][512 s][1024 d]
// ---------------------------------------------------------------------------
__global__ __launch_bounds__(256) void k_trans(
    const u16* __restrict__ ih, const u16* __restrict__ il,
    u16* __restrict__ oth, u16* __restrict__ otl)
{
    int bid = blockIdx.x;
    int st = bid & 7, dt = (bid >> 3) & 15, b = bid >> 7;
    const u16* srcH = ih + (size_t)b * 1024 * 512;
    const u16* srcL = il + (size_t)b * 1024 * 512;
    u16* dstH = oth + (size_t)b * 512 * 1024;
    u16* dstL = otl + (size_t)b * 512 * 1024;
    __shared__ u16 Th[64][72], Tl[64][72];
    int tid = threadIdx.x;
    #pragma unroll
    for (int rep = 0; rep < 2; rep++) {
        int idx = tid + rep * 256;
        int dl = idx >> 3, c8 = idx & 7;
        size_t so = (size_t)(dt * 64 + dl) * 512 + st * 64 + c8 * 8;
        bf16x8 vh = *(const bf16x8*)(srcH + so);
        bf16x8 vl = *(const bf16x8*)(srcL + so);
        #pragma unroll
        for (int jj = 0; jj < 8; jj++) { Th[c8 * 8 + jj][dl] = (u16)vh[jj]; Tl[c8 * 8 + jj][dl] = (u16)vl[jj]; }
    }
    __syncthreads();
    #pragma unroll
    for (int rep = 0; rep < 2; rep++) {
        int idx = tid + rep * 256;
        int sl = idx >> 3, c8 = idx & 7;
        bf16x8 vh = *(const bf16x8*)(&Th[sl][c8 * 8]);
        bf16x8 vl = *(const bf16x8*)(&Tl[sl][c8 * 8]);
        size_t doff = (size_t)(st * 64 + sl) * 1024 + dt * 64 + c8 * 8;
        *(bf16x8*)(dstH + doff) = vh;
        *(bf16x8*)(dstL + doff) = vl;
    }
}

// ---------------------------------------------------------------------------
// k_logits: per b: C[iq][s] = wT . imgT^T (3-pass split), softmax over q,
// U -> global, Zp partials, diag u -> out.  BK=32, XOR-swizzled LDS.
// ---------------------------------------------------------------------------
__global__ __launch_bounds__(512) void k_logits(
    const u16* __restrict__ wTh, const u16* __restrict__ wTl,
    const u16* __restrict__ iTh, const u16* __restrict__ iTl,
    u16* __restrict__ U, float* __restrict__ Zp, float* __restrict__ out)
{
    const int bid = blockIdx.x;
    const int b = bid >> 4, mt = (bid >> 1) & 7, nt = bid & 1;
    const int m0 = mt * 256, n0 = nt * 256;

    __shared__ char Ah[16384] __attribute__((aligned(16)));
    __shared__ char Alo[16384] __attribute__((aligned(16)));
    __shared__ char Bh[16384] __attribute__((aligned(16)));
    __shared__ char Blo[16384] __attribute__((aligned(16)));

    const int tid = threadIdx.x;
    const int wid = tid >> 6, lane = tid & 63;
    const int wr = wid >> 2, wc = wid & 3;
    const int l15 = lane & 15, l4 = lane >> 4;
    const int sw = (l15 >> 1) & 3;

    f32x4 acc[8][4] = {};

    for (int k0 = 0; k0 < 1024; k0 += 32) {
        __syncthreads();
        #pragma unroll
        for (int rep = 0; rep < 2; rep++) {
            int idx = tid + rep * 512;
            int row = idx >> 2, slot = idx & 3;
            int kb = (slot ^ ((row >> 1) & 3)) * 16;
            size_t ao = (size_t)(m0 + row) * 2048 + (size_t)k0 * 2 + kb;
            size_t bo = ((size_t)b * 512 + n0 + row) * 2048 + (size_t)k0 * 2 + kb;
            GLOAD(Ah + idx * 16, (const char*)wTh + ao);
            GLOAD(Alo + idx * 16, (const char*)wTl + ao);
            GLOAD(Bh + idx * 16, (const char*)iTh + bo);
            GLOAD(Blo + idx * 16, (const char*)iTl + bo);
        }
        __syncthreads();
        bf16x8 ah[8], bh[4];
        #pragma unroll
        for (int mf = 0; mf < 8; mf++)
            ah[mf] = *(const bf16x8*)(Ah + (wr * 128 + mf * 16 + l15) * 64 + ((l4 ^ sw) * 16));
        #pragma unroll
        for (int nf = 0; nf < 4; nf++)
            bh[nf] = *(const bf16x8*)(Bh + (wc * 64 + nf * 16 + l15) * 64 + ((l4 ^ sw) * 16));
        #pragma unroll
        for (int mf = 0; mf < 8; mf++)
            #pragma unroll
            for (int nf = 0; nf < 4; nf++)
                acc[mf][nf] = __builtin_amdgcn_mfma_f32_16x16x32_bf16(ah[mf], bh[nf], acc[mf][nf], 0, 0, 0);
        #pragma unroll
        for (int mf = 0; mf < 8; mf++) {
            bf16x8 al = *(const bf16x8*)(Alo + (wr * 128 + mf * 16 + l15) * 64 + ((l4 ^ sw) * 16));
            #pragma unroll
            for (int nf = 0; nf < 4; nf++)
                acc[mf][nf] = __builtin_amdgcn_mfma_f32_16x16x32_bf16(al, bh[nf], acc[mf][nf], 0, 0, 0);
        }
        #pragma unroll
        for (int nf = 0; nf < 4; nf++) {
            bf16x8 bl = *(const bf16x8*)(Blo + (wc * 64 + nf * 16 + l15) * 64 + ((l4 ^ sw) * 16));
            #pragma unroll
            for (int mf = 0; mf < 8; mf++)
                acc[mf][nf] = __builtin_amdgcn_mfma_f32_16x16x32_bf16(ah[mf], bl, acc[mf][nf], 0, 0, 0);
        }
    }

    float zacc[8][4] = {};
    #pragma unroll
    for (int il = 0; il < 2; il++) {
        int i_glob = mt * 4 + wr * 2 + il;
        bool diag = (i_glob == b);
        #pragma unroll
        for (int nf = 0; nf < 4; nf++) {
            int scol = n0 + wc * 64 + nf * 16 + l15;
            float m = -3.4e38f;
            #pragma unroll
            for (int mm = 0; mm < 4; mm++)
                #pragma unroll
                for (int r = 0; r < 4; r++)
                    m = fmaxf(m, acc[il * 4 + mm][nf][r]);
            m = fmaxf(m, __shfl_xor(m, 16));
            m = fmaxf(m, __shfl_xor(m, 32));
            float e[16], sum = 0.f;
            #pragma unroll
            for (int mm = 0; mm < 4; mm++)
                #pragma unroll
                for (int r = 0; r < 4; r++) {
                    float ev = __expf(acc[il * 4 + mm][nf][r] - m);
                    e[mm * 4 + r] = ev; sum += ev;
                }
            sum += __shfl_xor(sum, 16);
            sum += __shfl_xor(sum, 32);
            float inv = 1.f / sum;
            #pragma unroll
            for (int mm = 0; mm < 4; mm++)
                #pragma unroll
                for (int r = 0; r < 4; r++) {
                    float u = __expf(4.f * e[mm * 4 + r] * inv);   // in [1, e^4]
                    u16 ub = f2b(u);
                    zacc[il * 4 + mm][r] += b2f(ub);
                    int iqrow = m0 + wr * 128 + (il * 4 + mm) * 16 + l4 * 4 + r;
                    U[((size_t)b * 2048 + iqrow) * 512 + scol] = ub;
                    if (diag) {
                        int q = iqrow & 63;
                        out[1024 + ((size_t)i_glob * 64 + q) * 512 + scol] = u;
                    }
                }
        }
    }
    #pragma unroll
    for (int mf = 0; mf < 8; mf++)
        #pragma unroll
        for (int r = 0; r < 4; r++) {
            float z = zacc[mf][r];
            z += __shfl_xor(z, 1); z += __shfl_xor(z, 2);
            z += __shfl_xor(z, 4); z += __shfl_xor(z, 8);
            if (l15 == 0) {
                int iqrow = m0 + wr * 128 + mf * 16 + l4 * 4 + r;
                Zp[((size_t)b * 2048 + iqrow) * 8 + nt * 4 + wc] = z;
            }
        }
}

// k_zred: invZf[gi] = 1 / sum of 8 Zp partials
__global__ __launch_bounds__(256) void k_zred(const float* __restrict__ Zp, float* __restrict__ invZf)
{
    int gi = blockIdx.x * 256 + threadIdx.x;
    float4 z0 = *(const float4*)(Zp + (size_t)gi * 8);
    float4 z1 = *(const float4*)(Zp + (size_t)gi * 8 + 4);
    invZf[gi] = 1.f / (z0.x + z0.y + z0.z + z0.w + z1.x + z1.y + z1.z + z1.w);
}

// normalize att_maps rows in place. 32 blocks.
__global__ __launch_bounds__(256) void k_attmap2(float* __restrict__ out)
{
    const int i = blockIdx.x;
    float* am = out + 1024 + (size_t)i * Q_DIM * S_DIM;
    int q = threadIdx.x >> 2, ch = threadIdx.x & 3;
    float s = 0.f;
    for (int ss = ch * 128; ss < ch * 128 + 128; ss++) s += am[(size_t)q * S_DIM + ss];
    s += __shfl_xor(s, 1);
    s += __shfl_xor(s, 2);
    float iz = 1.f / s;
    for (int ss = ch * 128; ss < ch * 128 + 128; ss++) am[(size_t)q * S_DIM + ss] *= iz;
}

// ---------------------------------------------------------------------------
// k_wctx: per b: C[d][iq] = img_hi . U^T, K=512, BK=64, XOR-swizzled.
// Epilogue: v = acc*invZ*(wThi+wTlo) -> vbuf bf16; ssq partials.
// ---------------------------------------------------------------------------
__global__ __launch_bounds__(512) void k_wctx(
    const u16* __restrict__ img_hi, const u16* __restrict__ U,
    const float* __restrict__ invZf,
    const u16* __restrict__ wTh, const u16* __restrict__ wTl,
    u16* __restrict__ vbuf, float* __restrict__ ssqp)
{
    const int bid = blockIdx.x;
    const int b = bid >> 5, mt = (bid >> 3) & 3, nt = bid & 7;
    const int m0 = mt * 256, n0 = nt * 256;

    __shared__ char At[32768] __attribute__((aligned(16)));
    __shared__ char Bt[32768] __attribute__((aligned(16)));
    __shared__ float izS[256];

    const int tid = threadIdx.x;
    const int wid = tid >> 6, lane = tid & 63;
    const int wr = wid >> 2, wc = wid & 3;
    const int l15 = lane & 15, l4 = lane >> 4;
    const int sw = l15 & 7;

    if (tid < 256) izS[tid] = invZf[b * 2048 + n0 + tid];

    f32x4 acc[8][4] = {};

    for (int k0 = 0; k0 < 512; k0 += 64) {
        __syncthreads();
        #pragma unroll
        for (int rep = 0; rep < 4; rep++) {
            int idx = tid + rep * 512;
            int row = idx >> 3, slot = idx & 7;
            int kb = (slot ^ (row & 7)) * 16;
            GLOAD(At + idx * 16, (const char*)img_hi + ((size_t)b * 1024 + m0 + row) * 1024 + (size_t)k0 * 2 + kb);
            GLOAD(Bt + idx * 16, (const char*)U + ((size_t)b * 2048 + n0 + row) * 1024 + (size_t)k0 * 2 + kb);
        }
        __syncthreads();
        #pragma unroll
        for (int kf = 0; kf < 2; kf++) {
            bf16x8 a[8], bb[4];
            #pragma unroll
            for (int mf = 0; mf < 8; mf++)
                a[mf] = *(const bf16x8*)(At + (wr * 128 + mf * 16 + l15) * 128 + (((kf * 4 + l4) ^ sw) * 16));
            #pragma unroll
            for (int nf = 0; nf < 4; nf++)
                bb[nf] = *(const bf16x8*)(Bt + (wc * 64 + nf * 16 + l15) * 128 + (((kf * 4 + l4) ^ sw) * 16));
            #pragma unroll
            for (int mf = 0; mf < 8; mf++)
                #pragma unroll
                for (int nf = 0; nf < 4; nf++)
                    acc[mf][nf] = __builtin_amdgcn_mfma_f32_16x16x32_bf16(a[mf], bb[nf], acc[mf][nf], 0, 0, 0);
        }
    }

    #pragma unroll
    for (int nf = 0; nf < 4; nf++) {
        int col = wc * 64 + nf * 16 + l15;
        int iq = n0 + col;
        float iz = izS[col];
        size_t wtoff = (size_t)iq * 1024;
        float s_nf = 0.f;
        #pragma unroll
        for (int mf = 0; mf < 8; mf++) {
            int d0 = m0 + wr * 128 + mf * 16 + l4 * 4;
            ushort4 wh = *(const ushort4*)(wTh + wtoff + d0);
            ushort4 wl = *(const ushort4*)(wTl + wtoff + d0);
            const u16* pwh = (const u16*)&wh;
            const u16* pwl = (const u16*)&wl;
            ushort4 vo;
            u16* pv = (u16*)&vo;
            #pragma unroll
            for (int r = 0; r < 4; r++) {
                float wv = b2f(pwh[r]) + b2f(pwl[r]);
                float v = acc[mf][nf][r] * iz * wv;
                s_nf = fmaf(v, v, s_nf);
                pv[r] = f2b(v);
            }
            *(ushort4*)(vbuf + ((size_t)b * 2048 + iq) * 1024 + d0) = vo;
        }
        s_nf += __shfl_xor(s_nf, 16);
        s_nf += __shfl_xor(s_nf, 32);
        if (l4 == 0) ssqp[((size_t)b * 2048 + iq) * 4 + mt] = s_nf;
    }
}

// ---------------------------------------------------------------------------
// k_post: per pair: invn from ssqp; simave_bf16[pair][1024] = mean_q v*invn
// ---------------------------------------------------------------------------
__global__ __launch_bounds__(256) void k_post(
    const u16* __restrict__ vbuf, const float* __restrict__ ssqp,
    float* __restrict__ invn_ws, u16* __restrict__ simave_bf)
{
    const int pair = blockIdx.x;
    __shared__ float invnS[64];
    const int tid = threadIdx.x;
    if (tid < 64) {
        size_t o = ((size_t)pair * 64 + tid) * 4;
        float s = ssqp[o] + ssqp[o + 1] + ssqp[o + 2] + ssqp[o + 3];
        float n = 1.f / (sqrtf(s) + 1e-8f);
        invnS[tid] = n;
        invn_ws[pair * 64 + tid] = n;
    }
    __syncthreads();
    int d0 = tid * 4;
    ushort4 o4 = make_ushort4(0, 0, 0, 0);
    if (d0 < D_DIM) {
        float a0 = 0.f, a1 = 0.f, a2 = 0.f, a3 = 0.f;
        const u16* vb = vbuf + (size_t)pair * 65536;
        for (int q = 0; q < 64; q++) {
            float n = invnS[q];
            ushort4 v = *(const ushort4*)(vb + q * 1024 + d0);
            a0 = fmaf(b2f(v.x), n, a0); a1 = fmaf(b2f(v.y), n, a1);
            a2 = fmaf(b2f(v.z), n, a2); a3 = fmaf(b2f(v.w), n, a3);
        }
        o4.x = f2b(a0 * (1.f / 64.f)); o4.y = f2b(a1 * (1.f / 64.f));
        o4.z = f2b(a2 * (1.f / 64.f)); o4.w = f2b(a3 * (1.f / 64.f));
    }
    *(ushort4*)(simave_bf + (size_t)pair * 1024 + d0) = o4;
}

// ---------------------------------------------------------------------------
// k_g2M: g2[p][e] = tanh(simave . wg + bg) * wc  via bf16 MFMA.
// M=1024 pairs, N=1024 e, K=1024 d. BK=64 swizzled. grid 16 blocks.
// ---------------------------------------------------------------------------
__global__ __launch_bounds__(512) void k_g2M(
    const u16* __restrict__ simave_bf, const u16* __restrict__ wgT,
    const float* __restrict__ bg, const float* __restrict__ wc,
    float* __restrict__ g2)
{
    const int mt = blockIdx.x >> 2, nt = blockIdx.x & 3;
    const int m0 = mt * 256, n0 = nt * 256;

    __shared__ char Al[32768] __attribute__((aligned(16)));
    __shared__ char Bl[32768] __attribute__((aligned(16)));
    __shared__ float bgS[256], wcS[256];

    const int tid = threadIdx.x;
    const int wid = tid >> 6, lane = tid & 63;
    const int wr = wid >> 2, wc_ = wid & 3;
    const int l15 = lane & 15, l4 = lane >> 4;
    const int sw = l15 & 7;

    if (tid < 256) {
        int e = n0 + tid;
        bgS[tid] = (e < D_DIM) ? bg[e] : 0.f;
        wcS[tid] = (e < D_DIM) ? wc[e] : 0.f;
    }

    f32x4 acc[8][4] = {};

    for (int k0 = 0; k0 < 1024; k0 += 64) {
        __syncthreads();
        #pragma unroll
        for (int rep = 0; rep < 4; rep++) {
            int idx = tid + rep * 512;
            int row = idx >> 3, slot = idx & 7;
            int kb = (slot ^ (row & 7)) * 16;
            GLOAD(Al + idx * 16, (const char*)simave_bf + (size_t)(m0 + row) * 2048 + (size_t)k0 * 2 + kb);
            GLOAD(Bl + idx * 16, (const char*)wgT + (size_t)(n0 + row) * 2048 + (size_t)k0 * 2 + kb);
        }
        __syncthreads();
        #pragma unroll
        for (int kf = 0; kf < 2; kf++) {
            bf16x8 a[8], bb[4];
            #pragma unroll
            for (int mf = 0; mf < 8; mf++)
                a[mf] = *(const bf16x8*)(Al + (wr * 128 + mf * 16 + l15) * 128 + (((kf * 4 + l4) ^ sw) * 16));
            #pragma unroll
            for (int nf = 0; nf < 4; nf++)
                bb[nf] = *(const bf16x8*)(Bl + (wc_ * 64 + nf * 16 + l15) * 128 + (((kf * 4 + l4) ^ sw) * 16));
            #pragma unroll
            for (int mf = 0; mf < 8; mf++)
                #pragma unroll
                for (int nf = 0; nf < 4; nf++)
                    acc[mf][nf] = __builtin_amdgcn_mfma_f32_16x16x32_bf16(a[mf], bb[nf], acc[mf][nf], 0, 0, 0);
        }
    }

    #pragma unroll
    for (int mf = 0; mf < 8; mf++) {
        int p = m0 + wr * 128 + mf * 16 + l4 * 4;
        #pragma unroll
        for (int nf = 0; nf < 4; nf++) {
            int cl = wc_ * 64 + nf * 16 + l15;
            float bgv = bgS[cl], wcv = wcS[cl];
            #pragma unroll
            for (int r = 0; r < 4; r++)
                g2[(size_t)(p + r) * 1024 + n0 + cl] = ftanh(acc[mf][nf][r] + bgv) * wcv;
        }
    }
}

// ---------------------------------------------------------------------------
// k_saG: flat GEMM M=65536 (vbuf rows), N=1024 (wlT rows), K=1024. BK=64
// swizzled; nt-fast + XCD-bijective block swizzle.
// ---------------------------------------------------------------------------
__global__ __launch_bounds__(512) void k_saG(
    const u16* __restrict__ vbuf, const u16* __restrict__ wlT,
    const float* __restrict__ invn_ws, const float* __restrict__ g2_ws,
    const float* __restrict__ bl, float* __restrict__ wspart)
{
    const int bid = blockIdx.x;
    const int wg = (bid & 7) * 128 + (bid >> 3);   // 1024 = 8 XCD chunks x 128
    const int mt = wg >> 2, nt = wg & 3;           // nt fast: A-tile reuse
    const int m0 = mt * 256, n0 = nt * 256;

    __shared__ char Al[32768] __attribute__((aligned(16)));
    __shared__ char Bl[32768] __attribute__((aligned(16)));
    __shared__ float invnS[256];
    __shared__ float blS[256];
    __shared__ float g2S[4 * 256];

    const int tid = threadIdx.x;
    const int wid = tid >> 6, lane = tid & 63;
    const int wr = wid >> 2, wc = wid & 3;
    const int l15 = lane & 15, l4 = lane >> 4;
    const int sw = l15 & 7;

    if (tid < 256) {
        invnS[tid] = invn_ws[m0 + tid];
        int e = n0 + tid;
        blS[tid] = (e < D_DIM) ? bl[e] : 0.f;
    }
    #pragma unroll
    for (int rep = 0; rep < 2; rep++) {
        int idx = tid + rep * 512;
        int p = idx >> 8, el = idx & 255;
        g2S[idx] = g2_ws[(size_t)((m0 >> 6) + p) * 1024 + n0 + el];
    }

    f32x4 acc[8][4] = {};

    for (int k0 = 0; k0 < 1024; k0 += 64) {
        __syncthreads();
        #pragma unroll
        for (int rep = 0; rep < 4; rep++) {
            int idx = tid + rep * 512;
            int row = idx >> 3, slot = idx & 7;
            int kb = (slot ^ (row & 7)) * 16;
            GLOAD(Al + idx * 16, (const char*)vbuf + (size_t)(m0 + row) * 2048 + (size_t)k0 * 2 + kb);
            GLOAD(Bl + idx * 16, (const char*)wlT + (size_t)(n0 + row) * 2048 + (size_t)k0 * 2 + kb);
        }
        __syncthreads();
        #pragma unroll
        for (int kf = 0; kf < 2; kf++) {
            bf16x8 a[8], bb[4];
            #pragma unroll
            for (int mf = 0; mf < 8; mf++)
                a[mf] = *(const bf16x8*)(Al + (wr * 128 + mf * 16 + l15) * 128 + (((kf * 4 + l4) ^ sw) * 16));
            #pragma unroll
            for (int nf = 0; nf < 4; nf++)
                bb[nf] = *(const bf16x8*)(Bl + (wc * 64 + nf * 16 + l15) * 128 + (((kf * 4 + l4) ^ sw) * 16));
            #pragma unroll
            for (int mf = 0; mf < 8; mf++)
                #pragma unroll
                for (int nf = 0; nf < 4; nf++)
                    acc[mf][nf] = __builtin_amdgcn_mfma_f32_16x16x32_bf16(a[mf], bb[nf], acc[mf][nf], 0, 0, 0);
        }
    }

    #pragma unroll
    for (int mf = 0; mf < 8; mf++) {
        int mrow = wr * 128 + mf * 16 + l4 * 4;
        #pragma unroll
        for (int r = 0; r < 4; r++) {
            float inv = invnS[mrow + r];
            int p = (mrow + r) >> 6;
            float s = 0.f;
            #pragma unroll
            for (int nf = 0; nf < 4; nf++) {
                int el = wc * 64 + nf * 16 + l15;
                float x = acc[mf][nf][r] * inv + blS[el];
                s += ftanh(x) * g2S[p * 256 + el];
            }
            s += __shfl_xor(s, 1);
            s += __shfl_xor(s, 2);
            s += __shfl_xor(s, 4);
            s += __shfl_xor(s, 8);
            if (l15 == 0)
                wspart[(size_t)(nt * 4 + wc) * 65536 + m0 + mrow + r] = s;
        }
    }
}

// ---------------------------------------------------------------------------
// k_sa2: per pair: w[q] -> softmax -> new_global -> l2norm -> sigmoid -> out
// ---------------------------------------------------------------------------
__global__ __launch_bounds__(256) void k_sa2(
    const float* __restrict__ wspart, const float* __restrict__ invn_ws,
    const u16* __restrict__ vbuf, const float* __restrict__ capw,
    const float* __restrict__ capb, float* __restrict__ out)
{
    const int pair = blockIdx.x;
    const u16* vb = vbuf + (size_t)pair * 65536;

    __shared__ float wiS[64];
    __shared__ float red[8];

    const int tid = threadIdx.x;

    if (tid < 64) {
        float x = 0.f;
        #pragma unroll
        for (int c = 0; c < 16; c++) x += wspart[(size_t)c * 65536 + pair * 64 + tid];
        float m = x;
        #pragma unroll
        for (int mk = 1; mk < 64; mk <<= 1) m = fmaxf(m, __shfl_xor(m, mk));
        float e = __expf(x - m);
        float Z = e;
        #pragma unroll
        for (int mk = 1; mk < 64; mk <<= 1) Z += __shfl_xor(Z, mk);
        wiS[tid] = (e / Z) * invn_ws[pair * 64 + tid];
    }
    __syncthreads();

    float s1 = 0.f, s2 = 0.f;
    int d0 = tid * 4;
    if (d0 < D_DIM) {
        float a0 = 0.f, a1 = 0.f, a2 = 0.f, a3 = 0.f;
        for (int q = 0; q < 64; q++) {
            float wq = wiS[q];
            ushort4 v = *(const ushort4*)(vb + q * 1024 + d0);
            a0 = fmaf(wq, b2f(v.x), a0); a1 = fmaf(wq, b2f(v.y), a1);
            a2 = fmaf(wq, b2f(v.z), a2); a3 = fmaf(wq, b2f(v.w), a3);
        }
        float4 cw4 = *(const float4*)(capw + d0);
        s1 = a0 * cw4.x + a1 * cw4.y + a2 * cw4.z + a3 * cw4.w;
        s2 = a0 * a0 + a1 * a1 + a2 * a2 + a3 * a3;
    }
    #pragma unroll
    for (int mk = 1; mk < 64; mk <<= 1) { s1 += __shfl_xor(s1, mk); s2 += __shfl_xor(s2, mk); }
    if ((tid & 63) == 0) { red[tid >> 6] = s1; red[4 + (tid >> 6)] = s2; }
    __syncthreads();
    if (tid == 0) {
        float S1 = red[0] + red[1] + red[2] + red[3];
        float S2 = red[4] + red[5] + red[6] + red[7];
        float val = S1 / (sqrtf(S2) + 1e-8f) + capb[0];
        out[pair] = 1.f / (1.f + __expf(-val));
    }
}

// ---------------------------------------------------------------------------
extern "C" void kernel_launch(void* const* d_in, const int* in_sizes, int n_in,
                              void* d_out, int out_size, void* d_ws, size_t ws_size,
                              hipStream_t stream)
{
    const float* feat_l = (const float*)d_in[0];
    const float* feat_f = (const float*)d_in[1];
    const float* words  = (const float*)d_in[2];
    const float* conv_w = (const float*)d_in[3];
    const float* conv_b = (const float*)d_in[4];
    const float* sa_wl  = (const float*)d_in[5];
    const float* sa_bl  = (const float*)d_in[6];
    const float* sa_wg  = (const float*)d_in[7];
    const float* sa_bg  = (const float*)d_in[8];
    const float* sa_wc  = (const float*)d_in[9];
    // d_in[10] = sa_bc: constant pre-softmax shift -> result-invariant
    const float* cap_w  = (const float*)d_in[11];
    const float* cap_b  = (const float*)d_in[12];
    float* out = (float*)d_out;

    char* ws = (char*)d_ws;
    // Overlay layout (bytes), peak 253,755,392 (<= 253,820,928 known-safe):
    //   [0,134.2M): featT_hi@0, featT_lo@33.5M (prepf->convG);
    //               imgT_hi@67.1M, imgT_lo@100.7M (trans->logits); vbuf@0 (wctx->sa2)
    //   [134.2M,167.8M): img_hi (convG->wctx); wgT@134.2M (prep-late->g2M)
    //   [167.8M,234.9M): img_lo (convG->trans); U (logits->wctx); wspart (saG->sa2)
    //   [234.9M,243.3M): wT_hi,wT_lo (prepw->wctx); simave_bf@234.9M (post->g2M)
    //   [243.3M,247.5M): cw_hi,cw_lo (prepcw->convG); then Zp, invZf, ssqp, invn
    //   [247.5M,249.6M): wlT ; [249.6M,253.76M): g2 fp32 [1024][1024]
    u16*   featT_hi  = (u16*)(ws);
    u16*   featT_lo  = (u16*)(ws + 33554432);
    u16*   imgT_hi   = (u16*)(ws + 67108864);
    u16*   imgT_lo   = (u16*)(ws + 100663296);
    u16*   vbuf      = (u16*)(ws);
    u16*   img_hi    = (u16*)(ws + 134217728);
    u16*   wgT       = (u16*)(ws + 134217728);
    u16*   img_lo    = (u16*)(ws + 167772160);
    u16*   U         = (u16*)(ws + 167772160);
    float* wspart    = (float*)(ws + 167772160);
    u16*   wT_hi     = (u16*)(ws + 234881024);
    u16*   simave_bf = (u16*)(ws + 234881024);
    u16*   wT_lo     = (u16*)(ws + 239075328);
    u16*   cw_hi     = (u16*)(ws + 243269632);
    float* Zp        = (float*)(ws + 243269632);
    u16*   cw_lo     = (u16*)(ws + 245366784);
    float* invZf     = (float*)(ws + 245366784);
    float* ssqp      = (float*)(ws + 245628928);
    float* invn      = (float*)(ws + 246677504);
    u16*   wlT       = (u16*)(ws + 247463936);
    float* g2        = (float*)(ws + 249561088);

    hipLaunchKernelGGL(k_prepf, dim3(4096), dim3(256), 0, stream,
                       feat_l, feat_f, featT_hi, featT_lo);
    hipLaunchKernelGGL(k_prepcw, dim3(1024), dim3(256), 0, stream,
                       conv_w, cw_hi, cw_lo);
    hipLaunchKernelGGL(k_prepw, dim3(512), dim3(256), 0, stream,
                       words, wT_hi, wT_lo);
    hipLaunchKernelGGL(k_prep, dim3(256), dim3(256), 0, stream, sa_wl, wlT);
    hipLaunchKernelGGL(k_convG, dim3(256), dim3(512), 0, stream,
                       featT_hi, featT_lo, cw_hi, cw_lo, conv_b, img_hi, img_lo);
    hipLaunchKernelGGL(k_trans, dim3(4096), dim3(256), 0, stream,
                       img_hi, img_lo, imgT_hi, imgT_lo);
    hipLaunchKernelGGL(k_logits, dim3(512), dim3(512), 0, stream,
                       wT_hi, wT_lo, imgT_hi, imgT_lo, U, Zp, out);
    hipLaunchKernelGGL(k_zred, dim3(256), dim3(256), 0, stream, Zp, invZf);
    hipLaunchKernelGGL(k_attmap2, dim3(32), dim3(256), 0, stream, out);
    hipLaunchKernelGGL(k_wctx, dim3(1024), dim3(512), 0, stream,
                       img_hi, U, invZf, wT_hi, wT_lo, vbuf, ssqp);
    hipLaunchKernelGGL(k_prep, dim3(256), dim3(256), 0, stream, sa_wg, wgT);
    hipLaunchKernelGGL(k_post, dim3(1024), dim3(256), 0, stream,
                       vbuf, ssqp, invn, simave_bf);
    hipLaunchKernelGGL(k_g2M, dim3(16), dim3(512), 0, stream,
                       simave_bf, wgT, sa_bg, sa_wc, g2);
    hipLaunchKernelGGL(k_saG, dim3(1024), dim3(512), 0, stream,
                       vbuf, wlT, invn, g2, sa_bl, wspart);
    hipLaunchKernelGGL(k_sa2, dim3(1024), dim3(256), 0, stream,
                       wspart, invn, vbuf, cap_w, cap_b, out);
}

// Round 7
// 737.581 us; speedup vs baseline: 8.9049x; 1.1330x over previous
//
#include <hip/hip_runtime.h>
#include <cstdint>

typedef unsigned short u16;
typedef unsigned int   u32;
typedef __attribute__((ext_vector_type(8))) short bf16x8;
typedef __attribute__((ext_vector_type(4))) float f32x4;

#define D_DIM 1000
#define C_IN  1024
#define HW    256
#define S_DIM 512
#define Q_DIM 64

__device__ __forceinline__ u16 f2b(float x) {
    u32 u = __builtin_bit_cast(u32, x);
    u32 r = (u + 0x7FFFu + ((u >> 16) & 1u)) >> 16;
    return (u16)r;
}
__device__ __forceinline__ float b2f(u16 h) {
    u32 u = ((u32)h) << 16;
    return __builtin_bit_cast(float, u);
}
__device__ __forceinline__ float ftanh(float x) {
    float e = __expf(2.f * x);
    return 1.f - 2.f / (e + 1.f);
}

#define GLOAD(ldsptr, gptr) \
    __builtin_amdgcn_global_load_lds( \
        (const __attribute__((address_space(1))) unsigned int*)(gptr), \
        (__attribute__((address_space(3))) unsigned int*)(ldsptr), 16, 0, 0)

// ---------------------------------------------------------------------------
// k_prepf: feat [b][1024 c][256 hw] fp32 -> featT_hi/lo bf16 [b][512 s][1024 c]
// ---------------------------------------------------------------------------
__global__ __launch_bounds__(256) void k_prepf(
    const float* __restrict__ feat_l, const float* __restrict__ feat_f,
    u16* __restrict__ fT_hi, u16* __restrict__ fT_lo)
{
    int bid = blockIdx.x;
    int ct = bid & 15, ht = (bid >> 4) & 3, half_ = (bid >> 6) & 1, b = bid >> 7;
    const float* src = (half_ ? feat_l : feat_f) + (size_t)b * C_IN * HW;
    __shared__ float T[64][65];
    int tid = threadIdx.x;
    {
        int cl = tid >> 2, h16 = (tid & 3) * 16;
        const float* p = src + (size_t)(ct * 64 + cl) * 256 + ht * 64 + h16;
        #pragma unroll
        for (int j = 0; j < 4; j++) {
            float4 v = *(const float4*)(p + j * 4);
            T[h16 + j * 4 + 0][cl] = v.x;
            T[h16 + j * 4 + 1][cl] = v.y;
            T[h16 + j * 4 + 2][cl] = v.z;
            T[h16 + j * 4 + 3][cl] = v.w;
        }
    }
    __syncthreads();
    {
        int hl = tid >> 2, c16 = (tid & 3) * 16;
        int srow = b * 512 + half_ * 256 + ht * 64 + hl;
        bf16x8 vh[2], vl[2];
        #pragma unroll
        for (int g = 0; g < 2; g++)
            #pragma unroll
            for (int j = 0; j < 8; j++) {
                float x = T[hl][c16 + g * 8 + j];
                u16 hh = f2b(x);
                vh[g][j] = (short)hh;
                vl[g][j] = (short)f2b(x - b2f(hh));
            }
        size_t o = (size_t)srow * 1024 + ct * 64 + c16;
        *(bf16x8*)(fT_hi + o) = vh[0];
        *(bf16x8*)(fT_hi + o + 8) = vh[1];
        *(bf16x8*)(fT_lo + o) = vl[0];
        *(bf16x8*)(fT_lo + o + 8) = vl[1];
    }
}

// ---------------------------------------------------------------------------
// k_prepcw: cw [1000][1024] fp32 -> cw_hi/lo [1024][1024] bf16
// ---------------------------------------------------------------------------
__global__ __launch_bounds__(256) void k_prepcw(
    const float* __restrict__ cw, u16* __restrict__ cwh, u16* __restrict__ cwl)
{
    int d = blockIdx.x;
    int c4 = threadIdx.x * 4;
    ushort4 h = make_ushort4(0, 0, 0, 0), lo = make_ushort4(0, 0, 0, 0);
    if (d < D_DIM) {
        float4 v = *(const float4*)(cw + (size_t)d * 1024 + c4);
        float a[4] = {v.x, v.y, v.z, v.w};
        u16* ph = (u16*)&h; u16* pl = (u16*)&lo;
        #pragma unroll
        for (int j = 0; j < 4; j++) {
            ph[j] = f2b(a[j]);
            pl[j] = f2b(a[j] - b2f(ph[j]));
        }
    }
    *(ushort4*)(cwh + (size_t)d * 1024 + c4) = h;
    *(ushort4*)(cwl + (size_t)d * 1024 + c4) = lo;
}

// ---------------------------------------------------------------------------
// k_prepw: words [i][1000 d][64 q] fp32 -> wT_hi/lo bf16 [i][64 q][1024 d]
// ---------------------------------------------------------------------------
__global__ __launch_bounds__(256) void k_prepw(
    const float* __restrict__ words, u16* __restrict__ wth, u16* __restrict__ wtl)
{
    int i = blockIdx.x >> 4, dt = blockIdx.x & 15;
    const float* src = words + (size_t)i * D_DIM * Q_DIM;
    __shared__ u16 Th[64][72], Tl[64][72];
    int tid = threadIdx.x;
    #pragma unroll
    for (int rep = 0; rep < 4; rep++) {
        int idx = tid + rep * 256;
        int dl = idx >> 4, q4 = (idx & 15) * 4;
        int d = dt * 64 + dl;
        float4 v = make_float4(0.f, 0.f, 0.f, 0.f);
        if (d < D_DIM) v = *(const float4*)(src + (size_t)d * Q_DIM + q4);
        float a[4] = {v.x, v.y, v.z, v.w};
        #pragma unroll
        for (int jj = 0; jj < 4; jj++) {
            u16 hh = f2b(a[jj]);
            Th[dl][q4 + jj] = hh;
            Tl[dl][q4 + jj] = f2b(a[jj] - b2f(hh));
        }
    }
    __syncthreads();
    #pragma unroll
    for (int rep = 0; rep < 2; rep++) {
        int idx = tid + rep * 256;
        int q = idx >> 3, c8 = idx & 7;
        bf16x8 vh, vl;
        #pragma unroll
        for (int jj = 0; jj < 8; jj++) { vh[jj] = (short)Th[c8 * 8 + jj][q]; vl[jj] = (short)Tl[c8 * 8 + jj][q]; }
        size_t doff = (size_t)i * 65536 + (size_t)q * 1024 + dt * 64 + c8 * 8;
        *(bf16x8*)(wth + doff) = vh;
        *(bf16x8*)(wtl + doff) = vl;
    }
}

// ---------------------------------------------------------------------------
// k_prep: T[e][d] = bf16(W[d][e]); [1024][1024], zero-padded. (for wl AND wg)
// ---------------------------------------------------------------------------
__global__ __launch_bounds__(256) void k_prep(const float* __restrict__ wl, u16* __restrict__ wlT)
{
    __shared__ float t[64][65];
    int bd = blockIdx.x & 15, be = blockIdx.x >> 4;
    int tx = threadIdx.x & 15, ty = threadIdx.x >> 4;
    #pragma unroll
    for (int rr = 0; rr < 4; rr++) {
        int r = ty * 4 + rr;
        int d = bd * 64 + r;
        int e4 = be * 64 + tx * 4;
        float v0 = 0.f, v1 = 0.f, v2 = 0.f, v3 = 0.f;
        if (d < D_DIM) {
            if (e4 + 3 < D_DIM) {
                float4 v = *reinterpret_cast<const float4*>(wl + (size_t)d * D_DIM + e4);
                v0 = v.x; v1 = v.y; v2 = v.z; v3 = v.w;
            } else {
                if (e4 + 0 < D_DIM) v0 = wl[(size_t)d * D_DIM + e4 + 0];
                if (e4 + 1 < D_DIM) v1 = wl[(size_t)d * D_DIM + e4 + 1];
                if (e4 + 2 < D_DIM) v2 = wl[(size_t)d * D_DIM + e4 + 2];
                if (e4 + 3 < D_DIM) v3 = wl[(size_t)d * D_DIM + e4 + 3];
            }
        }
        t[r][tx * 4 + 0] = v0; t[r][tx * 4 + 1] = v1;
        t[r][tx * 4 + 2] = v2; t[r][tx * 4 + 3] = v3;
    }
    __syncthreads();
    #pragma unroll
    for (int rr = 0; rr < 4; rr++) {
        int r2 = ty * 4 + rr;
        int e = be * 64 + r2;
        int d0 = bd * 64 + tx * 4;
        ushort4 h;
        h.x = f2b(t[tx * 4 + 0][r2]); h.y = f2b(t[tx * 4 + 1][r2]);
        h.z = f2b(t[tx * 4 + 2][r2]); h.w = f2b(t[tx * 4 + 3][r2]);
        *reinterpret_cast<ushort4*>(wlT + (size_t)e * 1024 + d0) = h;
    }
}

// ---------------------------------------------------------------------------
// k_convG: img = featT . cw^T (split-bf16 3-pass) + cb.  BK=32, swizzled,
// double-buffered prefetch (stage t+1 issued before compute t).
// ---------------------------------------------------------------------------
__global__ __launch_bounds__(512) void k_convG(
    const u16* __restrict__ fT_hi, const u16* __restrict__ fT_lo,
    const u16* __restrict__ cwh, const u16* __restrict__ cwl,
    const float* __restrict__ cb,
    u16* __restrict__ img_hi, u16* __restrict__ img_lo)
{
    const int bid = blockIdx.x;
    const int mblk = bid >> 2, nt = bid & 3;
    const int m0 = mblk * 256, n0 = nt * 256;

    __shared__ char LDS[131072] __attribute__((aligned(16)));  // 2 x {Ah,Alo,Bh,Blo} 16KB each
    __shared__ float cbS[256];

    const int tid = threadIdx.x;
    const int wid = tid >> 6, lane = tid & 63;
    const int wr = wid >> 2, wc = wid & 3;
    const int l15 = lane & 15, l4 = lane >> 4;
    const int sw = (l15 >> 1) & 3;

    if (tid < 256) {
        int d = n0 + tid;
        cbS[tid] = (d < D_DIM) ? cb[d] : 0.f;
    }

    auto stage = [&](int buf, int k0) {
        char* base = LDS + buf * 65536;
        #pragma unroll
        for (int rep = 0; rep < 2; rep++) {
            int idx = tid + rep * 512;
            int row = idx >> 2, slot = idx & 3;
            int kb = (slot ^ ((row >> 1) & 3)) * 16;
            size_t ao = (size_t)(m0 + row) * 2048 + (size_t)k0 * 2 + kb;
            size_t bo = (size_t)(n0 + row) * 2048 + (size_t)k0 * 2 + kb;
            GLOAD(base + idx * 16, (const char*)fT_hi + ao);
            GLOAD(base + 16384 + idx * 16, (const char*)fT_lo + ao);
            GLOAD(base + 32768 + idx * 16, (const char*)cwh + bo);
            GLOAD(base + 49152 + idx * 16, (const char*)cwl + bo);
        }
    };

    f32x4 acc[8][4] = {};

    stage(0, 0);
    __syncthreads();
    int cur = 0;
    for (int k0 = 0; k0 < 1024; k0 += 32) {
        if (k0 + 32 < 1024) stage(cur ^ 1, k0 + 32);
        const char* Ah = LDS + cur * 65536;
        const char* Alo = Ah + 16384;
        const char* Bh = Ah + 32768;
        const char* Blo = Ah + 49152;
        bf16x8 ah[8], bh[4];
        #pragma unroll
        for (int mf = 0; mf < 8; mf++)
            ah[mf] = *(const bf16x8*)(Ah + (wr * 128 + mf * 16 + l15) * 64 + ((l4 ^ sw) * 16));
        #pragma unroll
        for (int nf = 0; nf < 4; nf++)
            bh[nf] = *(const bf16x8*)(Bh + (wc * 64 + nf * 16 + l15) * 64 + ((l4 ^ sw) * 16));
        #pragma unroll
        for (int mf = 0; mf < 8; mf++)
            #pragma unroll
            for (int nf = 0; nf < 4; nf++)
                acc[mf][nf] = __builtin_amdgcn_mfma_f32_16x16x32_bf16(ah[mf], bh[nf], acc[mf][nf], 0, 0, 0);
        #pragma unroll
        for (int mf = 0; mf < 8; mf++) {
            bf16x8 al = *(const bf16x8*)(Alo + (wr * 128 + mf * 16 + l15) * 64 + ((l4 ^ sw) * 16));
            #pragma unroll
            for (int nf = 0; nf < 4; nf++)
                acc[mf][nf] = __builtin_amdgcn_mfma_f32_16x16x32_bf16(al, bh[nf], acc[mf][nf], 0, 0, 0);
        }
        #pragma unroll
        for (int nf = 0; nf < 4; nf++) {
            bf16x8 bl = *(const bf16x8*)(Blo + (wc * 64 + nf * 16 + l15) * 64 + ((l4 ^ sw) * 16));
            #pragma unroll
            for (int mf = 0; mf < 8; mf++)
                acc[mf][nf] = __builtin_amdgcn_mfma_f32_16x16x32_bf16(ah[mf], bl, acc[mf][nf], 0, 0, 0);
        }
        __syncthreads();   // drains prefetch (compiler emits vmcnt(0) lgkmcnt(0))
        cur ^= 1;
    }
    const int b = m0 >> 9;
    const int sbase = m0 & 511;
    #pragma unroll
    for (int mf = 0; mf < 8; mf++) {
        int srow = sbase + wr * 128 + mf * 16 + l4 * 4;
        #pragma unroll
        for (int nf = 0; nf < 4; nf++) {
            int dcol = n0 + wc * 64 + nf * 16 + l15;
            float bias = cbS[wc * 64 + nf * 16 + l15];
            ushort4 h4, lo4;
            u16* ph = (u16*)&h4; u16* pl = (u16*)&lo4;
            #pragma unroll
            for (int r = 0; r < 4; r++) {
                float v = acc[mf][nf][r] + bias;
                u16 hh = f2b(v);
                ph[r] = hh;
                pl[r] = f2b(v - b2f(hh));
            }
            size_t off = ((size_t)b * 1024 + dcol) * 512 + srow;
            *(ushort4*)(img_hi + off) = h4;
            *(ushort4*)(img_lo + off) = lo4;
        }
    }
}

// ---------------------------------------------------------------------------
// k_trans: img_hi/lo [b][1024 d][512 s] -> imgT_hi/lo [b][512 s][1024 d]
// ---------------------------------------------------------------------------
__global__ __launch_bounds__(256) void k_trans(
    const u16* __restrict__ ih, const u16* __restrict__ il,
    u16* __restrict__ oth, u16* __restrict__ otl)
{
    int bid = blockIdx.x;
    int st = bid & 7, dt = (bid >> 3) & 15, b = bid >> 7;
    const u16* srcH = ih + (size_t)b * 1024 * 512;
    const u16* srcL = il + (size_t)b * 1024 * 512;
    u16* dstH = oth + (size_t)b * 512 * 1024;
    u16* dstL = otl + (size_t)b * 512 * 1024;
    __shared__ u16 Th[64][72], Tl[64][72];
    int tid = threadIdx.x;
    #pragma unroll
    for (int rep = 0; rep < 2; rep++) {
        int idx = tid + rep * 256;
        int dl = idx >> 3, c8 = idx & 7;
        size_t so = (size_t)(dt * 64 + dl) * 512 + st * 64 + c8 * 8;
        bf16x8 vh = *(const bf16x8*)(srcH + so);
        bf16x8 vl = *(const bf16x8*)(srcL + so);
        #pragma unroll
        for (int jj = 0; jj < 8; jj++) { Th[c8 * 8 + jj][dl] = (u16)vh[jj]; Tl[c8 * 8 + jj][dl] = (u16)vl[jj]; }
    }
    __syncthreads();
    #pragma unroll
    for (int rep = 0; rep < 2; rep++) {
        int idx = tid + rep * 256;
        int sl = idx >> 3, c8 = idx & 7;
        bf16x8 vh = *(const bf16x8*)(&Th[sl][c8 * 8]);
        bf16x8 vl = *(const bf16x8*)(&Tl[sl][c8 * 8]);
        size_t doff = (size_t)(st * 64 + sl) * 1024 + dt * 64 + c8 * 8;
        *(bf16x8*)(dstH + doff) = vh;
        *(bf16x8*)(dstL + doff) = vl;
    }
}

// ---------------------------------------------------------------------------
// k_logits: per b: C[iq][s] = wT . imgT^T (3-pass split), softmax over q,
// U -> global, Zp partials, diag u -> out.  BK=32, swizzled, dbuf prefetch.
// ---------------------------------------------------------------------------
__global__ __launch_bounds__(512) void k_logits(
    const u16* __restrict__ wTh, const u16* __restrict__ wTl,
    const u16* __restrict__ iTh, const u16* __restrict__ iTl,
    u16* __restrict__ U, float* __restrict__ Zp, float* __restrict__ out)
{
    const int bid = blockIdx.x;
    const int b = bid >> 4, mt = (bid >> 1) & 7, nt = bid & 1;
    const int m0 = mt * 256, n0 = nt * 256;

    __shared__ char LDS[131072] __attribute__((aligned(16)));

    const int tid = threadIdx.x;
    const int wid = tid >> 6, lane = tid & 63;
    const int wr = wid >> 2, wc = wid & 3;
    const int l15 = lane & 15, l4 = lane >> 4;
    const int sw = (l15 >> 1) & 3;

    auto stage = [&](int buf, int k0) {
        char* base = LDS + buf * 65536;
        #pragma unroll
        for (int rep = 0; rep < 2; rep++) {
            int idx = tid + rep * 512;
            int row = idx >> 2, slot = idx & 3;
            int kb = (slot ^ ((row >> 1) & 3)) * 16;
            size_t ao = (size_t)(m0 + row) * 2048 + (size_t)k0 * 2 + kb;
            size_t bo = ((size_t)b * 512 + n0 + row) * 2048 + (size_t)k0 * 2 + kb;
            GLOAD(base + idx * 16, (const char*)wTh + ao);
            GLOAD(base + 16384 + idx * 16, (const char*)wTl + ao);
            GLOAD(base + 32768 + idx * 16, (const char*)iTh + bo);
            GLOAD(base + 49152 + idx * 16, (const char*)iTl + bo);
        }
    };

    f32x4 acc[8][4] = {};

    stage(0, 0);
    __syncthreads();
    int cur = 0;
    for (int k0 = 0; k0 < 1024; k0 += 32) {
        if (k0 + 32 < 1024) stage(cur ^ 1, k0 + 32);
        const char* Ah = LDS + cur * 65536;
        const char* Alo = Ah + 16384;
        const char* Bh = Ah + 32768;
        const char* Blo = Ah + 49152;
        bf16x8 ah[8], bh[4];
        #pragma unroll
        for (int mf = 0; mf < 8; mf++)
            ah[mf] = *(const bf16x8*)(Ah + (wr * 128 + mf * 16 + l15) * 64 + ((l4 ^ sw) * 16));
        #pragma unroll
        for (int nf = 0; nf < 4; nf++)
            bh[nf] = *(const bf16x8*)(Bh + (wc * 64 + nf * 16 + l15) * 64 + ((l4 ^ sw) * 16));
        #pragma unroll
        for (int mf = 0; mf < 8; mf++)
            #pragma unroll
            for (int nf = 0; nf < 4; nf++)
                acc[mf][nf] = __builtin_amdgcn_mfma_f32_16x16x32_bf16(ah[mf], bh[nf], acc[mf][nf], 0, 0, 0);
        #pragma unroll
        for (int mf = 0; mf < 8; mf++) {
            bf16x8 al = *(const bf16x8*)(Alo + (wr * 128 + mf * 16 + l15) * 64 + ((l4 ^ sw) * 16));
            #pragma unroll
            for (int nf = 0; nf < 4; nf++)
                acc[mf][nf] = __builtin_amdgcn_mfma_f32_16x16x32_bf16(al, bh[nf], acc[mf][nf], 0, 0, 0);
        }
        #pragma unroll
        for (int nf = 0; nf < 4; nf++) {
            bf16x8 bl = *(const bf16x8*)(Blo + (wc * 64 + nf * 16 + l15) * 64 + ((l4 ^ sw) * 16));
            #pragma unroll
            for (int mf = 0; mf < 8; mf++)
                acc[mf][nf] = __builtin_amdgcn_mfma_f32_16x16x32_bf16(ah[mf], bl, acc[mf][nf], 0, 0, 0);
        }
        __syncthreads();
        cur ^= 1;
    }

    float zacc[8][4] = {};
    #pragma unroll
    for (int il = 0; il < 2; il++) {
        int i_glob = mt * 4 + wr * 2 + il;
        bool diag = (i_glob == b);
        #pragma unroll
        for (int nf = 0; nf < 4; nf++) {
            int scol = n0 + wc * 64 + nf * 16 + l15;
            float m = -3.4e38f;
            #pragma unroll
            for (int mm = 0; mm < 4; mm++)
                #pragma unroll
                for (int r = 0; r < 4; r++)
                    m = fmaxf(m, acc[il * 4 + mm][nf][r]);
            m = fmaxf(m, __shfl_xor(m, 16));
            m = fmaxf(m, __shfl_xor(m, 32));
            float e[16], sum = 0.f;
            #pragma unroll
            for (int mm = 0; mm < 4; mm++)
                #pragma unroll
                for (int r = 0; r < 4; r++) {
                    float ev = __expf(acc[il * 4 + mm][nf][r] - m);
                    e[mm * 4 + r] = ev; sum += ev;
                }
            sum += __shfl_xor(sum, 16);
            sum += __shfl_xor(sum, 32);
            float inv = 1.f / sum;
            #pragma unroll
            for (int mm = 0; mm < 4; mm++)
                #pragma unroll
                for (int r = 0; r < 4; r++) {
                    float u = __expf(4.f * e[mm * 4 + r] * inv);   // in [1, e^4]
                    u16 ub = f2b(u);
                    zacc[il * 4 + mm][r] += b2f(ub);
                    int iqrow = m0 + wr * 128 + (il * 4 + mm) * 16 + l4 * 4 + r;
                    U[((size_t)b * 2048 + iqrow) * 512 + scol] = ub;
                    if (diag) {
                        int q = iqrow & 63;
                        out[1024 + ((size_t)i_glob * 64 + q) * 512 + scol] = u;
                    }
                }
        }
    }
    #pragma unroll
    for (int mf = 0; mf < 8; mf++)
        #pragma unroll
        for (int r = 0; r < 4; r++) {
            float z = zacc[mf][r];
            z += __shfl_xor(z, 1); z += __shfl_xor(z, 2);
            z += __shfl_xor(z, 4); z += __shfl_xor(z, 8);
            if (l15 == 0) {
                int iqrow = m0 + wr * 128 + mf * 16 + l4 * 4 + r;
                Zp[((size_t)b * 2048 + iqrow) * 8 + nt * 4 + wc] = z;
            }
        }
}

// k_zred: invZf[gi] = 1 / sum of 8 Zp partials
__global__ __launch_bounds__(256) void k_zred(const float* __restrict__ Zp, float* __restrict__ invZf)
{
    int gi = blockIdx.x * 256 + threadIdx.x;
    float4 z0 = *(const float4*)(Zp + (size_t)gi * 8);
    float4 z1 = *(const float4*)(Zp + (size_t)gi * 8 + 4);
    invZf[gi] = 1.f / (z0.x + z0.y + z0.z + z0.w + z1.x + z1.y + z1.z + z1.w);
}

// normalize att_maps rows in place. 32 blocks.
__global__ __launch_bounds__(256) void k_attmap2(float* __restrict__ out)
{
    const int i = blockIdx.x;
    float* am = out + 1024 + (size_t)i * Q_DIM * S_DIM;
    int q = threadIdx.x >> 2, ch = threadIdx.x & 3;
    float s = 0.f;
    for (int ss = ch * 128; ss < ch * 128 + 128; ss++) s += am[(size_t)q * S_DIM + ss];
    s += __shfl_xor(s, 1);
    s += __shfl_xor(s, 2);
    float iz = 1.f / s;
    for (int ss = ch * 128; ss < ch * 128 + 128; ss++) am[(size_t)q * S_DIM + ss] *= iz;
}

// ---------------------------------------------------------------------------
// k_wctx: per b: C[d][iq] = img_hi . U^T, K=512, BK=64, swizzled, dbuf prefetch.
// Epilogue: v = acc*invZ*(wThi+wTlo) -> vbuf bf16; ssq partials.
// ---------------------------------------------------------------------------
__global__ __launch_bounds__(512) void k_wctx(
    const u16* __restrict__ img_hi, const u16* __restrict__ U,
    const float* __restrict__ invZf,
    const u16* __restrict__ wTh, const u16* __restrict__ wTl,
    u16* __restrict__ vbuf, float* __restrict__ ssqp)
{
    const int bid = blockIdx.x;
    const int b = bid >> 5, mt = (bid >> 3) & 3, nt = bid & 7;
    const int m0 = mt * 256, n0 = nt * 256;

    __shared__ char LDS[131072] __attribute__((aligned(16)));  // 2 x {At 32K, Bt 32K}
    __shared__ float izS[256];

    const int tid = threadIdx.x;
    const int wid = tid >> 6, lane = tid & 63;
    const int wr = wid >> 2, wc = wid & 3;
    const int l15 = lane & 15, l4 = lane >> 4;
    const int sw = l15 & 7;

    if (tid < 256) izS[tid] = invZf[b * 2048 + n0 + tid];

    auto stage = [&](int buf, int k0) {
        char* base = LDS + buf * 65536;
        #pragma unroll
        for (int rep = 0; rep < 4; rep++) {
            int idx = tid + rep * 512;
            int row = idx >> 3, slot = idx & 7;
            int kb = (slot ^ (row & 7)) * 16;
            GLOAD(base + idx * 16, (const char*)img_hi + ((size_t)b * 1024 + m0 + row) * 1024 + (size_t)k0 * 2 + kb);
            GLOAD(base + 32768 + idx * 16, (const char*)U + ((size_t)b * 2048 + n0 + row) * 1024 + (size_t)k0 * 2 + kb);
        }
    };

    f32x4 acc[8][4] = {};

    stage(0, 0);
    __syncthreads();
    int cur = 0;
    for (int k0 = 0; k0 < 512; k0 += 64) {
        if (k0 + 64 < 512) stage(cur ^ 1, k0 + 64);
        const char* At = LDS + cur * 65536;
        const char* Bt = At + 32768;
        #pragma unroll
        for (int kf = 0; kf < 2; kf++) {
            bf16x8 a[8], bb[4];
            #pragma unroll
            for (int mf = 0; mf < 8; mf++)
                a[mf] = *(const bf16x8*)(At + (wr * 128 + mf * 16 + l15) * 128 + (((kf * 4 + l4) ^ sw) * 16));
            #pragma unroll
            for (int nf = 0; nf < 4; nf++)
                bb[nf] = *(const bf16x8*)(Bt + (wc * 64 + nf * 16 + l15) * 128 + (((kf * 4 + l4) ^ sw) * 16));
            #pragma unroll
            for (int mf = 0; mf < 8; mf++)
                #pragma unroll
                for (int nf = 0; nf < 4; nf++)
                    acc[mf][nf] = __builtin_amdgcn_mfma_f32_16x16x32_bf16(a[mf], bb[nf], acc[mf][nf], 0, 0, 0);
        }
        __syncthreads();
        cur ^= 1;
    }

    #pragma unroll
    for (int nf = 0; nf < 4; nf++) {
        int col = wc * 64 + nf * 16 + l15;
        int iq = n0 + col;
        float iz = izS[col];
        size_t wtoff = (size_t)iq * 1024;
        float s_nf = 0.f;
        #pragma unroll
        for (int mf = 0; mf < 8; mf++) {
            int d0 = m0 + wr * 128 + mf * 16 + l4 * 4;
            ushort4 wh = *(const ushort4*)(wTh + wtoff + d0);
            ushort4 wl = *(const ushort4*)(wTl + wtoff + d0);
            const u16* pwh = (const u16*)&wh;
            const u16* pwl = (const u16*)&wl;
            ushort4 vo;
            u16* pv = (u16*)&vo;
            #pragma unroll
            for (int r = 0; r < 4; r++) {
                float wv = b2f(pwh[r]) + b2f(pwl[r]);
                float v = acc[mf][nf][r] * iz * wv;
                s_nf = fmaf(v, v, s_nf);
                pv[r] = f2b(v);
            }
            *(ushort4*)(vbuf + ((size_t)b * 2048 + iq) * 1024 + d0) = vo;
        }
        s_nf += __shfl_xor(s_nf, 16);
        s_nf += __shfl_xor(s_nf, 32);
        if (l4 == 0) ssqp[((size_t)b * 2048 + iq) * 4 + mt] = s_nf;
    }
}

// ---------------------------------------------------------------------------
// k_post: per pair: invn from ssqp; simave_bf16[pair][1024] = mean_q v*invn
// ---------------------------------------------------------------------------
__global__ __launch_bounds__(256) void k_post(
    const u16* __restrict__ vbuf, const float* __restrict__ ssqp,
    float* __restrict__ invn_ws, u16* __restrict__ simave_bf)
{
    const int pair = blockIdx.x;
    __shared__ float invnS[64];
    const int tid = threadIdx.x;
    if (tid < 64) {
        size_t o = ((size_t)pair * 64 + tid) * 4;
        float s = ssqp[o] + ssqp[o + 1] + ssqp[o + 2] + ssqp[o + 3];
        float n = 1.f / (sqrtf(s) + 1e-8f);
        invnS[tid] = n;
        invn_ws[pair * 64 + tid] = n;
    }
    __syncthreads();
    int d0 = tid * 4;
    ushort4 o4 = make_ushort4(0, 0, 0, 0);
    if (d0 < D_DIM) {
        float a0 = 0.f, a1 = 0.f, a2 = 0.f, a3 = 0.f;
        const u16* vb = vbuf + (size_t)pair * 65536;
        for (int q = 0; q < 64; q++) {
            float n = invnS[q];
            ushort4 v = *(const ushort4*)(vb + q * 1024 + d0);
            a0 = fmaf(b2f(v.x), n, a0); a1 = fmaf(b2f(v.y), n, a1);
            a2 = fmaf(b2f(v.z), n, a2); a3 = fmaf(b2f(v.w), n, a3);
        }
        o4.x = f2b(a0 * (1.f / 64.f)); o4.y = f2b(a1 * (1.f / 64.f));
        o4.z = f2b(a2 * (1.f / 64.f)); o4.w = f2b(a3 * (1.f / 64.f));
    }
    *(ushort4*)(simave_bf + (size_t)pair * 1024 + d0) = o4;
}

// ---------------------------------------------------------------------------
// k_g2M: g2[p][e] = tanh(simave . wg + bg) * wc  via bf16 MFMA, dbuf prefetch.
// ---------------------------------------------------------------------------
__global__ __launch_bounds__(512) void k_g2M(
    const u16* __restrict__ simave_bf, const u16* __restrict__ wgT,
    const float* __restrict__ bg, const float* __restrict__ wc,
    float* __restrict__ g2)
{
    const int mt = blockIdx.x >> 2, nt = blockIdx.x & 3;
    const int m0 = mt * 256, n0 = nt * 256;

    __shared__ char LDS[131072] __attribute__((aligned(16)));
    __shared__ float bgS[256], wcS[256];

    const int tid = threadIdx.x;
    const int wid = tid >> 6, lane = tid & 63;
    const int wr = wid >> 2, wc_ = wid & 3;
    const int l15 = lane & 15, l4 = lane >> 4;
    const int sw = l15 & 7;

    if (tid < 256) {
        int e = n0 + tid;
        bgS[tid] = (e < D_DIM) ? bg[e] : 0.f;
        wcS[tid] = (e < D_DIM) ? wc[e] : 0.f;
    }

    auto stage = [&](int buf, int k0) {
        char* base = LDS + buf * 65536;
        #pragma unroll
        for (int rep = 0; rep < 4; rep++) {
            int idx = tid + rep * 512;
            int row = idx >> 3, slot = idx & 7;
            int kb = (slot ^ (row & 7)) * 16;
            GLOAD(base + idx * 16, (const char*)simave_bf + (size_t)(m0 + row) * 2048 + (size_t)k0 * 2 + kb);
            GLOAD(base + 32768 + idx * 16, (const char*)wgT + (size_t)(n0 + row) * 2048 + (size_t)k0 * 2 + kb);
        }
    };

    f32x4 acc[8][4] = {};

    stage(0, 0);
    __syncthreads();
    int cur = 0;
    for (int k0 = 0; k0 < 1024; k0 += 64) {
        if (k0 + 64 < 1024) stage(cur ^ 1, k0 + 64);
        const char* Al = LDS + cur * 65536;
        const char* Bl = Al + 32768;
        #pragma unroll
        for (int kf = 0; kf < 2; kf++) {
            bf16x8 a[8], bb[4];
            #pragma unroll
            for (int mf = 0; mf < 8; mf++)
                a[mf] = *(const bf16x8*)(Al + (wr * 128 + mf * 16 + l15) * 128 + (((kf * 4 + l4) ^ sw) * 16));
            #pragma unroll
            for (int nf = 0; nf < 4; nf++)
                bb[nf] = *(const bf16x8*)(Bl + (wc_ * 64 + nf * 16 + l15) * 128 + (((kf * 4 + l4) ^ sw) * 16));
            #pragma unroll
            for (int mf = 0; mf < 8; mf++)
                #pragma unroll
                for (int nf = 0; nf < 4; nf++)
                    acc[mf][nf] = __builtin_amdgcn_mfma_f32_16x16x32_bf16(a[mf], bb[nf], acc[mf][nf], 0, 0, 0);
        }
        __syncthreads();
        cur ^= 1;
    }

    #pragma unroll
    for (int mf = 0; mf < 8; mf++) {
        int p = m0 + wr * 128 + mf * 16 + l4 * 4;
        #pragma unroll
        for (int nf = 0; nf < 4; nf++) {
            int cl = wc_ * 64 + nf * 16 + l15;
            float bgv = bgS[cl], wcv = wcS[cl];
            #pragma unroll
            for (int r = 0; r < 4; r++)
                g2[(size_t)(p + r) * 1024 + n0 + cl] = ftanh(acc[mf][nf][r] + bgv) * wcv;
        }
    }
}

// ---------------------------------------------------------------------------
// k_saG: flat GEMM M=65536, N=1024, K=1024. BK=64 swizzled, dbuf prefetch,
// nt-fast + XCD block swizzle.
// ---------------------------------------------------------------------------
__global__ __launch_bounds__(512) void k_saG(
    const u16* __restrict__ vbuf, const u16* __restrict__ wlT,
    const float* __restrict__ invn_ws, const float* __restrict__ g2_ws,
    const float* __restrict__ bl, float* __restrict__ wspart)
{
    const int bid = blockIdx.x;
    const int wg = (bid & 7) * 128 + (bid >> 3);
    const int mt = wg >> 2, nt = wg & 3;
    const int m0 = mt * 256, n0 = nt * 256;

    __shared__ char LDS[131072] __attribute__((aligned(16)));
    __shared__ float invnS[256];
    __shared__ float blS[256];
    __shared__ float g2S[4 * 256];

    const int tid = threadIdx.x;
    const int wid = tid >> 6, lane = tid & 63;
    const int wr = wid >> 2, wc = wid & 3;
    const int l15 = lane & 15, l4 = lane >> 4;
    const int sw = l15 & 7;

    if (tid < 256) {
        invnS[tid] = invn_ws[m0 + tid];
        int e = n0 + tid;
        blS[tid] = (e < D_DIM) ? bl[e] : 0.f;
    }
    #pragma unroll
    for (int rep = 0; rep < 2; rep++) {
        int idx = tid + rep * 512;
        int p = idx >> 8, el = idx & 255;
        g2S[idx] = g2_ws[(size_t)((m0 >> 6) + p) * 1024 + n0 + el];
    }

    auto stage = [&](int buf, int k0) {
        char* base = LDS + buf * 65536;
        #pragma unroll
        for (int rep = 0; rep < 4; rep++) {
            int idx = tid + rep * 512;
            int row = idx >> 3, slot = idx & 7;
            int kb = (slot ^ (row & 7)) * 16;
            GLOAD(base + idx * 16, (const char*)vbuf + (size_t)(m0 + row) * 2048 + (size_t)k0 * 2 + kb);
            GLOAD(base + 32768 + idx * 16, (const char*)wlT + (size_t)(n0 + row) * 2048 + (size_t)k0 * 2 + kb);
        }
    };

    f32x4 acc[8][4] = {};

    stage(0, 0);
    __syncthreads();
    int cur = 0;
    for (int k0 = 0; k0 < 1024; k0 += 64) {
        if (k0 + 64 < 1024) stage(cur ^ 1, k0 + 64);
        const char* Al = LDS + cur * 65536;
        const char* Bl = Al + 32768;
        #pragma unroll
        for (int kf = 0; kf < 2; kf++) {
            bf16x8 a[8], bb[4];
            #pragma unroll
            for (int mf = 0; mf < 8; mf++)
                a[mf] = *(const bf16x8*)(Al + (wr * 128 + mf * 16 + l15) * 128 + (((kf * 4 + l4) ^ sw) * 16));
            #pragma unroll
            for (int nf = 0; nf < 4; nf++)
                bb[nf] = *(const bf16x8*)(Bl + (wc * 64 + nf * 16 + l15) * 128 + (((kf * 4 + l4) ^ sw) * 16));
            #pragma unroll
            for (int mf = 0; mf < 8; mf++)
                #pragma unroll
                for (int nf = 0; nf < 4; nf++)
                    acc[mf][nf] = __builtin_amdgcn_mfma_f32_16x16x32_bf16(a[mf], bb[nf], acc[mf][nf], 0, 0, 0);
        }
        __syncthreads();
        cur ^= 1;
    }

    #pragma unroll
    for (int mf = 0; mf < 8; mf++) {
        int mrow = wr * 128 + mf * 16 + l4 * 4;
        #pragma unroll
        for (int r = 0; r < 4; r++) {
            float inv = invnS[mrow + r];
            int p = (mrow + r) >> 6;
            float s = 0.f;
            #pragma unroll
            for (int nf = 0; nf < 4; nf++) {
                int el = wc * 64 + nf * 16 + l15;
                float x = acc[mf][nf][r] * inv + blS[el];
                s += ftanh(x) * g2S[p * 256 + el];
            }
            s += __shfl_xor(s, 1);
            s += __shfl_xor(s, 2);
            s += __shfl_xor(s, 4);
            s += __shfl_xor(s, 8);
            if (l15 == 0)
                wspart[(size_t)(nt * 4 + wc) * 65536 + m0 + mrow + r] = s;
        }
    }
}

// ---------------------------------------------------------------------------
// k_sa2: per pair: w[q] -> softmax -> new_global -> l2norm -> sigmoid -> out
// ---------------------------------------------------------------------------
__global__ __launch_bounds__(256) void k_sa2(
    const float* __restrict__ wspart, const float* __restrict__ invn_ws,
    const u16* __restrict__ vbuf, const float* __restrict__ capw,
    const float* __restrict__ capb, float* __restrict__ out)
{
    const int pair = blockIdx.x;
    const u16* vb = vbuf + (size_t)pair * 65536;

    __shared__ float wiS[64];
    __shared__ float red[8];

    const int tid = threadIdx.x;

    if (tid < 64) {
        float x = 0.f;
        #pragma unroll
        for (int c = 0; c < 16; c++) x += wspart[(size_t)c * 65536 + pair * 64 + tid];
        float m = x;
        #pragma unroll
        for (int mk = 1; mk < 64; mk <<= 1) m = fmaxf(m, __shfl_xor(m, mk));
        float e = __expf(x - m);
        float Z = e;
        #pragma unroll
        for (int mk = 1; mk < 64; mk <<= 1) Z += __shfl_xor(Z, mk);
        wiS[tid] = (e / Z) * invn_ws[pair * 64 + tid];
    }
    __syncthreads();

    float s1 = 0.f, s2 = 0.f;
    int d0 = tid * 4;
    if (d0 < D_DIM) {
        float a0 = 0.f, a1 = 0.f, a2 = 0.f, a3 = 0.f;
        for (int q = 0; q < 64; q++) {
            float wq = wiS[q];
            ushort4 v = *(const ushort4*)(vb + q * 1024 + d0);
            a0 = fmaf(wq, b2f(v.x), a0); a1 = fmaf(wq, b2f(v.y), a1);
            a2 = fmaf(wq, b2f(v.z), a2); a3 = fmaf(wq, b2f(v.w), a3);
        }
        float4 cw4 = *(const float4*)(capw + d0);
        s1 = a0 * cw4.x + a1 * cw4.y + a2 * cw4.z + a3 * cw4.w;
        s2 = a0 * a0 + a1 * a1 + a2 * a2 + a3 * a3;
    }
    #pragma unroll
    for (int mk = 1; mk < 64; mk <<= 1) { s1 += __shfl_xor(s1, mk); s2 += __shfl_xor(s2, mk); }
    if ((tid & 63) == 0) { red[tid >> 6] = s1; red[4 + (tid >> 6)] = s2; }
    __syncthreads();
    if (tid == 0) {
        float S1 = red[0] + red[1] + red[2] + red[3];
        float S2 = red[4] + red[5] + red[6] + red[7];
        float val = S1 / (sqrtf(S2) + 1e-8f) + capb[0];
        out[pair] = 1.f / (1.f + __expf(-val));
    }
}

// ---------------------------------------------------------------------------
extern "C" void kernel_launch(void* const* d_in, const int* in_sizes, int n_in,
                              void* d_out, int out_size, void* d_ws, size_t ws_size,
                              hipStream_t stream)
{
    const float* feat_l = (const float*)d_in[0];
    const float* feat_f = (const float*)d_in[1];
    const float* words  = (const float*)d_in[2];
    const float* conv_w = (const float*)d_in[3];
    const float* conv_b = (const float*)d_in[4];
    const float* sa_wl  = (const float*)d_in[5];
    const float* sa_bl  = (const float*)d_in[6];
    const float* sa_wg  = (const float*)d_in[7];
    const float* sa_bg  = (const float*)d_in[8];
    const float* sa_wc  = (const float*)d_in[9];
    // d_in[10] = sa_bc: constant pre-softmax shift -> result-invariant
    const float* cap_w  = (const float*)d_in[11];
    const float* cap_b  = (const float*)d_in[12];
    float* out = (float*)d_out;

    char* ws = (char*)d_ws;
    // Overlay layout (bytes), peak 253,755,392:
    //   [0,134.2M): featT_hi@0, featT_lo@33.5M (prepf->convG);
    //               imgT_hi@67.1M, imgT_lo@100.7M (trans->logits); vbuf@0 (wctx->sa2)
    //   [134.2M,167.8M): img_hi (convG->wctx); wgT@134.2M (prep-late->g2M)
    //   [167.8M,234.9M): img_lo (convG->trans); U (logits->wctx); wspart (saG->sa2)
    //   [234.9M,243.3M): wT_hi,wT_lo (prepw->wctx); simave_bf@234.9M (post->g2M)
    //   [243.3M,247.5M): cw_hi,cw_lo (prepcw->convG); then Zp, invZf, ssqp, invn
    //   [247.5M,249.6M): wlT ; [249.6M,253.76M): g2 fp32 [1024][1024]
    u16*   featT_hi  = (u16*)(ws);
    u16*   featT_lo  = (u16*)(ws + 33554432);
    u16*   imgT_hi   = (u16*)(ws + 67108864);
    u16*   imgT_lo   = (u16*)(ws + 100663296);
    u16*   vbuf      = (u16*)(ws);
    u16*   img_hi    = (u16*)(ws + 134217728);
    u16*   wgT       = (u16*)(ws + 134217728);
    u16*   img_lo    = (u16*)(ws + 167772160);
    u16*   U         = (u16*)(ws + 167772160);
    float* wspart    = (float*)(ws + 167772160);
    u16*   wT_hi     = (u16*)(ws + 234881024);
    u16*   simave_bf = (u16*)(ws + 234881024);
    u16*   wT_lo     = (u16*)(ws + 239075328);
    u16*   cw_hi     = (u16*)(ws + 243269632);
    float* Zp        = (float*)(ws + 243269632);
    u16*   cw_lo     = (u16*)(ws + 245366784);
    float* invZf     = (float*)(ws + 245366784);
    float* ssqp      = (float*)(ws + 245628928);
    float* invn      = (float*)(ws + 246677504);
    u16*   wlT       = (u16*)(ws + 247463936);
    float* g2        = (float*)(ws + 249561088);

    hipLaunchKernelGGL(k_prepf, dim3(4096), dim3(256), 0, stream,
                       feat_l, feat_f, featT_hi, featT_lo);
    hipLaunchKernelGGL(k_prepcw, dim3(1024), dim3(256), 0, stream,
                       conv_w, cw_hi, cw_lo);
    hipLaunchKernelGGL(k_prepw, dim3(512), dim3(256), 0, stream,
                       words, wT_hi, wT_lo);
    hipLaunchKernelGGL(k_prep, dim3(256), dim3(256), 0, stream, sa_wl, wlT);
    hipLaunchKernelGGL(k_convG, dim3(256), dim3(512), 0, stream,
                       featT_hi, featT_lo, cw_hi, cw_lo, conv_b, img_hi, img_lo);
    hipLaunchKernelGGL(k_trans, dim3(4096), dim3(256), 0, stream,
                       img_hi, img_lo, imgT_hi, imgT_lo);
    hipLaunchKernelGGL(k_logits, dim3(512), dim3(512), 0, stream,
                       wT_hi, wT_lo, imgT_hi, imgT_lo, U, Zp, out);
    hipLaunchKernelGGL(k_zred, dim3(256), dim3(256), 0, stream, Zp, invZf);
    hipLaunchKernelGGL(k_attmap2, dim3(32), dim3(256), 0, stream, out);
    hipLaunchKernelGGL(k_wctx, dim3(1024), dim3(512), 0, stream,
                       img_hi, U, invZf, wT_hi, wT_lo, vbuf, ssqp);
    hipLaunchKernelGGL(k_prep, dim3(256), dim3(256), 0, stream, sa_wg, wgT);
    hipLaunchKernelGGL(k_post, dim3(1024), dim3(256), 0, stream,
                       vbuf, ssqp, invn, simave_bf);
    hipLaunchKernelGGL(k_g2M, dim3(16), dim3(512), 0, stream,
                       simave_bf, wgT, sa_bg, sa_wc, g2);
    hipLaunchKernelGGL(k_saG, dim3(1024), dim3(512), 0, stream,
                       vbuf, wlT, invn, g2, sa_bl, wspart);
    hipLaunchKernelGGL(k_sa2, dim3(1024), dim3(256), 0, stream,
                       wspart, invn, vbuf, cap_w, cap_b, out);
}